// Round 8
// baseline (269.311 us; speedup 1.0000x reference)
//
#include <hip/hip_runtime.h>
#include <hip/hip_bf16.h>
#include <math.h>

#define NN 1024
#define BB 64
#define LL 197
#define LP 256
#define DD 768
#define PSTRIDE 260  // plds row stride in elements (256 + 4 pad)

typedef __attribute__((ext_vector_type(8))) short short8;
typedef __attribute__((ext_vector_type(4))) float f32x4;

constexpr float LN_EPS = 1e-5f;
constexpr float NORM_EPS = 1e-12f;
constexpr float EPS = 1e-8f;

__device__ __forceinline__ float waveSum(float v) {
#pragma unroll
    for (int m = 32; m >= 1; m >>= 1) v += __shfl_xor(v, m, 64);
    return v;
}
__device__ __forceinline__ float grpSum(float v) {
#pragma unroll
    for (int m = 8; m >= 1; m >>= 1) v += __shfl_xor(v, m, 64);
    return v;
}
__device__ __forceinline__ float grpMax(float v) {
#pragma unroll
    for (int m = 8; m >= 1; m >>= 1) v = fmaxf(v, __shfl_xor(v, m, 64));
    return v;
}

__device__ __forceinline__ unsigned short f2bf(float f) {
    __hip_bfloat16 h = __float2bfloat16(f);
    return reinterpret_cast<unsigned short&>(h);
}

__device__ __forceinline__ float sum8(const float* p) {
    float4 x = *(const float4*)p;
    float4 y = *(const float4*)(p + 4);
    return (x.x + x.y + x.z + x.w) + (y.x + y.y + y.z + y.w);
}
__device__ __forceinline__ float max8(const float* p) {
    float4 x = *(const float4*)p;
    float4 y = *(const float4*)(p + 4);
    return fmaxf(fmaxf(fmaxf(x.x, x.y), fmaxf(x.z, x.w)),
                 fmaxf(fmaxf(y.x, y.y), fmaxf(y.z, y.w)));
}

// Text LayerNorm -> bf16 + qinv = 1/max(||y||,eps)
__global__ __launch_bounds__(256) void ln_kernel(
    const float* __restrict__ x, __hip_bfloat16* __restrict__ y,
    const float* __restrict__ gamma, const float* __restrict__ beta,
    float* __restrict__ qinv) {
    const int row = blockIdx.x;
    const int tid = threadIdx.x;
    const float* xr = x + (size_t)row * DD;
    __hip_bfloat16* yr = y + (size_t)row * DD;

    float v[3];
    float s = 0.f, ss = 0.f;
#pragma unroll
    for (int c = 0; c < 3; c++) {
        float t = xr[tid + 256 * c];
        v[c] = t; s += t; ss += t * t;
    }
    __shared__ float red[8];
    s = waveSum(s); ss = waveSum(ss);
    const int w = tid >> 6;
    if ((tid & 63) == 0) { red[w] = s; red[4 + w] = ss; }
    __syncthreads();
    s = red[0] + red[1] + red[2] + red[3];
    ss = red[4] + red[5] + red[6] + red[7];
    const float mean = s * (1.f / DD);
    const float var = ss * (1.f / DD) - mean * mean;
    const float rs = rsqrtf(var + LN_EPS);

    float q = 0.f;
#pragma unroll
    for (int c = 0; c < 3; c++) {
        const int d = tid + 256 * c;
        float t = (v[c] - mean) * rs * gamma[d] + beta[d];
        __hip_bfloat16 hb = __float2bfloat16(t);
        yr[d] = hb;
        float tb = __bfloat162float(hb);
        q += tb * tb;
    }
    __syncthreads();
    q = waveSum(q);
    if ((tid & 63) == 0) red[w] = q;
    __syncthreads();
    if (tid == 0) {
        float n2 = red[0] + red[1] + red[2] + red[3];
        qinv[row] = 1.f / fmaxf(sqrtf(n2), NORM_EPS);
    }
}

// Vision LayerNorm into padded [B, LP, D]; XCD-swizzled: blockid ≡ b (mod 8).
__global__ __launch_bounds__(256) void ln_vis_kernel(
    const float* __restrict__ x, __hip_bfloat16* __restrict__ y,
    const float* __restrict__ gamma, const float* __restrict__ beta) {
    const int id = blockIdx.x;           // 0..BB*LP-1 (16384)
    const int xcd = id & 7;
    const int k = id >> 3;               // 0..2047
    const int bhi = k >> 8;              // 0..7
    const int l = k & 255;               // 0..255
    const int b = xcd + 8 * bhi;
    const int tid = threadIdx.x;
    __hip_bfloat16* yr = y + ((size_t)b * LP + l) * DD;
    if (l >= LL) {
#pragma unroll
        for (int c = 0; c < 3; c++) yr[tid + 256 * c] = __float2bfloat16(0.f);
        return;
    }
    const float* xr = x + ((size_t)b * LL + l) * DD;

    float v[3];
    float s = 0.f, ss = 0.f;
#pragma unroll
    for (int c = 0; c < 3; c++) {
        float t = xr[tid + 256 * c];
        v[c] = t; s += t; ss += t * t;
    }
    __shared__ float red[8];
    s = waveSum(s); ss = waveSum(ss);
    const int w = tid >> 6;
    if ((tid & 63) == 0) { red[w] = s; red[4 + w] = ss; }
    __syncthreads();
    s = red[0] + red[1] + red[2] + red[3];
    ss = red[4] + red[5] + red[6] + red[7];
    const float mean = s * (1.f / DD);
    const float var = ss * (1.f / DD) - mean * mean;
    const float rs = rsqrtf(var + LN_EPS);
#pragma unroll
    for (int c = 0; c < 3; c++) {
        const int d = tid + 256 * c;
        yr[d] = __float2bfloat16((v[c] - mean) * rs * gamma[d] + beta[d]);
    }
}

// G[b] = vt_b . vt_b^T [LP x LP] bf16. 1-D grid 1024, XCD-swizzled like main.
__global__ __launch_bounds__(256) void gram_kernel(
    const __hip_bfloat16* __restrict__ vt, __hip_bfloat16* __restrict__ G) {
    const int id = blockIdx.x;
    const int xcd = id & 7;
    const int k = id >> 3;               // 0..127
    const int bhi = k >> 4;              // 0..7
    const int rb = k & 15;               // 0..15
    const int b = xcd + 8 * bhi;
    const int tid = threadIdx.x, w = tid >> 6, lane = tid & 63;
    const short* vtb = (const short*)(vt + (size_t)b * LP * DD);
    const int kof = (lane >> 4) * 8;

    short8 a[24];
    const int arow = rb * 16 + (lane & 15);
#pragma unroll
    for (int ks = 0; ks < 24; ks++)
        a[ks] = *(const short8*)(vtb + (size_t)arow * DD + ks * 32 + kof);

#pragma unroll
    for (int cbi = 0; cbi < 4; cbi++) {
        const int cb = w + 4 * cbi;
        f32x4 c = {0.f, 0.f, 0.f, 0.f};
        const int brow = cb * 16 + (lane & 15);
#pragma unroll
        for (int ks = 0; ks < 24; ks++) {
            short8 bf = *(const short8*)(vtb + (size_t)brow * DD + ks * 32 + kof);
            c = __builtin_amdgcn_mfma_f32_16x16x32_bf16(a[ks], bf, c, 0, 0, 0);
        }
        __hip_bfloat16* Gb = G + ((size_t)b * LP + rb * 16) * LP + cb * 16;
        const int col = lane & 15, rg = (lane >> 4) * 4;
#pragma unroll
        for (int r = 0; r < 4; r++) Gb[(size_t)(rg + r) * LP + col] = __float2bfloat16(c[r]);
    }
}

// Fused main: S = tf.vt^T (direct from L2), softmax, num, T = P.G, den, logits.
// 1-D grid 1024 x 512 threads (8 waves). XCD-swizzled. Wave w owns l-blocks
// {w, w+8}. acc = 2x4 frags (32 regs) -> fits 4 waves/EU without spill.
__global__ __launch_bounds__(512, 4) void main_kernel(
    const __hip_bfloat16* __restrict__ tf, const __hip_bfloat16* __restrict__ vt,
    const __hip_bfloat16* __restrict__ G, const float* __restrict__ qinv,
    float* __restrict__ logits) {
    const int id = blockIdx.x;
    const int xcd = id & 7;
    const int kk = id >> 3;              // 0..127
    const int bhi = kk >> 4;             // 0..7
    const int nt = kk & 15;              // 0..15
    const int b = xcd + 8 * bhi;
    const int n0 = nt * 64;
    const int tid = threadIdx.x, w = tid >> 6, lane = tid & 63;
    const int g = lane >> 4, c = lane & 15;

    __shared__ __align__(16) unsigned char smem[64 * PSTRIDE * 2 + 3 * 64 * 8 * 4];
    unsigned short* plds = (unsigned short*)smem;            // [64][PSTRIDE]
    float* mx = (float*)(smem + 64 * PSTRIDE * 2);           // [64][8]
    float* sm = mx + 512;                                    // [64][8]
    float* nm = sm + 512;                                    // [64][8]

    const short* tfp = (const short*)tf;
    const short* vtb = (const short*)(vt + (size_t)b * LP * DD);

    // ---- Stage 1: S = tf . vt^T, K-sliced, operands straight from L2 ----
    f32x4 acc[2][4];  // [i = lb slot][nb]
#pragma unroll
    for (int i = 0; i < 2; i++)
#pragma unroll
        for (int nb = 0; nb < 4; nb++) acc[i][nb] = {0.f, 0.f, 0.f, 0.f};

#pragma unroll
    for (int ks = 0; ks < 24; ks++) {
        short8 a[4];
#pragma unroll
        for (int nb = 0; nb < 4; nb++)
            a[nb] = *(const short8*)(tfp + (size_t)(n0 + nb * 16 + c) * DD + ks * 32 + g * 8);
#pragma unroll
        for (int i = 0; i < 2; i++) {
            const int lb = w + 8 * i;
            short8 bf = *(const short8*)(vtb + (size_t)(lb * 16 + c) * DD + ks * 32 + g * 8);
#pragma unroll
            for (int nb = 0; nb < 4; nb++)
                acc[i][nb] = __builtin_amdgcn_mfma_f32_16x16x32_bf16(a[nb], bf, acc[i][nb], 0, 0, 0);
        }
    }

    // ---- Stage 2: softmax over l (waves hold disjoint l-columns) ----
    const float inv_sqrtD = 0.0360843918f;
    float mp[4][4];
#pragma unroll
    for (int nb = 0; nb < 4; nb++)
#pragma unroll
        for (int r = 0; r < 4; r++) mp[nb][r] = -1e30f;
#pragma unroll
    for (int i = 0; i < 2; i++) {
        const int l = (w + 8 * i) * 16 + c;
        if (l < LL) {
#pragma unroll
            for (int nb = 0; nb < 4; nb++)
#pragma unroll
                for (int r = 0; r < 4; r++) mp[nb][r] = fmaxf(mp[nb][r], acc[i][nb][r]);
        }
    }
#pragma unroll
    for (int nb = 0; nb < 4; nb++)
#pragma unroll
        for (int r = 0; r < 4; r++) mp[nb][r] = grpMax(mp[nb][r]);
    if (c == 0) {
#pragma unroll
        for (int nb = 0; nb < 4; nb++)
#pragma unroll
            for (int r = 0; r < 4; r++) mx[(nb * 16 + g * 4 + r) * 8 + w] = mp[nb][r];
    }
    __syncthreads();
    float mf[4][4];
#pragma unroll
    for (int nb = 0; nb < 4; nb++)
#pragma unroll
        for (int r = 0; r < 4; r++) mf[nb][r] = max8(mx + (nb * 16 + g * 4 + r) * 8);

    float sp[4][4], np[4][4];
#pragma unroll
    for (int nb = 0; nb < 4; nb++)
#pragma unroll
        for (int r = 0; r < 4; r++) { sp[nb][r] = 0.f; np[nb][r] = 0.f; }
#pragma unroll
    for (int i = 0; i < 2; i++) {
        const int l = (w + 8 * i) * 16 + c;
#pragma unroll
        for (int nb = 0; nb < 4; nb++)
#pragma unroll
            for (int r = 0; r < 4; r++) {
                const float raw = acc[i][nb][r];
                const float p = (l < LL) ? __expf((raw - mf[nb][r]) * inv_sqrtD) : 0.f;
                acc[i][nb][r] = p;
                sp[nb][r] += p;
                np[nb][r] += p * raw;
            }
    }
#pragma unroll
    for (int nb = 0; nb < 4; nb++)
#pragma unroll
        for (int r = 0; r < 4; r++) { sp[nb][r] = grpSum(sp[nb][r]); np[nb][r] = grpSum(np[nb][r]); }
    if (c == 0) {
#pragma unroll
        for (int nb = 0; nb < 4; nb++)
#pragma unroll
            for (int r = 0; r < 4; r++) {
                const int row = nb * 16 + g * 4 + r;
                sm[row * 8 + w] = sp[nb][r];
                nm[row * 8 + w] = np[nb][r];
            }
    }
    __syncthreads();

    float invs[4][4];
#pragma unroll
    for (int nb = 0; nb < 4; nb++)
#pragma unroll
        for (int r = 0; r < 4; r++)
            invs[nb][r] = 1.f / sum8(sm + (nb * 16 + g * 4 + r) * 8);

    // write normalized P (bf16) to plds [64][PSTRIDE]
#pragma unroll
    for (int i = 0; i < 2; i++) {
        const int lb = w + 8 * i;
#pragma unroll
        for (int nb = 0; nb < 4; nb++)
#pragma unroll
            for (int r = 0; r < 4; r++)
                plds[(size_t)(nb * 16 + g * 4 + r) * PSTRIDE + lb * 16 + c] =
                    f2bf(acc[i][nb][r] * invs[nb][r]);
    }
    __syncthreads();

    // ---- Stage 3: T = P.G (lb-outer, G rows direct from L2), den = sum P*T ----
    const short* Gb = (const short*)(G + (size_t)b * LP * LP);
    float den[4][4];
#pragma unroll
    for (int nb = 0; nb < 4; nb++)
#pragma unroll
        for (int r = 0; r < 4; r++) den[nb][r] = 0.f;

#pragma unroll
    for (int i = 0; i < 2; i++) {
        const int lb = w + 8 * i;
        short8 gbv[8];
#pragma unroll
        for (int kb = 0; kb < 8; kb++)
            gbv[kb] = *(const short8*)(Gb + (size_t)(lb * 16 + c) * LP + kb * 32 + g * 8);
#pragma unroll
        for (int nb = 0; nb < 4; nb++) {
            f32x4 t = {0.f, 0.f, 0.f, 0.f};
#pragma unroll
            for (int kb = 0; kb < 8; kb++) {
                short8 pa = *(const short8*)(plds + (size_t)(nb * 16 + c) * PSTRIDE + kb * 32 + g * 8);
                t = __builtin_amdgcn_mfma_f32_16x16x32_bf16(pa, gbv[kb], t, 0, 0, 0);
            }
#pragma unroll
            for (int r = 0; r < 4; r++)
                den[nb][r] += acc[i][nb][r] * invs[nb][r] * t[r];
        }
    }

    // cross-wave den reduce + epilogue
#pragma unroll
    for (int nb = 0; nb < 4; nb++)
#pragma unroll
        for (int r = 0; r < 4; r++) den[nb][r] = grpSum(den[nb][r]);
    __syncthreads();
    if (c == 0) {
#pragma unroll
        for (int nb = 0; nb < 4; nb++)
#pragma unroll
            for (int r = 0; r < 4; r++) mx[(nb * 16 + g * 4 + r) * 8 + w] = den[nb][r];
    }
    __syncthreads();
    if (tid < 64) {
        const int row = tid;
        const int n = n0 + row;
        const float dsum = sum8(mx + row * 8);
        const float ssum = sum8(sm + row * 8);
        const float nsum = sum8(nm + row * 8);
        const float num = nsum / ssum;
        const float dn = fmaxf(sqrtf(fmaxf(dsum, 0.f)), NORM_EPS);
        logits[(size_t)n * BB + b] = num * qinv[n] / dn;
    }
}

__global__ __launch_bounds__(64) void loss_row_kernel(
    const float* __restrict__ logits, const int* __restrict__ gm,
    const float* __restrict__ logtemp, float* __restrict__ scaled,
    float* __restrict__ posv, float* __restrict__ rowloss) {
    const int n = blockIdx.x;
    const int b = threadIdx.x;
    const float invtemp = 1.f / expf(logtemp[0]);
    const float e = expf(logits[(size_t)n * BB + b] * invtemp);
    scaled[(size_t)n * BB + b] = e;
    const float sum = waveSum(e);
    const int g = gm[n];
    const float pos = __shfl(e, g, 64);
    if (b == 0) {
        posv[n] = pos;
        rowloss[n] = -logf(pos / (sum + EPS) + EPS);
    }
}

__global__ __launch_bounds__(256) void colsum_kernel(
    const float* __restrict__ scaled, const int* __restrict__ gm,
    float* __restrict__ colsum, float* __restrict__ poscol) {
    const int b = blockIdx.x;
    const int tid = threadIdx.x;
    float s = 0.f, p = 0.f;
    for (int n = tid; n < NN; n += 256) {
        const float e = scaled[(size_t)n * BB + b];
        s += e;
        if (gm[n] == b) p += e;
    }
    s = waveSum(s); p = waveSum(p);
    __shared__ float red[8];
    const int w = tid >> 6;
    if ((tid & 63) == 0) { red[w] = s; red[4 + w] = p; }
    __syncthreads();
    if (tid == 0) {
        colsum[b] = red[0] + red[1] + red[2] + red[3];
        poscol[b] = red[4] + red[5] + red[6] + red[7];
    }
}

__global__ __launch_bounds__(1024) void final_kernel(
    const float* __restrict__ posv, const float* __restrict__ rowloss,
    const float* __restrict__ colsum, const float* __restrict__ poscol,
    const int* __restrict__ gm, float* __restrict__ out) {
    const int n = threadIdx.x;
    const int g = gm[n];
    const float pos = posv[n];
    const float sum_neg = colsum[g] - poscol[g];
    const float cl = -logf(pos / (pos + sum_neg + EPS) + EPS);
    float v = rowloss[n] + cl;
    v = waveSum(v);
    __shared__ float red[16];
    if ((n & 63) == 0) red[n >> 6] = v;
    __syncthreads();
    if (n == 0) {
        float s = 0.f;
#pragma unroll
        for (int i = 0; i < 16; i++) s += red[i];
        out[0] = s / (2.f * NN);
    }
}

extern "C" void kernel_launch(void* const* d_in, const int* in_sizes, int n_in,
                              void* d_out, int out_size, void* d_ws, size_t ws_size,
                              hipStream_t stream) {
    const float* text = (const float*)d_in[0];
    const float* vis = (const float*)d_in[1];
    const int* gm = (const int*)d_in[2];
    const float* gamma = (const float*)d_in[3];
    const float* beta = (const float*)d_in[4];
    const float* logtemp = (const float*)d_in[5];
    float* out = (float*)d_out;

    char* w = (char*)d_ws;
    __hip_bfloat16* tf = (__hip_bfloat16*)w;             w += (size_t)NN * DD * 2;
    __hip_bfloat16* vt = (__hip_bfloat16*)w;             w += (size_t)BB * LP * DD * 2;
    __hip_bfloat16* G  = (__hip_bfloat16*)w;             w += (size_t)BB * LP * LP * 2;
    float* qinv    = (float*)w;  w += (size_t)NN * 4;
    float* logits  = (float*)w;  w += (size_t)NN * BB * 4;
    float* scaled  = (float*)w;  w += (size_t)NN * BB * 4;
    float* posv    = (float*)w;  w += (size_t)NN * 4;
    float* rowloss = (float*)w;  w += (size_t)NN * 4;
    float* colsum  = (float*)w;  w += (size_t)BB * 4;
    float* poscol  = (float*)w;  w += (size_t)BB * 4;

    ln_kernel<<<NN, 256, 0, stream>>>(text, tf, gamma, beta, qinv);
    ln_vis_kernel<<<BB * LP, 256, 0, stream>>>(vis, vt, gamma, beta);

    gram_kernel<<<1024, 256, 0, stream>>>(vt, G);
    main_kernel<<<1024, 512, 0, stream>>>(tf, vt, G, qinv, logits);

    loss_row_kernel<<<NN, 64, 0, stream>>>(logits, gm, logtemp, scaled, posv, rowloss);
    colsum_kernel<<<BB, 256, 0, stream>>>(scaled, gm, colsum, poscol);
    final_kernel<<<1, 1024, 0, stream>>>(posv, rowloss, colsum, poscol, gm, out);
}

// Round 9
// 242.000 us; speedup vs baseline: 1.1129x; 1.1129x over previous
//
#include <hip/hip_runtime.h>
#include <hip/hip_bf16.h>
#include <math.h>

#define NN 1024
#define BB 64
#define LL 197
#define LP 256
#define DD 768
#define PSTRIDE 260  // plds row stride in elements (256 + 4 pad)

typedef __attribute__((ext_vector_type(8))) short short8;
typedef __attribute__((ext_vector_type(4))) float f32x4;

constexpr float LN_EPS = 1e-5f;
constexpr float NORM_EPS = 1e-12f;
constexpr float EPS = 1e-8f;

__device__ __forceinline__ float waveSum(float v) {
#pragma unroll
    for (int m = 32; m >= 1; m >>= 1) v += __shfl_xor(v, m, 64);
    return v;
}
__device__ __forceinline__ float grpSum(float v) {
#pragma unroll
    for (int m = 8; m >= 1; m >>= 1) v += __shfl_xor(v, m, 64);
    return v;
}
__device__ __forceinline__ float grpMax(float v) {
#pragma unroll
    for (int m = 8; m >= 1; m >>= 1) v = fmaxf(v, __shfl_xor(v, m, 64));
    return v;
}

__device__ __forceinline__ unsigned short f2bf(float f) {
    __hip_bfloat16 h = __float2bfloat16(f);
    return reinterpret_cast<unsigned short&>(h);
}

// Text LayerNorm -> bf16 + qinv = 1/max(||y||,eps)
__global__ __launch_bounds__(256) void ln_kernel(
    const float* __restrict__ x, __hip_bfloat16* __restrict__ y,
    const float* __restrict__ gamma, const float* __restrict__ beta,
    float* __restrict__ qinv) {
    const int row = blockIdx.x;
    const int tid = threadIdx.x;
    const float* xr = x + (size_t)row * DD;
    __hip_bfloat16* yr = y + (size_t)row * DD;

    float v[3];
    float s = 0.f, ss = 0.f;
#pragma unroll
    for (int c = 0; c < 3; c++) {
        float t = xr[tid + 256 * c];
        v[c] = t; s += t; ss += t * t;
    }
    __shared__ float red[8];
    s = waveSum(s); ss = waveSum(ss);
    const int w = tid >> 6;
    if ((tid & 63) == 0) { red[w] = s; red[4 + w] = ss; }
    __syncthreads();
    s = red[0] + red[1] + red[2] + red[3];
    ss = red[4] + red[5] + red[6] + red[7];
    const float mean = s * (1.f / DD);
    const float var = ss * (1.f / DD) - mean * mean;
    const float rs = rsqrtf(var + LN_EPS);

    float q = 0.f;
#pragma unroll
    for (int c = 0; c < 3; c++) {
        const int d = tid + 256 * c;
        float t = (v[c] - mean) * rs * gamma[d] + beta[d];
        __hip_bfloat16 hb = __float2bfloat16(t);
        yr[d] = hb;
        float tb = __bfloat162float(hb);
        q += tb * tb;
    }
    __syncthreads();
    q = waveSum(q);
    if ((tid & 63) == 0) red[w] = q;
    __syncthreads();
    if (tid == 0) {
        float n2 = red[0] + red[1] + red[2] + red[3];
        qinv[row] = 1.f / fmaxf(sqrtf(n2), NORM_EPS);
    }
}

// Vision LayerNorm into padded [B, LP, D]; XCD-swizzled: blockid ≡ b (mod 8).
__global__ __launch_bounds__(256) void ln_vis_kernel(
    const float* __restrict__ x, __hip_bfloat16* __restrict__ y,
    const float* __restrict__ gamma, const float* __restrict__ beta) {
    const int id = blockIdx.x;           // 0..BB*LP-1 (16384)
    const int xcd = id & 7;
    const int k = id >> 3;               // 0..2047
    const int bhi = k >> 8;              // 0..7
    const int l = k & 255;               // 0..255
    const int b = xcd + 8 * bhi;
    const int tid = threadIdx.x;
    __hip_bfloat16* yr = y + ((size_t)b * LP + l) * DD;
    if (l >= LL) {
#pragma unroll
        for (int c = 0; c < 3; c++) yr[tid + 256 * c] = __float2bfloat16(0.f);
        return;
    }
    const float* xr = x + ((size_t)b * LL + l) * DD;

    float v[3];
    float s = 0.f, ss = 0.f;
#pragma unroll
    for (int c = 0; c < 3; c++) {
        float t = xr[tid + 256 * c];
        v[c] = t; s += t; ss += t * t;
    }
    __shared__ float red[8];
    s = waveSum(s); ss = waveSum(ss);
    const int w = tid >> 6;
    if ((tid & 63) == 0) { red[w] = s; red[4 + w] = ss; }
    __syncthreads();
    s = red[0] + red[1] + red[2] + red[3];
    ss = red[4] + red[5] + red[6] + red[7];
    const float mean = s * (1.f / DD);
    const float var = ss * (1.f / DD) - mean * mean;
    const float rs = rsqrtf(var + LN_EPS);
#pragma unroll
    for (int c = 0; c < 3; c++) {
        const int d = tid + 256 * c;
        yr[d] = __float2bfloat16((v[c] - mean) * rs * gamma[d] + beta[d]);
    }
}

// G[b] = vt_b . vt_b^T [LP x LP] bf16. 1-D grid 1024, XCD-swizzled like main.
__global__ __launch_bounds__(256) void gram_kernel(
    const __hip_bfloat16* __restrict__ vt, __hip_bfloat16* __restrict__ G) {
    const int id = blockIdx.x;
    const int xcd = id & 7;
    const int k = id >> 3;               // 0..127
    const int bhi = k >> 4;              // 0..7
    const int rb = k & 15;               // 0..15
    const int b = xcd + 8 * bhi;
    const int tid = threadIdx.x, w = tid >> 6, lane = tid & 63;
    const short* vtb = (const short*)(vt + (size_t)b * LP * DD);
    const int kof = (lane >> 4) * 8;

    short8 a[24];
    const int arow = rb * 16 + (lane & 15);
#pragma unroll
    for (int ks = 0; ks < 24; ks++)
        a[ks] = *(const short8*)(vtb + (size_t)arow * DD + ks * 32 + kof);

#pragma unroll
    for (int cbi = 0; cbi < 4; cbi++) {
        const int cb = w + 4 * cbi;
        f32x4 c = {0.f, 0.f, 0.f, 0.f};
        const int brow = cb * 16 + (lane & 15);
#pragma unroll
        for (int ks = 0; ks < 24; ks++) {
            short8 bf = *(const short8*)(vtb + (size_t)brow * DD + ks * 32 + kof);
            c = __builtin_amdgcn_mfma_f32_16x16x32_bf16(a[ks], bf, c, 0, 0, 0);
        }
        __hip_bfloat16* Gb = G + ((size_t)b * LP + rb * 16) * LP + cb * 16;
        const int col = lane & 15, rg = (lane >> 4) * 4;
#pragma unroll
        for (int r = 0; r < 4; r++) Gb[(size_t)(rg + r) * LP + col] = __float2bfloat16(c[r]);
    }
}

// Fused main: S = tf.vt^T (direct from L2, depth-1 register prefetch), softmax,
// num, T = P.G, den, logits. 1-D grid 1024 x 256 thr, XCD-swizzled.
// Wave w owns l-blocks {w, w+4, w+8, w+12}; LP=256 -> branch-free.
__global__ __launch_bounds__(256, 3) void main_kernel(
    const __hip_bfloat16* __restrict__ tf, const __hip_bfloat16* __restrict__ vt,
    const __hip_bfloat16* __restrict__ G, const float* __restrict__ qinv,
    float* __restrict__ logits) {
    const int id = blockIdx.x;
    const int xcd = id & 7;
    const int kk = id >> 3;              // 0..127
    const int bhi = kk >> 4;             // 0..7
    const int nt = kk & 15;              // 0..15
    const int b = xcd + 8 * bhi;
    const int n0 = nt * 64;
    const int tid = threadIdx.x, w = tid >> 6, lane = tid & 63;
    const int g = lane >> 4, c = lane & 15;

    __shared__ __align__(16) unsigned char smem[64 * PSTRIDE * 2 + 3072];
    unsigned short* plds = (unsigned short*)smem;            // [64][PSTRIDE]
    float* mx = (float*)(smem + 64 * PSTRIDE * 2);           // [64][4]
    float* sm = mx + 256;                                    // [64][4]
    float* nm = sm + 256;                                    // [64][4]

    const short* tfp = (const short*)tf;
    const short* vtb = (const short*)(vt + (size_t)b * LP * DD);

    // ---- Stage 1: S = tf . vt^T, K-sliced, depth-1 register double-buffer ----
    f32x4 acc[4][4];  // [i = lb slot][nb]
#pragma unroll
    for (int i = 0; i < 4; i++)
#pragma unroll
        for (int nb = 0; nb < 4; nb++) acc[i][nb] = {0.f, 0.f, 0.f, 0.f};

#define LOADS(ks, aa, bb)                                                        \
    {                                                                            \
        _Pragma("unroll")                                                        \
        for (int nb_ = 0; nb_ < 4; nb_++)                                        \
            aa[nb_] = *(const short8*)(tfp + (size_t)(n0 + nb_ * 16 + c) * DD +  \
                                       (ks) * 32 + g * 8);                       \
        _Pragma("unroll")                                                        \
        for (int i_ = 0; i_ < 4; i_++)                                           \
            bb[i_] = *(const short8*)(vtb + (size_t)((w + 4 * i_) * 16 + c) * DD \
                                      + (ks) * 32 + g * 8);                      \
    }
#define MFMAS(aa, bb)                                                            \
    {                                                                            \
        _Pragma("unroll")                                                        \
        for (int i_ = 0; i_ < 4; i_++)                                           \
            _Pragma("unroll")                                                    \
            for (int nb_ = 0; nb_ < 4; nb_++)                                    \
                acc[i_][nb_] = __builtin_amdgcn_mfma_f32_16x16x32_bf16(          \
                    aa[nb_], bb[i_], acc[i_][nb_], 0, 0, 0);                     \
    }

    short8 aA[4], bA[4], aB[4], bB[4];
    LOADS(0, aA, bA);
    for (int ks = 0; ks < 24; ks += 2) {
        LOADS(ks + 1, aB, bB);     // issue next loads before computing current
        MFMAS(aA, bA);
        if (ks + 2 < 24) LOADS(ks + 2, aA, bA);
        MFMAS(aB, bB);
    }
#undef LOADS
#undef MFMAS

    // ---- Stage 2: softmax over l (waves hold disjoint l-columns) ----
    const float inv_sqrtD = 0.0360843918f;
    float mp[4][4];
#pragma unroll
    for (int nb = 0; nb < 4; nb++)
#pragma unroll
        for (int r = 0; r < 4; r++) mp[nb][r] = -1e30f;
#pragma unroll
    for (int i = 0; i < 4; i++) {
        const int l = (w + 4 * i) * 16 + c;
        if (l < LL) {
#pragma unroll
            for (int nb = 0; nb < 4; nb++)
#pragma unroll
                for (int r = 0; r < 4; r++) mp[nb][r] = fmaxf(mp[nb][r], acc[i][nb][r]);
        }
    }
#pragma unroll
    for (int nb = 0; nb < 4; nb++)
#pragma unroll
        for (int r = 0; r < 4; r++) mp[nb][r] = grpMax(mp[nb][r]);
    if (c == 0) {
#pragma unroll
        for (int nb = 0; nb < 4; nb++)
#pragma unroll
            for (int r = 0; r < 4; r++) mx[(nb * 16 + g * 4 + r) * 4 + w] = mp[nb][r];
    }
    __syncthreads();
    float mf[4][4];
#pragma unroll
    for (int nb = 0; nb < 4; nb++)
#pragma unroll
        for (int r = 0; r < 4; r++) {
            const int row = nb * 16 + g * 4 + r;
            mf[nb][r] = fmaxf(fmaxf(mx[row * 4 + 0], mx[row * 4 + 1]),
                              fmaxf(mx[row * 4 + 2], mx[row * 4 + 3]));
        }

    float sp[4][4], np[4][4];
#pragma unroll
    for (int nb = 0; nb < 4; nb++)
#pragma unroll
        for (int r = 0; r < 4; r++) { sp[nb][r] = 0.f; np[nb][r] = 0.f; }
#pragma unroll
    for (int i = 0; i < 4; i++) {
        const int l = (w + 4 * i) * 16 + c;
#pragma unroll
        for (int nb = 0; nb < 4; nb++)
#pragma unroll
            for (int r = 0; r < 4; r++) {
                const float raw = acc[i][nb][r];
                const float p = (l < LL) ? __expf((raw - mf[nb][r]) * inv_sqrtD) : 0.f;
                acc[i][nb][r] = p;
                sp[nb][r] += p;
                np[nb][r] += p * raw;
            }
    }
#pragma unroll
    for (int nb = 0; nb < 4; nb++)
#pragma unroll
        for (int r = 0; r < 4; r++) { sp[nb][r] = grpSum(sp[nb][r]); np[nb][r] = grpSum(np[nb][r]); }
    if (c == 0) {
#pragma unroll
        for (int nb = 0; nb < 4; nb++)
#pragma unroll
            for (int r = 0; r < 4; r++) {
                const int row = nb * 16 + g * 4 + r;
                sm[row * 4 + w] = sp[nb][r];
                nm[row * 4 + w] = np[nb][r];
            }
    }
    __syncthreads();

    float invs[4][4];
#pragma unroll
    for (int nb = 0; nb < 4; nb++)
#pragma unroll
        for (int r = 0; r < 4; r++) {
            const int row = nb * 16 + g * 4 + r;
            const float ssum = sm[row * 4 + 0] + sm[row * 4 + 1] + sm[row * 4 + 2] + sm[row * 4 + 3];
            invs[nb][r] = 1.f / ssum;
        }

    // write normalized P (bf16) to plds [64][PSTRIDE]
#pragma unroll
    for (int i = 0; i < 4; i++) {
        const int lb = w + 4 * i;
#pragma unroll
        for (int nb = 0; nb < 4; nb++)
#pragma unroll
            for (int r = 0; r < 4; r++)
                plds[(size_t)(nb * 16 + g * 4 + r) * PSTRIDE + lb * 16 + c] =
                    f2bf(acc[i][nb][r] * invs[nb][r]);
    }
    __syncthreads();

    // ---- Stage 3: T = P.G (lb-outer, G rows direct from L2), den = sum P*T ----
    const short* Gb = (const short*)(G + (size_t)b * LP * LP);
    float den[4][4];
#pragma unroll
    for (int nb = 0; nb < 4; nb++)
#pragma unroll
        for (int r = 0; r < 4; r++) den[nb][r] = 0.f;

#pragma unroll
    for (int i = 0; i < 4; i++) {
        const int lb = w + 4 * i;
        short8 gbv[8];
#pragma unroll
        for (int kb = 0; kb < 8; kb++)
            gbv[kb] = *(const short8*)(Gb + (size_t)(lb * 16 + c) * LP + kb * 32 + g * 8);
#pragma unroll
        for (int nb = 0; nb < 4; nb++) {
            f32x4 t = {0.f, 0.f, 0.f, 0.f};
#pragma unroll
            for (int kb = 0; kb < 8; kb++) {
                short8 pa = *(const short8*)(plds + (size_t)(nb * 16 + c) * PSTRIDE + kb * 32 + g * 8);
                t = __builtin_amdgcn_mfma_f32_16x16x32_bf16(pa, gbv[kb], t, 0, 0, 0);
            }
#pragma unroll
            for (int r = 0; r < 4; r++)
                den[nb][r] += acc[i][nb][r] * invs[nb][r] * t[r];
        }
    }

    // cross-wave den reduce + epilogue
#pragma unroll
    for (int nb = 0; nb < 4; nb++)
#pragma unroll
        for (int r = 0; r < 4; r++) den[nb][r] = grpSum(den[nb][r]);
    __syncthreads();
    if (c == 0) {
#pragma unroll
        for (int nb = 0; nb < 4; nb++)
#pragma unroll
            for (int r = 0; r < 4; r++) mx[(nb * 16 + g * 4 + r) * 4 + w] = den[nb][r];
    }
    __syncthreads();
    if (tid < 64) {
        const int row = tid;
        const int n = n0 + row;
        const float dsum = mx[row * 4 + 0] + mx[row * 4 + 1] + mx[row * 4 + 2] + mx[row * 4 + 3];
        const float ssum = sm[row * 4 + 0] + sm[row * 4 + 1] + sm[row * 4 + 2] + sm[row * 4 + 3];
        const float nsum = nm[row * 4 + 0] + nm[row * 4 + 1] + nm[row * 4 + 2] + nm[row * 4 + 3];
        const float num = nsum / ssum;
        const float dn = fmaxf(sqrtf(fmaxf(dsum, 0.f)), NORM_EPS);
        logits[(size_t)n * BB + b] = num * qinv[n] / dn;
    }
}

__global__ __launch_bounds__(64) void loss_row_kernel(
    const float* __restrict__ logits, const int* __restrict__ gm,
    const float* __restrict__ logtemp, float* __restrict__ scaled,
    float* __restrict__ posv, float* __restrict__ rowloss) {
    const int n = blockIdx.x;
    const int b = threadIdx.x;
    const float invtemp = 1.f / expf(logtemp[0]);
    const float e = expf(logits[(size_t)n * BB + b] * invtemp);
    scaled[(size_t)n * BB + b] = e;
    const float sum = waveSum(e);
    const int g = gm[n];
    const float pos = __shfl(e, g, 64);
    if (b == 0) {
        posv[n] = pos;
        rowloss[n] = -logf(pos / (sum + EPS) + EPS);
    }
}

__global__ __launch_bounds__(256) void colsum_kernel(
    const float* __restrict__ scaled, const int* __restrict__ gm,
    float* __restrict__ colsum, float* __restrict__ poscol) {
    const int b = blockIdx.x;
    const int tid = threadIdx.x;
    float s = 0.f, p = 0.f;
    for (int n = tid; n < NN; n += 256) {
        const float e = scaled[(size_t)n * BB + b];
        s += e;
        if (gm[n] == b) p += e;
    }
    s = waveSum(s); p = waveSum(p);
    __shared__ float red[8];
    const int w = tid >> 6;
    if ((tid & 63) == 0) { red[w] = s; red[4 + w] = p; }
    __syncthreads();
    if (tid == 0) {
        colsum[b] = red[0] + red[1] + red[2] + red[3];
        poscol[b] = red[4] + red[5] + red[6] + red[7];
    }
}

__global__ __launch_bounds__(1024) void final_kernel(
    const float* __restrict__ posv, const float* __restrict__ rowloss,
    const float* __restrict__ colsum, const float* __restrict__ poscol,
    const int* __restrict__ gm, float* __restrict__ out) {
    const int n = threadIdx.x;
    const int g = gm[n];
    const float pos = posv[n];
    const float sum_neg = colsum[g] - poscol[g];
    const float cl = -logf(pos / (pos + sum_neg + EPS) + EPS);
    float v = rowloss[n] + cl;
    v = waveSum(v);
    __shared__ float red[16];
    if ((n & 63) == 0) red[n >> 6] = v;
    __syncthreads();
    if (n == 0) {
        float s = 0.f;
#pragma unroll
        for (int i = 0; i < 16; i++) s += red[i];
        out[0] = s / (2.f * NN);
    }
}

extern "C" void kernel_launch(void* const* d_in, const int* in_sizes, int n_in,
                              void* d_out, int out_size, void* d_ws, size_t ws_size,
                              hipStream_t stream) {
    const float* text = (const float*)d_in[0];
    const float* vis = (const float*)d_in[1];
    const int* gm = (const int*)d_in[2];
    const float* gamma = (const float*)d_in[3];
    const float* beta = (const float*)d_in[4];
    const float* logtemp = (const float*)d_in[5];
    float* out = (float*)d_out;

    char* w = (char*)d_ws;
    __hip_bfloat16* tf = (__hip_bfloat16*)w;             w += (size_t)NN * DD * 2;
    __hip_bfloat16* vt = (__hip_bfloat16*)w;             w += (size_t)BB * LP * DD * 2;
    __hip_bfloat16* G  = (__hip_bfloat16*)w;             w += (size_t)BB * LP * LP * 2;
    float* qinv    = (float*)w;  w += (size_t)NN * 4;
    float* logits  = (float*)w;  w += (size_t)NN * BB * 4;
    float* scaled  = (float*)w;  w += (size_t)NN * BB * 4;
    float* posv    = (float*)w;  w += (size_t)NN * 4;
    float* rowloss = (float*)w;  w += (size_t)NN * 4;
    float* colsum  = (float*)w;  w += (size_t)BB * 4;
    float* poscol  = (float*)w;  w += (size_t)BB * 4;

    ln_kernel<<<NN, 256, 0, stream>>>(text, tf, gamma, beta, qinv);
    ln_vis_kernel<<<BB * LP, 256, 0, stream>>>(vis, vt, gamma, beta);

    gram_kernel<<<1024, 256, 0, stream>>>(vt, G);
    main_kernel<<<1024, 256, 0, stream>>>(tf, vt, G, qinv, logits);

    loss_row_kernel<<<NN, 64, 0, stream>>>(logits, gm, logtemp, scaled, posv, rowloss);
    colsum_kernel<<<BB, 256, 0, stream>>>(scaled, gm, colsum, poscol);
    final_kernel<<<1, 1024, 0, stream>>>(posv, rowloss, colsum, poscol, gm, out);
}

// Round 10
// 202.767 us; speedup vs baseline: 1.3282x; 1.1935x over previous
//
#include <hip/hip_runtime.h>
#include <hip/hip_bf16.h>
#include <math.h>

#define NN 1024
#define BB 64
#define LL 197
#define LP 256
#define DD 768
#define PSTRIDE 260   // plds row stride in elements (256 + 4 pad)
#define VSTRB 80      // staged vt/tf LDS row stride in BYTES (64 data + 16 pad)

typedef __attribute__((ext_vector_type(8))) short short8;
typedef __attribute__((ext_vector_type(4))) float f32x4;

constexpr float LN_EPS = 1e-5f;
constexpr float NORM_EPS = 1e-12f;
constexpr float EPS = 1e-8f;

__device__ __forceinline__ float waveSum(float v) {
#pragma unroll
    for (int m = 32; m >= 1; m >>= 1) v += __shfl_xor(v, m, 64);
    return v;
}
__device__ __forceinline__ float grpSum(float v) {
#pragma unroll
    for (int m = 8; m >= 1; m >>= 1) v += __shfl_xor(v, m, 64);
    return v;
}
__device__ __forceinline__ float grpMax(float v) {
#pragma unroll
    for (int m = 8; m >= 1; m >>= 1) v = fmaxf(v, __shfl_xor(v, m, 64));
    return v;
}

__device__ __forceinline__ unsigned short f2bf(float f) {
    __hip_bfloat16 h = __float2bfloat16(f);
    return reinterpret_cast<unsigned short&>(h);
}

// Text LayerNorm -> bf16 + qinv = 1/max(||y||,eps)
__global__ __launch_bounds__(256) void ln_kernel(
    const float* __restrict__ x, __hip_bfloat16* __restrict__ y,
    const float* __restrict__ gamma, const float* __restrict__ beta,
    float* __restrict__ qinv) {
    const int row = blockIdx.x;
    const int tid = threadIdx.x;
    const float* xr = x + (size_t)row * DD;
    __hip_bfloat16* yr = y + (size_t)row * DD;

    float v[3];
    float s = 0.f, ss = 0.f;
#pragma unroll
    for (int c = 0; c < 3; c++) {
        float t = xr[tid + 256 * c];
        v[c] = t; s += t; ss += t * t;
    }
    __shared__ float red[8];
    s = waveSum(s); ss = waveSum(ss);
    const int w = tid >> 6;
    if ((tid & 63) == 0) { red[w] = s; red[4 + w] = ss; }
    __syncthreads();
    s = red[0] + red[1] + red[2] + red[3];
    ss = red[4] + red[5] + red[6] + red[7];
    const float mean = s * (1.f / DD);
    const float var = ss * (1.f / DD) - mean * mean;
    const float rs = rsqrtf(var + LN_EPS);

    float q = 0.f;
#pragma unroll
    for (int c = 0; c < 3; c++) {
        const int d = tid + 256 * c;
        float t = (v[c] - mean) * rs * gamma[d] + beta[d];
        __hip_bfloat16 hb = __float2bfloat16(t);
        yr[d] = hb;
        float tb = __bfloat162float(hb);
        q += tb * tb;
    }
    __syncthreads();
    q = waveSum(q);
    if ((tid & 63) == 0) red[w] = q;
    __syncthreads();
    if (tid == 0) {
        float n2 = red[0] + red[1] + red[2] + red[3];
        qinv[row] = 1.f / fmaxf(sqrtf(n2), NORM_EPS);
    }
}

// Vision LayerNorm into padded [B, LP, D]; XCD-swizzled: blockid ≡ b (mod 8).
__global__ __launch_bounds__(256) void ln_vis_kernel(
    const float* __restrict__ x, __hip_bfloat16* __restrict__ y,
    const float* __restrict__ gamma, const float* __restrict__ beta) {
    const int id = blockIdx.x;           // 0..BB*LP-1 (16384)
    const int xcd = id & 7;
    const int k = id >> 3;               // 0..2047
    const int bhi = k >> 8;              // 0..7
    const int l = k & 255;               // 0..255
    const int b = xcd + 8 * bhi;
    const int tid = threadIdx.x;
    __hip_bfloat16* yr = y + ((size_t)b * LP + l) * DD;
    if (l >= LL) {
#pragma unroll
        for (int c = 0; c < 3; c++) yr[tid + 256 * c] = __float2bfloat16(0.f);
        return;
    }
    const float* xr = x + ((size_t)b * LL + l) * DD;

    float v[3];
    float s = 0.f, ss = 0.f;
#pragma unroll
    for (int c = 0; c < 3; c++) {
        float t = xr[tid + 256 * c];
        v[c] = t; s += t; ss += t * t;
    }
    __shared__ float red[8];
    s = waveSum(s); ss = waveSum(ss);
    const int w = tid >> 6;
    if ((tid & 63) == 0) { red[w] = s; red[4 + w] = ss; }
    __syncthreads();
    s = red[0] + red[1] + red[2] + red[3];
    ss = red[4] + red[5] + red[6] + red[7];
    const float mean = s * (1.f / DD);
    const float var = ss * (1.f / DD) - mean * mean;
    const float rs = rsqrtf(var + LN_EPS);
#pragma unroll
    for (int c = 0; c < 3; c++) {
        const int d = tid + 256 * c;
        yr[d] = __float2bfloat16((v[c] - mean) * rs * gamma[d] + beta[d]);
    }
}

// G[b] = vt_b . vt_b^T [LP x LP] bf16. 1-D grid 1024, XCD-swizzled like main.
__global__ __launch_bounds__(256) void gram_kernel(
    const __hip_bfloat16* __restrict__ vt, __hip_bfloat16* __restrict__ G) {
    const int id = blockIdx.x;
    const int xcd = id & 7;
    const int k = id >> 3;               // 0..127
    const int bhi = k >> 4;              // 0..7
    const int rb = k & 15;               // 0..15
    const int b = xcd + 8 * bhi;
    const int tid = threadIdx.x, w = tid >> 6, lane = tid & 63;
    const short* vtb = (const short*)(vt + (size_t)b * LP * DD);
    const int kof = (lane >> 4) * 8;

    short8 a[24];
    const int arow = rb * 16 + (lane & 15);
#pragma unroll
    for (int ks = 0; ks < 24; ks++)
        a[ks] = *(const short8*)(vtb + (size_t)arow * DD + ks * 32 + kof);

#pragma unroll
    for (int cbi = 0; cbi < 4; cbi++) {
        const int cb = w + 4 * cbi;
        f32x4 c = {0.f, 0.f, 0.f, 0.f};
        const int brow = cb * 16 + (lane & 15);
#pragma unroll
        for (int ks = 0; ks < 24; ks++) {
            short8 bf = *(const short8*)(vtb + (size_t)brow * DD + ks * 32 + kof);
            c = __builtin_amdgcn_mfma_f32_16x16x32_bf16(a[ks], bf, c, 0, 0, 0);
        }
        __hip_bfloat16* Gb = G + ((size_t)b * LP + rb * 16) * LP + cb * 16;
        const int col = lane & 15, rg = (lane >> 4) * 4;
#pragma unroll
        for (int r = 0; r < 4; r++) Gb[(size_t)(rg + r) * LP + col] = __float2bfloat16(c[r]);
    }
}

// Fused main: S = tf.vt^T (LDS-staged, reg-prefetch double-buffer), softmax,
// num, T = P.G, den, logits. 1-D grid 1024 x 256 thr, XCD-swizzled.
// Wave w owns l-blocks {w, w+4, w+8, w+12}; LP=256 -> branch-free.
// LDS: staging vbuf[2][256][80B] @0 (40KB) + tbuf[2][64][80B] @40960 (10KB).
// After stage 1 the staging region is dead; plds[64][260]us @0 (33.3KB) +
// mx/sm/nm @33280 (3KB) overlay it.
__global__ __launch_bounds__(256, 3) void main_kernel(
    const __hip_bfloat16* __restrict__ tf, const __hip_bfloat16* __restrict__ vt,
    const __hip_bfloat16* __restrict__ G, const float* __restrict__ qinv,
    float* __restrict__ logits) {
    const int id = blockIdx.x;
    const int xcd = id & 7;
    const int kk = id >> 3;              // 0..127
    const int bhi = kk >> 4;             // 0..7
    const int nt = kk & 15;              // 0..15
    const int b = xcd + 8 * bhi;
    const int n0 = nt * 64;
    const int tid = threadIdx.x, w = tid >> 6, lane = tid & 63;
    const int g = lane >> 4, c = lane & 15;

    __shared__ __align__(16) unsigned char smem[51200];
    unsigned short* plds = (unsigned short*)smem;        // [64][PSTRIDE] (post-stage1)
    float* mx = (float*)(smem + 33280);                  // [64][4]
    float* sm = mx + 256;                                // [64][4]
    float* nm = sm + 256;                                // [64][4]

    const char* vtbc = (const char*)(vt + (size_t)b * LP * DD);
    const char* tfc = (const char*)(tf + (size_t)n0 * DD);
    const int trow = tid >> 2, tj = tid & 3;             // staging decomposition

    // ---- Stage 1: S = tf . vt^T, BK=32 LDS double-buffer, reg-staged ----
    f32x4 acc[4][4];  // [i = lb slot][nb]
#pragma unroll
    for (int i = 0; i < 4; i++)
#pragma unroll
        for (int nb = 0; nb < 4; nb++) acc[i][nb] = {0.f, 0.f, 0.f, 0.f};

    short8 rv[4], rt;
#define STAGE(ks)                                                               \
    {                                                                           \
        const int kb_ = (ks) * 64;                                              \
        _Pragma("unroll")                                                       \
        for (int q_ = 0; q_ < 4; q_++)                                          \
            rv[q_] = *(const short8*)(vtbc + (size_t)(trow + 64 * q_) * 1536 +  \
                                      kb_ + tj * 16);                           \
        rt = *(const short8*)(tfc + (size_t)trow * 1536 + kb_ + tj * 16);       \
    }
#define COMMIT(buf)                                                             \
    {                                                                           \
        _Pragma("unroll")                                                       \
        for (int q_ = 0; q_ < 4; q_++)                                          \
            *(short8*)(smem + (buf) * 20480 + (trow + 64 * q_) * VSTRB +        \
                       tj * 16) = rv[q_];                                       \
        *(short8*)(smem + 40960 + (buf) * 5120 + trow * VSTRB + tj * 16) = rt;  \
    }

    STAGE(0);
    COMMIT(0);
    STAGE(1);
    __syncthreads();

    for (int ks = 0; ks < 24; ks++) {
        const unsigned char* vb = smem + (ks & 1) * 20480;
        const unsigned char* tb = smem + 40960 + (ks & 1) * 5120;
        short8 af[4], bf[4];
#pragma unroll
        for (int nb = 0; nb < 4; nb++)
            af[nb] = *(const short8*)(tb + (nb * 16 + c) * VSTRB + g * 16);
#pragma unroll
        for (int i = 0; i < 4; i++)
            bf[i] = *(const short8*)(vb + ((w + 4 * i) * 16 + c) * VSTRB + g * 16);
#pragma unroll
        for (int i = 0; i < 4; i++)
#pragma unroll
            for (int nb = 0; nb < 4; nb++)
                acc[i][nb] = __builtin_amdgcn_mfma_f32_16x16x32_bf16(
                    af[nb], bf[i], acc[i][nb], 0, 0, 0);
        if (ks < 23) {
            COMMIT((ks + 1) & 1);     // waits on STAGE(ks+1) loads, writes other buffer
            if (ks < 22) STAGE(ks + 2);
        }
        __syncthreads();
    }
#undef STAGE
#undef COMMIT

    // ---- Stage 2: softmax over l (waves hold disjoint l-columns) ----
    const float inv_sqrtD = 0.0360843918f;
    float mp[4][4];
#pragma unroll
    for (int nb = 0; nb < 4; nb++)
#pragma unroll
        for (int r = 0; r < 4; r++) mp[nb][r] = -1e30f;
#pragma unroll
    for (int i = 0; i < 4; i++) {
        const int l = (w + 4 * i) * 16 + c;
        if (l < LL) {
#pragma unroll
            for (int nb = 0; nb < 4; nb++)
#pragma unroll
                for (int r = 0; r < 4; r++) mp[nb][r] = fmaxf(mp[nb][r], acc[i][nb][r]);
        }
    }
#pragma unroll
    for (int nb = 0; nb < 4; nb++)
#pragma unroll
        for (int r = 0; r < 4; r++) mp[nb][r] = grpMax(mp[nb][r]);
    if (c == 0) {
#pragma unroll
        for (int nb = 0; nb < 4; nb++)
#pragma unroll
            for (int r = 0; r < 4; r++) mx[(nb * 16 + g * 4 + r) * 4 + w] = mp[nb][r];
    }
    __syncthreads();
    float mf[4][4];
#pragma unroll
    for (int nb = 0; nb < 4; nb++)
#pragma unroll
        for (int r = 0; r < 4; r++) {
            const int row = nb * 16 + g * 4 + r;
            mf[nb][r] = fmaxf(fmaxf(mx[row * 4 + 0], mx[row * 4 + 1]),
                              fmaxf(mx[row * 4 + 2], mx[row * 4 + 3]));
        }

    float sp[4][4], np[4][4];
#pragma unroll
    for (int nb = 0; nb < 4; nb++)
#pragma unroll
        for (int r = 0; r < 4; r++) { sp[nb][r] = 0.f; np[nb][r] = 0.f; }
#pragma unroll
    for (int i = 0; i < 4; i++) {
        const int l = (w + 4 * i) * 16 + c;
#pragma unroll
        for (int nb = 0; nb < 4; nb++)
#pragma unroll
            for (int r = 0; r < 4; r++) {
                const float raw = acc[i][nb][r];
                const float p = (l < LL) ? __expf((raw - mf[nb][r]) * inv_sqrtD) : 0.f;
                acc[i][nb][r] = p;
                sp[nb][r] += p;
                np[nb][r] += p * raw;
            }
    }
#pragma unroll
    for (int nb = 0; nb < 4; nb++)
#pragma unroll
        for (int r = 0; r < 4; r++) { sp[nb][r] = grpSum(sp[nb][r]); np[nb][r] = grpSum(np[nb][r]); }
    if (c == 0) {
#pragma unroll
        for (int nb = 0; nb < 4; nb++)
#pragma unroll
            for (int r = 0; r < 4; r++) {
                const int row = nb * 16 + g * 4 + r;
                sm[row * 4 + w] = sp[nb][r];
                nm[row * 4 + w] = np[nb][r];
            }
    }
    __syncthreads();

    float invs[4][4];
#pragma unroll
    for (int nb = 0; nb < 4; nb++)
#pragma unroll
        for (int r = 0; r < 4; r++) {
            const int row = nb * 16 + g * 4 + r;
            const float ssum = sm[row * 4 + 0] + sm[row * 4 + 1] + sm[row * 4 + 2] + sm[row * 4 + 3];
            invs[nb][r] = 1.f / ssum;
        }

    // write normalized P (bf16) to plds [64][PSTRIDE]
#pragma unroll
    for (int i = 0; i < 4; i++) {
        const int lb = w + 4 * i;
#pragma unroll
        for (int nb = 0; nb < 4; nb++)
#pragma unroll
            for (int r = 0; r < 4; r++)
                plds[(size_t)(nb * 16 + g * 4 + r) * PSTRIDE + lb * 16 + c] =
                    f2bf(acc[i][nb][r] * invs[nb][r]);
    }
    __syncthreads();

    // ---- Stage 3: T = P.G (lb-outer, G rows direct from L2), den = sum P*T ----
    const short* Gb = (const short*)(G + (size_t)b * LP * LP);
    float den[4][4];
#pragma unroll
    for (int nb = 0; nb < 4; nb++)
#pragma unroll
        for (int r = 0; r < 4; r++) den[nb][r] = 0.f;

#pragma unroll
    for (int i = 0; i < 4; i++) {
        const int lb = w + 4 * i;
        short8 gbv[8];
#pragma unroll
        for (int kb = 0; kb < 8; kb++)
            gbv[kb] = *(const short8*)(Gb + (size_t)(lb * 16 + c) * LP + kb * 32 + g * 8);
#pragma unroll
        for (int nb = 0; nb < 4; nb++) {
            f32x4 t = {0.f, 0.f, 0.f, 0.f};
#pragma unroll
            for (int kb = 0; kb < 8; kb++) {
                short8 pa = *(const short8*)(plds + (size_t)(nb * 16 + c) * PSTRIDE + kb * 32 + g * 8);
                t = __builtin_amdgcn_mfma_f32_16x16x32_bf16(pa, gbv[kb], t, 0, 0, 0);
            }
#pragma unroll
            for (int r = 0; r < 4; r++)
                den[nb][r] += acc[i][nb][r] * invs[nb][r] * t[r];
        }
    }

    // cross-wave den reduce + epilogue
#pragma unroll
    for (int nb = 0; nb < 4; nb++)
#pragma unroll
        for (int r = 0; r < 4; r++) den[nb][r] = grpSum(den[nb][r]);
    __syncthreads();
    if (c == 0) {
#pragma unroll
        for (int nb = 0; nb < 4; nb++)
#pragma unroll
            for (int r = 0; r < 4; r++) mx[(nb * 16 + g * 4 + r) * 4 + w] = den[nb][r];
    }
    __syncthreads();
    if (tid < 64) {
        const int row = tid;
        const int n = n0 + row;
        const float dsum = mx[row * 4 + 0] + mx[row * 4 + 1] + mx[row * 4 + 2] + mx[row * 4 + 3];
        const float ssum = sm[row * 4 + 0] + sm[row * 4 + 1] + sm[row * 4 + 2] + sm[row * 4 + 3];
        const float nsum = nm[row * 4 + 0] + nm[row * 4 + 1] + nm[row * 4 + 2] + nm[row * 4 + 3];
        const float num = nsum / ssum;
        const float dn = fmaxf(sqrtf(fmaxf(dsum, 0.f)), NORM_EPS);
        logits[(size_t)n * BB + b] = num * qinv[n] / dn;
    }
}

__global__ __launch_bounds__(64) void loss_row_kernel(
    const float* __restrict__ logits, const int* __restrict__ gm,
    const float* __restrict__ logtemp, float* __restrict__ scaled,
    float* __restrict__ posv, float* __restrict__ rowloss) {
    const int n = blockIdx.x;
    const int b = threadIdx.x;
    const float invtemp = 1.f / expf(logtemp[0]);
    const float e = expf(logits[(size_t)n * BB + b] * invtemp);
    scaled[(size_t)n * BB + b] = e;
    const float sum = waveSum(e);
    const int g = gm[n];
    const float pos = __shfl(e, g, 64);
    if (b == 0) {
        posv[n] = pos;
        rowloss[n] = -logf(pos / (sum + EPS) + EPS);
    }
}

__global__ __launch_bounds__(256) void colsum_kernel(
    const float* __restrict__ scaled, const int* __restrict__ gm,
    float* __restrict__ colsum, float* __restrict__ poscol) {
    const int b = blockIdx.x;
    const int tid = threadIdx.x;
    float s = 0.f, p = 0.f;
    for (int n = tid; n < NN; n += 256) {
        const float e = scaled[(size_t)n * BB + b];
        s += e;
        if (gm[n] == b) p += e;
    }
    s = waveSum(s); p = waveSum(p);
    __shared__ float red[8];
    const int w = tid >> 6;
    if ((tid & 63) == 0) { red[w] = s; red[4 + w] = p; }
    __syncthreads();
    if (tid == 0) {
        colsum[b] = red[0] + red[1] + red[2] + red[3];
        poscol[b] = red[4] + red[5] + red[6] + red[7];
    }
}

__global__ __launch_bounds__(1024) void final_kernel(
    const float* __restrict__ posv, const float* __restrict__ rowloss,
    const float* __restrict__ colsum, const float* __restrict__ poscol,
    const int* __restrict__ gm, float* __restrict__ out) {
    const int n = threadIdx.x;
    const int g = gm[n];
    const float pos = posv[n];
    const float sum_neg = colsum[g] - poscol[g];
    const float cl = -logf(pos / (pos + sum_neg + EPS) + EPS);
    float v = rowloss[n] + cl;
    v = waveSum(v);
    __shared__ float red[16];
    if ((n & 63) == 0) red[n >> 6] = v;
    __syncthreads();
    if (n == 0) {
        float s = 0.f;
#pragma unroll
        for (int i = 0; i < 16; i++) s += red[i];
        out[0] = s / (2.f * NN);
    }
}

extern "C" void kernel_launch(void* const* d_in, const int* in_sizes, int n_in,
                              void* d_out, int out_size, void* d_ws, size_t ws_size,
                              hipStream_t stream) {
    const float* text = (const float*)d_in[0];
    const float* vis = (const float*)d_in[1];
    const int* gm = (const int*)d_in[2];
    const float* gamma = (const float*)d_in[3];
    const float* beta = (const float*)d_in[4];
    const float* logtemp = (const float*)d_in[5];
    float* out = (float*)d_out;

    char* w = (char*)d_ws;
    __hip_bfloat16* tf = (__hip_bfloat16*)w;             w += (size_t)NN * DD * 2;
    __hip_bfloat16* vt = (__hip_bfloat16*)w;             w += (size_t)BB * LP * DD * 2;
    __hip_bfloat16* G  = (__hip_bfloat16*)w;             w += (size_t)BB * LP * LP * 2;
    float* qinv    = (float*)w;  w += (size_t)NN * 4;
    float* logits  = (float*)w;  w += (size_t)NN * BB * 4;
    float* scaled  = (float*)w;  w += (size_t)NN * BB * 4;
    float* posv    = (float*)w;  w += (size_t)NN * 4;
    float* rowloss = (float*)w;  w += (size_t)NN * 4;
    float* colsum  = (float*)w;  w += (size_t)BB * 4;
    float* poscol  = (float*)w;  w += (size_t)BB * 4;

    ln_kernel<<<NN, 256, 0, stream>>>(text, tf, gamma, beta, qinv);
    ln_vis_kernel<<<BB * LP, 256, 0, stream>>>(vis, vt, gamma, beta);

    gram_kernel<<<1024, 256, 0, stream>>>(vt, G);
    main_kernel<<<1024, 256, 0, stream>>>(tf, vt, G, qinv, logits);

    loss_row_kernel<<<NN, 64, 0, stream>>>(logits, gm, logtemp, scaled, posv, rowloss);
    colsum_kernel<<<BB, 256, 0, stream>>>(scaled, gm, colsum, poscol);
    final_kernel<<<1, 1024, 0, stream>>>(posv, rowloss, colsum, poscol, gm, out);
}

// Round 11
// 176.865 us; speedup vs baseline: 1.5227x; 1.1464x over previous
//
#include <hip/hip_runtime.h>
#include <hip/hip_bf16.h>
#include <math.h>

#define NN 1024
#define BB 64
#define LL 197
#define LP 256
#define DD 768
#define VSTRB 80      // staged vt/tf LDS row stride in BYTES (64 data + 16 pad)

typedef __attribute__((ext_vector_type(8))) short short8;
typedef __attribute__((ext_vector_type(4))) float f32x4;

constexpr float LN_EPS = 1e-5f;
constexpr float NORM_EPS = 1e-12f;
constexpr float EPS = 1e-8f;

__device__ __forceinline__ float waveSum(float v) {
#pragma unroll
    for (int m = 32; m >= 1; m >>= 1) v += __shfl_xor(v, m, 64);
    return v;
}
__device__ __forceinline__ float grpSum(float v) {
#pragma unroll
    for (int m = 8; m >= 1; m >>= 1) v += __shfl_xor(v, m, 64);
    return v;
}
__device__ __forceinline__ float grpMax(float v) {
#pragma unroll
    for (int m = 8; m >= 1; m >>= 1) v = fmaxf(v, __shfl_xor(v, m, 64));
    return v;
}

__device__ __forceinline__ unsigned short f2bf(float f) {
    __hip_bfloat16 h = __float2bfloat16(f);
    return reinterpret_cast<unsigned short&>(h);
}
__device__ __forceinline__ float bf2f(unsigned short u) {
    unsigned int x = ((unsigned int)u) << 16;
    return reinterpret_cast<float&>(x);
}

// Text LayerNorm -> bf16 + qinv = 1/max(||y||,eps)
__global__ __launch_bounds__(256) void ln_kernel(
    const float* __restrict__ x, __hip_bfloat16* __restrict__ y,
    const float* __restrict__ gamma, const float* __restrict__ beta,
    float* __restrict__ qinv) {
    const int row = blockIdx.x;
    const int tid = threadIdx.x;
    const float* xr = x + (size_t)row * DD;
    __hip_bfloat16* yr = y + (size_t)row * DD;

    float v[3];
    float s = 0.f, ss = 0.f;
#pragma unroll
    for (int c = 0; c < 3; c++) {
        float t = xr[tid + 256 * c];
        v[c] = t; s += t; ss += t * t;
    }
    __shared__ float red[8];
    s = waveSum(s); ss = waveSum(ss);
    const int w = tid >> 6;
    if ((tid & 63) == 0) { red[w] = s; red[4 + w] = ss; }
    __syncthreads();
    s = red[0] + red[1] + red[2] + red[3];
    ss = red[4] + red[5] + red[6] + red[7];
    const float mean = s * (1.f / DD);
    const float var = ss * (1.f / DD) - mean * mean;
    const float rs = rsqrtf(var + LN_EPS);

    float q = 0.f;
#pragma unroll
    for (int c = 0; c < 3; c++) {
        const int d = tid + 256 * c;
        float t = (v[c] - mean) * rs * gamma[d] + beta[d];
        __hip_bfloat16 hb = __float2bfloat16(t);
        yr[d] = hb;
        float tb = __bfloat162float(hb);
        q += tb * tb;
    }
    __syncthreads();
    q = waveSum(q);
    if ((tid & 63) == 0) red[w] = q;
    __syncthreads();
    if (tid == 0) {
        float n2 = red[0] + red[1] + red[2] + red[3];
        qinv[row] = 1.f / fmaxf(sqrtf(n2), NORM_EPS);
    }
}

// Vision LayerNorm into padded [B, LP, D]; XCD-swizzled: blockid ≡ b (mod 8).
__global__ __launch_bounds__(256) void ln_vis_kernel(
    const float* __restrict__ x, __hip_bfloat16* __restrict__ y,
    const float* __restrict__ gamma, const float* __restrict__ beta) {
    const int id = blockIdx.x;           // 0..BB*LP-1 (16384)
    const int xcd = id & 7;
    const int k = id >> 3;               // 0..2047
    const int bhi = k >> 8;              // 0..7
    const int l = k & 255;               // 0..255
    const int b = xcd + 8 * bhi;
    const int tid = threadIdx.x;
    __hip_bfloat16* yr = y + ((size_t)b * LP + l) * DD;
    if (l >= LL) {
#pragma unroll
        for (int c = 0; c < 3; c++) yr[tid + 256 * c] = __float2bfloat16(0.f);
        return;
    }
    const float* xr = x + ((size_t)b * LL + l) * DD;

    float v[3];
    float s = 0.f, ss = 0.f;
#pragma unroll
    for (int c = 0; c < 3; c++) {
        float t = xr[tid + 256 * c];
        v[c] = t; s += t; ss += t * t;
    }
    __shared__ float red[8];
    s = waveSum(s); ss = waveSum(ss);
    const int w = tid >> 6;
    if ((tid & 63) == 0) { red[w] = s; red[4 + w] = ss; }
    __syncthreads();
    s = red[0] + red[1] + red[2] + red[3];
    ss = red[4] + red[5] + red[6] + red[7];
    const float mean = s * (1.f / DD);
    const float var = ss * (1.f / DD) - mean * mean;
    const float rs = rsqrtf(var + LN_EPS);
#pragma unroll
    for (int c = 0; c < 3; c++) {
        const int d = tid + 256 * c;
        yr[d] = __float2bfloat16((v[c] - mean) * rs * gamma[d] + beta[d]);
    }
}

// G[b] = vt_b . vt_b^T [LP x LP] bf16. 1-D grid 1024, XCD-swizzled like main.
__global__ __launch_bounds__(256) void gram_kernel(
    const __hip_bfloat16* __restrict__ vt, __hip_bfloat16* __restrict__ G) {
    const int id = blockIdx.x;
    const int xcd = id & 7;
    const int k = id >> 3;               // 0..127
    const int bhi = k >> 4;              // 0..7
    const int rb = k & 15;               // 0..15
    const int b = xcd + 8 * bhi;
    const int tid = threadIdx.x, w = tid >> 6, lane = tid & 63;
    const short* vtb = (const short*)(vt + (size_t)b * LP * DD);
    const int kof = (lane >> 4) * 8;

    short8 a[24];
    const int arow = rb * 16 + (lane & 15);
#pragma unroll
    for (int ks = 0; ks < 24; ks++)
        a[ks] = *(const short8*)(vtb + (size_t)arow * DD + ks * 32 + kof);

#pragma unroll
    for (int cbi = 0; cbi < 4; cbi++) {
        const int cb = w + 4 * cbi;
        f32x4 c = {0.f, 0.f, 0.f, 0.f};
        const int brow = cb * 16 + (lane & 15);
#pragma unroll
        for (int ks = 0; ks < 24; ks++) {
            short8 bf = *(const short8*)(vtb + (size_t)brow * DD + ks * 32 + kof);
            c = __builtin_amdgcn_mfma_f32_16x16x32_bf16(a[ks], bf, c, 0, 0, 0);
        }
        __hip_bfloat16* Gb = G + ((size_t)b * LP + rb * 16) * LP + cb * 16;
        const int col = lane & 15, rg = (lane >> 4) * 4;
#pragma unroll
        for (int r = 0; r < 4; r++) Gb[(size_t)(rg + r) * LP + col] = __float2bfloat16(c[r]);
    }
}

// score: S = tf.vt^T (LDS-staged dbuf), softmax, num -> Pbuf (bf16 normalized P)
// + numq = (num/ssum)*qinv. 1-D grid 1024 x 256 thr, XCD-swizzled.
__global__ __launch_bounds__(256, 3) void score_kernel(
    const __hip_bfloat16* __restrict__ tf, const __hip_bfloat16* __restrict__ vt,
    const float* __restrict__ qinv, __hip_bfloat16* __restrict__ Pbuf,
    float* __restrict__ numq) {
    const int id = blockIdx.x;
    const int xcd = id & 7;
    const int kk = id >> 3;              // 0..127
    const int bhi = kk >> 4;             // 0..7
    const int nt = kk & 15;              // 0..15
    const int b = xcd + 8 * bhi;
    const int n0 = nt * 64;
    const int tid = threadIdx.x, w = tid >> 6, lane = tid & 63;
    const int g = lane >> 4, c = lane & 15;

    __shared__ __align__(16) unsigned char smem[51200];
    float* mx = (float*)(smem + 33280);                  // [64][4] (overlay, post-stage1)
    float* sm = mx + 256;                                // [64][4]
    float* nm = sm + 256;                                // [64][4]

    const char* vtbc = (const char*)(vt + (size_t)b * LP * DD);
    const char* tfc = (const char*)(tf + (size_t)n0 * DD);
    const int trow = tid >> 2, tj = tid & 3;

    // ---- Stage 1: S = tf . vt^T, BK=32 LDS double-buffer, reg-staged ----
    f32x4 acc[4][4];  // [i = lb slot][nb]
#pragma unroll
    for (int i = 0; i < 4; i++)
#pragma unroll
        for (int nb = 0; nb < 4; nb++) acc[i][nb] = {0.f, 0.f, 0.f, 0.f};

    short8 rv[4], rt;
#define STAGE(ks)                                                               \
    {                                                                           \
        const int kb_ = (ks) * 64;                                              \
        _Pragma("unroll")                                                       \
        for (int q_ = 0; q_ < 4; q_++)                                          \
            rv[q_] = *(const short8*)(vtbc + (size_t)(trow + 64 * q_) * 1536 +  \
                                      kb_ + tj * 16);                           \
        rt = *(const short8*)(tfc + (size_t)trow * 1536 + kb_ + tj * 16);       \
    }
#define COMMIT(buf)                                                             \
    {                                                                           \
        _Pragma("unroll")                                                       \
        for (int q_ = 0; q_ < 4; q_++)                                          \
            *(short8*)(smem + (buf) * 20480 + (trow + 64 * q_) * VSTRB +        \
                       tj * 16) = rv[q_];                                       \
        *(short8*)(smem + 40960 + (buf) * 5120 + trow * VSTRB + tj * 16) = rt;  \
    }

    STAGE(0);
    COMMIT(0);
    STAGE(1);
    __syncthreads();

    for (int ks = 0; ks < 24; ks++) {
        const unsigned char* vb = smem + (ks & 1) * 20480;
        const unsigned char* tb = smem + 40960 + (ks & 1) * 5120;
        short8 af[4], bf[4];
#pragma unroll
        for (int nb = 0; nb < 4; nb++)
            af[nb] = *(const short8*)(tb + (nb * 16 + c) * VSTRB + g * 16);
#pragma unroll
        for (int i = 0; i < 4; i++)
            bf[i] = *(const short8*)(vb + ((w + 4 * i) * 16 + c) * VSTRB + g * 16);
#pragma unroll
        for (int i = 0; i < 4; i++)
#pragma unroll
            for (int nb = 0; nb < 4; nb++)
                acc[i][nb] = __builtin_amdgcn_mfma_f32_16x16x32_bf16(
                    af[nb], bf[i], acc[i][nb], 0, 0, 0);
        if (ks < 23) {
            COMMIT((ks + 1) & 1);
            if (ks < 22) STAGE(ks + 2);
        }
        __syncthreads();
    }
#undef STAGE
#undef COMMIT

    // ---- Stage 2: softmax over l (waves hold disjoint l-columns) ----
    const float inv_sqrtD = 0.0360843918f;
    float mp[4][4];
#pragma unroll
    for (int nb = 0; nb < 4; nb++)
#pragma unroll
        for (int r = 0; r < 4; r++) mp[nb][r] = -1e30f;
#pragma unroll
    for (int i = 0; i < 4; i++) {
        const int l = (w + 4 * i) * 16 + c;
        if (l < LL) {
#pragma unroll
            for (int nb = 0; nb < 4; nb++)
#pragma unroll
                for (int r = 0; r < 4; r++) mp[nb][r] = fmaxf(mp[nb][r], acc[i][nb][r]);
        }
    }
#pragma unroll
    for (int nb = 0; nb < 4; nb++)
#pragma unroll
        for (int r = 0; r < 4; r++) mp[nb][r] = grpMax(mp[nb][r]);
    if (c == 0) {
#pragma unroll
        for (int nb = 0; nb < 4; nb++)
#pragma unroll
            for (int r = 0; r < 4; r++) mx[(nb * 16 + g * 4 + r) * 4 + w] = mp[nb][r];
    }
    __syncthreads();
    float mf[4][4];
#pragma unroll
    for (int nb = 0; nb < 4; nb++)
#pragma unroll
        for (int r = 0; r < 4; r++) {
            const int row = nb * 16 + g * 4 + r;
            mf[nb][r] = fmaxf(fmaxf(mx[row * 4 + 0], mx[row * 4 + 1]),
                              fmaxf(mx[row * 4 + 2], mx[row * 4 + 3]));
        }

    float sp[4][4], np[4][4];
#pragma unroll
    for (int nb = 0; nb < 4; nb++)
#pragma unroll
        for (int r = 0; r < 4; r++) { sp[nb][r] = 0.f; np[nb][r] = 0.f; }
#pragma unroll
    for (int i = 0; i < 4; i++) {
        const int l = (w + 4 * i) * 16 + c;
#pragma unroll
        for (int nb = 0; nb < 4; nb++)
#pragma unroll
            for (int r = 0; r < 4; r++) {
                const float raw = acc[i][nb][r];
                const float p = (l < LL) ? __expf((raw - mf[nb][r]) * inv_sqrtD) : 0.f;
                acc[i][nb][r] = p;
                sp[nb][r] += p;
                np[nb][r] += p * raw;
            }
    }
#pragma unroll
    for (int nb = 0; nb < 4; nb++)
#pragma unroll
        for (int r = 0; r < 4; r++) { sp[nb][r] = grpSum(sp[nb][r]); np[nb][r] = grpSum(np[nb][r]); }
    if (c == 0) {
#pragma unroll
        for (int nb = 0; nb < 4; nb++)
#pragma unroll
            for (int r = 0; r < 4; r++) {
                const int row = nb * 16 + g * 4 + r;
                sm[row * 4 + w] = sp[nb][r];
                nm[row * 4 + w] = np[nb][r];
            }
    }
    __syncthreads();

    float invs[4][4];
#pragma unroll
    for (int nb = 0; nb < 4; nb++)
#pragma unroll
        for (int r = 0; r < 4; r++) {
            const int row = nb * 16 + g * 4 + r;
            const float ssum = sm[row * 4 + 0] + sm[row * 4 + 1] + sm[row * 4 + 2] + sm[row * 4 + 3];
            invs[nb][r] = 1.f / ssum;
        }

    // write normalized P (bf16) to global Pbuf [B][NN][LP]
    __hip_bfloat16* Pb = Pbuf + ((size_t)b * NN + n0) * LP;
#pragma unroll
    for (int i = 0; i < 4; i++) {
        const int lb = w + 4 * i;
#pragma unroll
        for (int nb = 0; nb < 4; nb++)
#pragma unroll
            for (int r = 0; r < 4; r++)
                Pb[(size_t)(nb * 16 + g * 4 + r) * LP + lb * 16 + c] =
                    __float2bfloat16(acc[i][nb][r] * invs[nb][r]);
    }

    if (tid < 64) {
        const int row = tid;
        const int n = n0 + row;
        const float ssum = sm[row * 4 + 0] + sm[row * 4 + 1] + sm[row * 4 + 2] + sm[row * 4 + 3];
        const float nsum = nm[row * 4 + 0] + nm[row * 4 + 1] + nm[row * 4 + 2] + nm[row * 4 + 3];
        numq[(size_t)n * BB + b] = (nsum / ssum) * qinv[n];
    }
}

// den: T = P.G, den = sum P*T, logits = numq / ||agg||. Light registers.
__global__ __launch_bounds__(256, 4) void den_kernel(
    const __hip_bfloat16* __restrict__ Pbuf, const __hip_bfloat16* __restrict__ G,
    const float* __restrict__ numq, float* __restrict__ logits) {
    const int id = blockIdx.x;
    const int xcd = id & 7;
    const int kk = id >> 3;
    const int bhi = kk >> 4;
    const int nt = kk & 15;
    const int b = xcd + 8 * bhi;
    const int n0 = nt * 64;
    const int tid = threadIdx.x, w = tid >> 6, lane = tid & 63;
    const int g = lane >> 4, c = lane & 15;

    __shared__ float mx[64 * 4];

    const short* Pb = (const short*)(Pbuf + ((size_t)b * NN + n0) * LP);
    const short* Gb = (const short*)(G + (size_t)b * LP * LP);

    float den[4][4];
#pragma unroll
    for (int nb = 0; nb < 4; nb++)
#pragma unroll
        for (int r = 0; r < 4; r++) den[nb][r] = 0.f;

#pragma unroll
    for (int i = 0; i < 4; i++) {
        const int lb = w + 4 * i;
        short8 gbv[8];
#pragma unroll
        for (int kb = 0; kb < 8; kb++)
            gbv[kb] = *(const short8*)(Gb + (size_t)(lb * 16 + c) * LP + kb * 32 + g * 8);
#pragma unroll
        for (int nb = 0; nb < 4; nb++) {
            f32x4 t = {0.f, 0.f, 0.f, 0.f};
#pragma unroll
            for (int kb = 0; kb < 8; kb++) {
                short8 pa = *(const short8*)(Pb + (size_t)(nb * 16 + c) * LP + kb * 32 + g * 8);
                t = __builtin_amdgcn_mfma_f32_16x16x32_bf16(pa, gbv[kb], t, 0, 0, 0);
            }
#pragma unroll
            for (int r = 0; r < 4; r++) {
                const float P = bf2f((unsigned short)Pb[(size_t)(nb * 16 + g * 4 + r) * LP + lb * 16 + c]);
                den[nb][r] += P * t[r];
            }
        }
    }

#pragma unroll
    for (int nb = 0; nb < 4; nb++)
#pragma unroll
        for (int r = 0; r < 4; r++) den[nb][r] = grpSum(den[nb][r]);
    if (c == 0) {
#pragma unroll
        for (int nb = 0; nb < 4; nb++)
#pragma unroll
            for (int r = 0; r < 4; r++) mx[(nb * 16 + g * 4 + r) * 4 + w] = den[nb][r];
    }
    __syncthreads();
    if (tid < 64) {
        const int row = tid;
        const int n = n0 + row;
        const float dsum = mx[row * 4 + 0] + mx[row * 4 + 1] + mx[row * 4 + 2] + mx[row * 4 + 3];
        const float dn = fmaxf(sqrtf(fmaxf(dsum, 0.f)), NORM_EPS);
        logits[(size_t)n * BB + b] = numq[(size_t)n * BB + b] / dn;
    }
}

__global__ __launch_bounds__(64) void loss_row_kernel(
    const float* __restrict__ logits, const int* __restrict__ gm,
    const float* __restrict__ logtemp, float* __restrict__ scaled,
    float* __restrict__ posv, float* __restrict__ rowloss) {
    const int n = blockIdx.x;
    const int b = threadIdx.x;
    const float invtemp = 1.f / expf(logtemp[0]);
    const float e = expf(logits[(size_t)n * BB + b] * invtemp);
    scaled[(size_t)n * BB + b] = e;
    const float sum = waveSum(e);
    const int g = gm[n];
    const float pos = __shfl(e, g, 64);
    if (b == 0) {
        posv[n] = pos;
        rowloss[n] = -logf(pos / (sum + EPS) + EPS);
    }
}

__global__ __launch_bounds__(256) void colsum_kernel(
    const float* __restrict__ scaled, const int* __restrict__ gm,
    float* __restrict__ colsum, float* __restrict__ poscol) {
    const int b = blockIdx.x;
    const int tid = threadIdx.x;
    float s = 0.f, p = 0.f;
    for (int n = tid; n < NN; n += 256) {
        const float e = scaled[(size_t)n * BB + b];
        s += e;
        if (gm[n] == b) p += e;
    }
    s = waveSum(s); p = waveSum(p);
    __shared__ float red[8];
    const int w = tid >> 6;
    if ((tid & 63) == 0) { red[w] = s; red[4 + w] = p; }
    __syncthreads();
    if (tid == 0) {
        colsum[b] = red[0] + red[1] + red[2] + red[3];
        poscol[b] = red[4] + red[5] + red[6] + red[7];
    }
}

__global__ __launch_bounds__(1024) void final_kernel(
    const float* __restrict__ posv, const float* __restrict__ rowloss,
    const float* __restrict__ colsum, const float* __restrict__ poscol,
    const int* __restrict__ gm, float* __restrict__ out) {
    const int n = threadIdx.x;
    const int g = gm[n];
    const float pos = posv[n];
    const float sum_neg = colsum[g] - poscol[g];
    const float cl = -logf(pos / (pos + sum_neg + EPS) + EPS);
    float v = rowloss[n] + cl;
    v = waveSum(v);
    __shared__ float red[16];
    if ((n & 63) == 0) red[n >> 6] = v;
    __syncthreads();
    if (n == 0) {
        float s = 0.f;
#pragma unroll
        for (int i = 0; i < 16; i++) s += red[i];
        out[0] = s / (2.f * NN);
    }
}

extern "C" void kernel_launch(void* const* d_in, const int* in_sizes, int n_in,
                              void* d_out, int out_size, void* d_ws, size_t ws_size,
                              hipStream_t stream) {
    const float* text = (const float*)d_in[0];
    const float* vis = (const float*)d_in[1];
    const int* gm = (const int*)d_in[2];
    const float* gamma = (const float*)d_in[3];
    const float* beta = (const float*)d_in[4];
    const float* logtemp = (const float*)d_in[5];
    float* out = (float*)d_out;

    char* w = (char*)d_ws;
    __hip_bfloat16* tf = (__hip_bfloat16*)w;             w += (size_t)NN * DD * 2;
    __hip_bfloat16* vt = (__hip_bfloat16*)w;             w += (size_t)BB * LP * DD * 2;
    __hip_bfloat16* G  = (__hip_bfloat16*)w;             w += (size_t)BB * LP * LP * 2;
    __hip_bfloat16* Pbuf = (__hip_bfloat16*)w;           w += (size_t)BB * NN * LP * 2;
    float* qinv    = (float*)w;  w += (size_t)NN * 4;
    float* numq    = (float*)w;  w += (size_t)NN * BB * 4;
    float* logits  = (float*)w;  w += (size_t)NN * BB * 4;
    float* scaled  = (float*)w;  w += (size_t)NN * BB * 4;
    float* posv    = (float*)w;  w += (size_t)NN * 4;
    float* rowloss = (float*)w;  w += (size_t)NN * 4;
    float* colsum  = (float*)w;  w += (size_t)BB * 4;
    float* poscol  = (float*)w;  w += (size_t)BB * 4;

    ln_kernel<<<NN, 256, 0, stream>>>(text, tf, gamma, beta, qinv);
    ln_vis_kernel<<<BB * LP, 256, 0, stream>>>(vis, vt, gamma, beta);

    gram_kernel<<<1024, 256, 0, stream>>>(vt, G);
    score_kernel<<<1024, 256, 0, stream>>>(tf, vt, qinv, Pbuf, numq);
    den_kernel<<<1024, 256, 0, stream>>>(Pbuf, G, numq, logits);

    loss_row_kernel<<<NN, 64, 0, stream>>>(logits, gm, logtemp, scaled, posv, rowloss);
    colsum_kernel<<<BB, 256, 0, stream>>>(scaled, gm, colsum, poscol);
    final_kernel<<<1, 1024, 0, stream>>>(posv, rowloss, colsum, poscol, gm, out);
}

// Round 12
// 131.159 us; speedup vs baseline: 2.0533x; 1.3485x over previous
//
#include <hip/hip_runtime.h>
#include <hip/hip_bf16.h>
#include <math.h>

#define NN 1024
#define BB 64
#define LL 197
#define LP 256
#define DD 768

typedef __attribute__((ext_vector_type(8))) short short8;
typedef __attribute__((ext_vector_type(4))) float f32x4;

constexpr float LN_EPS = 1e-5f;
constexpr float NORM_EPS = 1e-12f;
constexpr float EPS = 1e-8f;

__device__ __forceinline__ float waveSum(float v) {
#pragma unroll
    for (int m = 32; m >= 1; m >>= 1) v += __shfl_xor(v, m, 64);
    return v;
}
__device__ __forceinline__ float grpSum(float v) {
#pragma unroll
    for (int m = 8; m >= 1; m >>= 1) v += __shfl_xor(v, m, 64);
    return v;
}
__device__ __forceinline__ float grpMax(float v) {
#pragma unroll
    for (int m = 8; m >= 1; m >>= 1) v = fmaxf(v, __shfl_xor(v, m, 64));
    return v;
}

__device__ __forceinline__ float bf2f(unsigned short u) {
    unsigned int x = ((unsigned int)u) << 16;
    return reinterpret_cast<float&>(x);
}

__device__ __forceinline__ void gl_lds16(const void* g, void* l) {
    __builtin_amdgcn_global_load_lds(
        (const __attribute__((address_space(1))) unsigned int*)g,
        (__attribute__((address_space(3))) unsigned int*)l, 16, 0, 0);
}

// Text LayerNorm -> bf16 + qinv = 1/max(||y||,eps)
__global__ __launch_bounds__(256) void ln_kernel(
    const float* __restrict__ x, __hip_bfloat16* __restrict__ y,
    const float* __restrict__ gamma, const float* __restrict__ beta,
    float* __restrict__ qinv) {
    const int row = blockIdx.x;
    const int tid = threadIdx.x;
    const float* xr = x + (size_t)row * DD;
    __hip_bfloat16* yr = y + (size_t)row * DD;

    float v[3];
    float s = 0.f, ss = 0.f;
#pragma unroll
    for (int c = 0; c < 3; c++) {
        float t = xr[tid + 256 * c];
        v[c] = t; s += t; ss += t * t;
    }
    __shared__ float red[8];
    s = waveSum(s); ss = waveSum(ss);
    const int w = tid >> 6;
    if ((tid & 63) == 0) { red[w] = s; red[4 + w] = ss; }
    __syncthreads();
    s = red[0] + red[1] + red[2] + red[3];
    ss = red[4] + red[5] + red[6] + red[7];
    const float mean = s * (1.f / DD);
    const float var = ss * (1.f / DD) - mean * mean;
    const float rs = rsqrtf(var + LN_EPS);

    float q = 0.f;
#pragma unroll
    for (int c = 0; c < 3; c++) {
        const int d = tid + 256 * c;
        float t = (v[c] - mean) * rs * gamma[d] + beta[d];
        __hip_bfloat16 hb = __float2bfloat16(t);
        yr[d] = hb;
        float tb = __bfloat162float(hb);
        q += tb * tb;
    }
    __syncthreads();
    q = waveSum(q);
    if ((tid & 63) == 0) red[w] = q;
    __syncthreads();
    if (tid == 0) {
        float n2 = red[0] + red[1] + red[2] + red[3];
        qinv[row] = 1.f / fmaxf(sqrtf(n2), NORM_EPS);
    }
}

// Vision LayerNorm into padded [B, LP, D]; XCD-swizzled: blockid ≡ b (mod 8).
__global__ __launch_bounds__(256) void ln_vis_kernel(
    const float* __restrict__ x, __hip_bfloat16* __restrict__ y,
    const float* __restrict__ gamma, const float* __restrict__ beta) {
    const int id = blockIdx.x;           // 0..BB*LP-1 (16384)
    const int xcd = id & 7;
    const int k = id >> 3;               // 0..2047
    const int bhi = k >> 8;              // 0..7
    const int l = k & 255;               // 0..255
    const int b = xcd + 8 * bhi;
    const int tid = threadIdx.x;
    __hip_bfloat16* yr = y + ((size_t)b * LP + l) * DD;
    if (l >= LL) {
#pragma unroll
        for (int c = 0; c < 3; c++) yr[tid + 256 * c] = __float2bfloat16(0.f);
        return;
    }
    const float* xr = x + ((size_t)b * LL + l) * DD;

    float v[3];
    float s = 0.f, ss = 0.f;
#pragma unroll
    for (int c = 0; c < 3; c++) {
        float t = xr[tid + 256 * c];
        v[c] = t; s += t; ss += t * t;
    }
    __shared__ float red[8];
    s = waveSum(s); ss = waveSum(ss);
    const int w = tid >> 6;
    if ((tid & 63) == 0) { red[w] = s; red[4 + w] = ss; }
    __syncthreads();
    s = red[0] + red[1] + red[2] + red[3];
    ss = red[4] + red[5] + red[6] + red[7];
    const float mean = s * (1.f / DD);
    const float var = ss * (1.f / DD) - mean * mean;
    const float rs = rsqrtf(var + LN_EPS);
#pragma unroll
    for (int c = 0; c < 3; c++) {
        const int d = tid + 256 * c;
        yr[d] = __float2bfloat16((v[c] - mean) * rs * gamma[d] + beta[d]);
    }
}

// Gram: G[b] = vt_b . vt_b^T, LDS-staged via global_load_lds.
// Grid 512: 8 row-blocks of 32 x 64 b, XCD-swizzled.
// LDS: vbuf 2x16KB @0 (all 256 vt rows, BK=32) + tbuf 2x2KB @32768 (32 A-rows).
__global__ __launch_bounds__(256, 4) void gram_kernel(
    const __hip_bfloat16* __restrict__ vt, __hip_bfloat16* __restrict__ G) {
    const int id = blockIdx.x;           // 0..511
    const int xcd = id & 7;
    const int k = id >> 3;               // 0..63
    const int bhi = k >> 3;              // 0..7
    const int rb = k & 7;                // 0..7
    const int b = xcd + 8 * bhi;
    const int n0 = rb * 32;
    const int tid = threadIdx.x, w = tid >> 6, lane = tid & 63;
    const int g = lane >> 4, c = lane & 15;

    __shared__ __align__(16) unsigned char smem[36864];
    const char* vtbc = (const char*)(vt + (size_t)b * LP * DD);

#define GSTAGE(ks, bsel)                                                        \
    {                                                                           \
        const int kb_ = (ks) * 64;                                              \
        _Pragma("unroll")                                                       \
        for (int q_ = 0; q_ < 4; q_++) {                                        \
            const int off_ = q_ * 4096 + tid * 16;                              \
            gl_lds16(vtbc + (size_t)(off_ >> 6) * 1536 + kb_ + (off_ & 63),     \
                     smem + (bsel) * 16384 + q_ * 4096 + w * 1024);             \
        }                                                                       \
        if (w < 2) {                                                            \
            const int off_ = tid * 16;                                          \
            gl_lds16(vtbc + (size_t)(n0 + (off_ >> 6)) * 1536 + kb_ + (off_ & 63), \
                     smem + 32768 + (bsel) * 2048 + w * 1024);                  \
        }                                                                       \
    }

    f32x4 acc[4][2];  // [i = col-block slot][nb row-block]
#pragma unroll
    for (int i = 0; i < 4; i++)
#pragma unroll
        for (int nb = 0; nb < 2; nb++) acc[i][nb] = {0.f, 0.f, 0.f, 0.f};

    GSTAGE(0, 0);
    asm volatile("s_waitcnt vmcnt(0)" ::: "memory");
    __syncthreads();

    for (int ks = 0; ks < 24; ks++) {
        const int cur = ks & 1;
        if (ks < 23) GSTAGE(ks + 1, cur ^ 1);
        const unsigned char* vb = smem + cur * 16384;
        const unsigned char* tb = smem + 32768 + cur * 2048;
        short8 af[2], bf[4];
#pragma unroll
        for (int nb = 0; nb < 2; nb++)
            af[nb] = *(const short8*)(tb + (nb * 16 + c) * 64 + g * 16);
#pragma unroll
        for (int i = 0; i < 4; i++)
            bf[i] = *(const short8*)(vb + ((w + 4 * i) * 16 + c) * 64 + g * 16);
#pragma unroll
        for (int i = 0; i < 4; i++)
#pragma unroll
            for (int nb = 0; nb < 2; nb++)
                acc[i][nb] = __builtin_amdgcn_mfma_f32_16x16x32_bf16(
                    af[nb], bf[i], acc[i][nb], 0, 0, 0);
        asm volatile("s_waitcnt vmcnt(0)" ::: "memory");
        __syncthreads();
    }
#undef GSTAGE

    __hip_bfloat16* Gb = G + (size_t)b * LP * LP;
#pragma unroll
    for (int i = 0; i < 4; i++) {
        const int col = (w + 4 * i) * 16 + c;
#pragma unroll
        for (int nb = 0; nb < 2; nb++)
#pragma unroll
            for (int r = 0; r < 4; r++)
                Gb[(size_t)(n0 + nb * 16 + g * 4 + r) * LP + col] =
                    __float2bfloat16(acc[i][nb][r]);
    }
}

// score: S = tf.vt^T (global_load_lds staged dbuf), softmax, num ->
// Pbuf (bf16 normalized P) + numq = (num/ssum)*qinv. Grid 1024, XCD-swizzled.
// LDS 40960: vbuf 2x16KB @0, tbuf 2x4KB @32768; mx/sm/nm overlay @0 post-stage1.
__global__ __launch_bounds__(256, 4) void score_kernel(
    const __hip_bfloat16* __restrict__ tf, const __hip_bfloat16* __restrict__ vt,
    const float* __restrict__ qinv, __hip_bfloat16* __restrict__ Pbuf,
    float* __restrict__ numq) {
    const int id = blockIdx.x;
    const int xcd = id & 7;
    const int kk = id >> 3;              // 0..127
    const int bhi = kk >> 4;             // 0..7
    const int nt = kk & 15;              // 0..15
    const int b = xcd + 8 * bhi;
    const int n0 = nt * 64;
    const int tid = threadIdx.x, w = tid >> 6, lane = tid & 63;
    const int g = lane >> 4, c = lane & 15;

    __shared__ __align__(16) unsigned char smem[40960];
    float* mx = (float*)smem;            // [64][4] overlay (post-stage1)
    float* sm = mx + 256;
    float* nm = sm + 256;

    const char* vtbc = (const char*)(vt + (size_t)b * LP * DD);
    const char* tfc = (const char*)(tf + (size_t)n0 * DD);

#define SSTAGE(ks, bsel)                                                        \
    {                                                                           \
        const int kb_ = (ks) * 64;                                              \
        _Pragma("unroll")                                                       \
        for (int q_ = 0; q_ < 4; q_++) {                                        \
            const int off_ = q_ * 4096 + tid * 16;                              \
            gl_lds16(vtbc + (size_t)(off_ >> 6) * 1536 + kb_ + (off_ & 63),     \
                     smem + (bsel) * 16384 + q_ * 4096 + w * 1024);             \
        }                                                                       \
        {                                                                       \
            const int off_ = tid * 16;                                          \
            gl_lds16(tfc + (size_t)(off_ >> 6) * 1536 + kb_ + (off_ & 63),      \
                     smem + 32768 + (bsel) * 4096 + w * 1024);                  \
        }                                                                       \
    }

    f32x4 acc[4][4];  // [i = lb slot][nb]
#pragma unroll
    for (int i = 0; i < 4; i++)
#pragma unroll
        for (int nb = 0; nb < 4; nb++) acc[i][nb] = {0.f, 0.f, 0.f, 0.f};

    SSTAGE(0, 0);
    asm volatile("s_waitcnt vmcnt(0)" ::: "memory");
    __syncthreads();

    for (int ks = 0; ks < 24; ks++) {
        const int cur = ks & 1;
        if (ks < 23) SSTAGE(ks + 1, cur ^ 1);
        const unsigned char* vb = smem + cur * 16384;
        const unsigned char* tb = smem + 32768 + cur * 4096;
        short8 af[4], bf[4];
#pragma unroll
        for (int nb = 0; nb < 4; nb++)
            af[nb] = *(const short8*)(tb + (nb * 16 + c) * 64 + g * 16);
#pragma unroll
        for (int i = 0; i < 4; i++)
            bf[i] = *(const short8*)(vb + ((w + 4 * i) * 16 + c) * 64 + g * 16);
#pragma unroll
        for (int i = 0; i < 4; i++)
#pragma unroll
            for (int nb = 0; nb < 4; nb++)
                acc[i][nb] = __builtin_amdgcn_mfma_f32_16x16x32_bf16(
                    af[nb], bf[i], acc[i][nb], 0, 0, 0);
        asm volatile("s_waitcnt vmcnt(0)" ::: "memory");
        __syncthreads();
    }
#undef SSTAGE

    // ---- softmax over l (waves hold disjoint l-columns) ----
    const float inv_sqrtD = 0.0360843918f;
    float mp[4][4];
#pragma unroll
    for (int nb = 0; nb < 4; nb++)
#pragma unroll
        for (int r = 0; r < 4; r++) mp[nb][r] = -1e30f;
#pragma unroll
    for (int i = 0; i < 4; i++) {
        const int l = (w + 4 * i) * 16 + c;
        if (l < LL) {
#pragma unroll
            for (int nb = 0; nb < 4; nb++)
#pragma unroll
                for (int r = 0; r < 4; r++) mp[nb][r] = fmaxf(mp[nb][r], acc[i][nb][r]);
        }
    }
#pragma unroll
    for (int nb = 0; nb < 4; nb++)
#pragma unroll
        for (int r = 0; r < 4; r++) mp[nb][r] = grpMax(mp[nb][r]);
    if (c == 0) {
#pragma unroll
        for (int nb = 0; nb < 4; nb++)
#pragma unroll
            for (int r = 0; r < 4; r++) mx[(nb * 16 + g * 4 + r) * 4 + w] = mp[nb][r];
    }
    __syncthreads();
    float mf[4][4];
#pragma unroll
    for (int nb = 0; nb < 4; nb++)
#pragma unroll
        for (int r = 0; r < 4; r++) {
            const int row = nb * 16 + g * 4 + r;
            mf[nb][r] = fmaxf(fmaxf(mx[row * 4 + 0], mx[row * 4 + 1]),
                              fmaxf(mx[row * 4 + 2], mx[row * 4 + 3]));
        }

    float sp[4][4], np[4][4];
#pragma unroll
    for (int nb = 0; nb < 4; nb++)
#pragma unroll
        for (int r = 0; r < 4; r++) { sp[nb][r] = 0.f; np[nb][r] = 0.f; }
#pragma unroll
    for (int i = 0; i < 4; i++) {
        const int l = (w + 4 * i) * 16 + c;
#pragma unroll
        for (int nb = 0; nb < 4; nb++)
#pragma unroll
            for (int r = 0; r < 4; r++) {
                const float raw = acc[i][nb][r];
                const float p = (l < LL) ? __expf((raw - mf[nb][r]) * inv_sqrtD) : 0.f;
                acc[i][nb][r] = p;
                sp[nb][r] += p;
                np[nb][r] += p * raw;
            }
    }
#pragma unroll
    for (int nb = 0; nb < 4; nb++)
#pragma unroll
        for (int r = 0; r < 4; r++) { sp[nb][r] = grpSum(sp[nb][r]); np[nb][r] = grpSum(np[nb][r]); }
    if (c == 0) {
#pragma unroll
        for (int nb = 0; nb < 4; nb++)
#pragma unroll
            for (int r = 0; r < 4; r++) {
                const int row = nb * 16 + g * 4 + r;
                sm[row * 4 + w] = sp[nb][r];
                nm[row * 4 + w] = np[nb][r];
            }
    }
    __syncthreads();

    float invs[4][4];
#pragma unroll
    for (int nb = 0; nb < 4; nb++)
#pragma unroll
        for (int r = 0; r < 4; r++) {
            const int row = nb * 16 + g * 4 + r;
            const float ssum = sm[row * 4 + 0] + sm[row * 4 + 1] + sm[row * 4 + 2] + sm[row * 4 + 3];
            invs[nb][r] = 1.f / ssum;
        }

    __hip_bfloat16* Pb = Pbuf + ((size_t)b * NN + n0) * LP;
#pragma unroll
    for (int i = 0; i < 4; i++) {
        const int lb = w + 4 * i;
#pragma unroll
        for (int nb = 0; nb < 4; nb++)
#pragma unroll
            for (int r = 0; r < 4; r++)
                Pb[(size_t)(nb * 16 + g * 4 + r) * LP + lb * 16 + c] =
                    __float2bfloat16(acc[i][nb][r] * invs[nb][r]);
    }

    if (tid < 64) {
        const int row = tid;
        const int n = n0 + row;
        const float ssum = sm[row * 4 + 0] + sm[row * 4 + 1] + sm[row * 4 + 2] + sm[row * 4 + 3];
        const float nsum = nm[row * 4 + 0] + nm[row * 4 + 1] + nm[row * 4 + 2] + nm[row * 4 + 3];
        numq[(size_t)n * BB + b] = (nsum / ssum) * qinv[n];
    }
}

// den: T = P.G (both operands LDS-staged, K=256 in 8 steps), den = sum P*T,
// logits = numq / ||agg||. Grid 1024, XCD-swizzled.
// LDS 40960: vbuf (G rows) 2x16KB @0, tbuf (P rows) 2x4KB @32768; mx overlay @0.
__global__ __launch_bounds__(256, 4) void den_kernel(
    const __hip_bfloat16* __restrict__ Pbuf, const __hip_bfloat16* __restrict__ G,
    const float* __restrict__ numq, float* __restrict__ logits) {
    const int id = blockIdx.x;
    const int xcd = id & 7;
    const int kk = id >> 3;
    const int bhi = kk >> 4;
    const int nt = kk & 15;
    const int b = xcd + 8 * bhi;
    const int n0 = nt * 64;
    const int tid = threadIdx.x, w = tid >> 6, lane = tid & 63;
    const int g = lane >> 4, c = lane & 15;

    __shared__ __align__(16) unsigned char smem[40960];
    float* mx = (float*)smem;            // [64][4] overlay (post-GEMM)

    const char* Gbc = (const char*)(G + (size_t)b * LP * LP);
    const char* Pbc = (const char*)(Pbuf + ((size_t)b * NN + n0) * LP);

#define DSTAGE(ks, bsel)                                                        \
    {                                                                           \
        const int kb_ = (ks) * 64;                                              \
        _Pragma("unroll")                                                       \
        for (int q_ = 0; q_ < 4; q_++) {                                        \
            const int off_ = q_ * 4096 + tid * 16;                              \
            gl_lds16(Gbc + (size_t)(off_ >> 6) * 512 + kb_ + (off_ & 63),       \
                     smem + (bsel) * 16384 + q_ * 4096 + w * 1024);             \
        }                                                                       \
        {                                                                       \
            const int off_ = tid * 16;                                          \
            gl_lds16(Pbc + (size_t)(off_ >> 6) * 512 + kb_ + (off_ & 63),       \
                     smem + 32768 + (bsel) * 4096 + w * 1024);                  \
        }                                                                       \
    }

    f32x4 acc[4][4];  // T frags: [i = col-block slot][nb]
#pragma unroll
    for (int i = 0; i < 4; i++)
#pragma unroll
        for (int nb = 0; nb < 4; nb++) acc[i][nb] = {0.f, 0.f, 0.f, 0.f};

    DSTAGE(0, 0);
    asm volatile("s_waitcnt vmcnt(0)" ::: "memory");
    __syncthreads();

    for (int ks = 0; ks < 8; ks++) {
        const int cur = ks & 1;
        if (ks < 7) DSTAGE(ks + 1, cur ^ 1);
        const unsigned char* vb = smem + cur * 16384;
        const unsigned char* tb = smem + 32768 + cur * 4096;
        short8 af[4], bf[4];
#pragma unroll
        for (int nb = 0; nb < 4; nb++)
            af[nb] = *(const short8*)(tb + (nb * 16 + c) * 64 + g * 16);
#pragma unroll
        for (int i = 0; i < 4; i++)
            bf[i] = *(const short8*)(vb + ((w + 4 * i) * 16 + c) * 64 + g * 16);
#pragma unroll
        for (int i = 0; i < 4; i++)
#pragma unroll
            for (int nb = 0; nb < 4; nb++)
                acc[i][nb] = __builtin_amdgcn_mfma_f32_16x16x32_bf16(
                    af[nb], bf[i], acc[i][nb], 0, 0, 0);
        asm volatile("s_waitcnt vmcnt(0)" ::: "memory");
        __syncthreads();
    }
#undef DSTAGE

    // den = sum over cols of P * T (P re-read from L2-hot Pbuf)
    const short* Pb = (const short*)Pbc;
    float den[4][4];
#pragma unroll
    for (int nb = 0; nb < 4; nb++)
#pragma unroll
        for (int r = 0; r < 4; r++) den[nb][r] = 0.f;
#pragma unroll
    for (int i = 0; i < 4; i++) {
        const int col = (w + 4 * i) * 16 + c;
#pragma unroll
        for (int nb = 0; nb < 4; nb++)
#pragma unroll
            for (int r = 0; r < 4; r++) {
                const float P = bf2f((unsigned short)Pb[(size_t)(nb * 16 + g * 4 + r) * LP + col]);
                den[nb][r] += P * acc[i][nb][r];
            }
    }

#pragma unroll
    for (int nb = 0; nb < 4; nb++)
#pragma unroll
        for (int r = 0; r < 4; r++) den[nb][r] = grpSum(den[nb][r]);
    if (c == 0) {
#pragma unroll
        for (int nb = 0; nb < 4; nb++)
#pragma unroll
            for (int r = 0; r < 4; r++) mx[(nb * 16 + g * 4 + r) * 4 + w] = den[nb][r];
    }
    __syncthreads();
    if (tid < 64) {
        const int row = tid;
        const int n = n0 + row;
        const float dsum = mx[row * 4 + 0] + mx[row * 4 + 1] + mx[row * 4 + 2] + mx[row * 4 + 3];
        const float dn = fmaxf(sqrtf(fmaxf(dsum, 0.f)), NORM_EPS);
        logits[(size_t)n * BB + b] = numq[(size_t)n * BB + b] / dn;
    }
}

__global__ __launch_bounds__(64) void loss_row_kernel(
    const float* __restrict__ logits, const int* __restrict__ gm,
    const float* __restrict__ logtemp, float* __restrict__ scaled,
    float* __restrict__ posv, float* __restrict__ rowloss) {
    const int n = blockIdx.x;
    const int b = threadIdx.x;
    const float invtemp = 1.f / expf(logtemp[0]);
    const float e = expf(logits[(size_t)n * BB + b] * invtemp);
    scaled[(size_t)n * BB + b] = e;
    const float sum = waveSum(e);
    const int g = gm[n];
    const float pos = __shfl(e, g, 64);
    if (b == 0) {
        posv[n] = pos;
        rowloss[n] = -logf(pos / (sum + EPS) + EPS);
    }
}

__global__ __launch_bounds__(256) void colsum_kernel(
    const float* __restrict__ scaled, const int* __restrict__ gm,
    float* __restrict__ colsum, float* __restrict__ poscol) {
    const int b = blockIdx.x;
    const int tid = threadIdx.x;
    float s = 0.f, p = 0.f;
    for (int n = tid; n < NN; n += 256) {
        const float e = scaled[(size_t)n * BB + b];
        s += e;
        if (gm[n] == b) p += e;
    }
    s = waveSum(s); p = waveSum(p);
    __shared__ float red[8];
    const int w = tid >> 6;
    if ((tid & 63) == 0) { red[w] = s; red[4 + w] = p; }
    __syncthreads();
    if (tid == 0) {
        colsum[b] = red[0] + red[1] + red[2] + red[3];
        poscol[b] = red[4] + red[5] + red[6] + red[7];
    }
}

__global__ __launch_bounds__(1024) void final_kernel(
    const float* __restrict__ posv, const float* __restrict__ rowloss,
    const float* __restrict__ colsum, const float* __restrict__ poscol,
    const int* __restrict__ gm, float* __restrict__ out) {
    const int n = threadIdx.x;
    const int g = gm[n];
    const float pos = posv[n];
    const float sum_neg = colsum[g] - poscol[g];
    const float cl = -logf(pos / (pos + sum_neg + EPS) + EPS);
    float v = rowloss[n] + cl;
    v = waveSum(v);
    __shared__ float red[16];
    if ((n & 63) == 0) red[n >> 6] = v;
    __syncthreads();
    if (n == 0) {
        float s = 0.f;
#pragma unroll
        for (int i = 0; i < 16; i++) s += red[i];
        out[0] = s / (2.f * NN);
    }
}

extern "C" void kernel_launch(void* const* d_in, const int* in_sizes, int n_in,
                              void* d_out, int out_size, void* d_ws, size_t ws_size,
                              hipStream_t stream) {
    const float* text = (const float*)d_in[0];
    const float* vis = (const float*)d_in[1];
    const int* gm = (const int*)d_in[2];
    const float* gamma = (const float*)d_in[3];
    const float* beta = (const float*)d_in[4];
    const float* logtemp = (const float*)d_in[5];
    float* out = (float*)d_out;

    char* w = (char*)d_ws;
    __hip_bfloat16* tf = (__hip_bfloat16*)w;             w += (size_t)NN * DD * 2;
    __hip_bfloat16* vt = (__hip_bfloat16*)w;             w += (size_t)BB * LP * DD * 2;
    __hip_bfloat16* G  = (__hip_bfloat16*)w;             w += (size_t)BB * LP * LP * 2;
    __hip_bfloat16* Pbuf = (__hip_bfloat16*)w;           w += (size_t)BB * NN * LP * 2;
    float* qinv    = (float*)w;  w += (size_t)NN * 4;
    float* numq    = (float*)w;  w += (size_t)NN * BB * 4;
    float* logits  = (float*)w;  w += (size_t)NN * BB * 4;
    float* scaled  = (float*)w;  w += (size_t)NN * BB * 4;
    float* posv    = (float*)w;  w += (size_t)NN * 4;
    float* rowloss = (float*)w;  w += (size_t)NN * 4;
    float* colsum  = (float*)w;  w += (size_t)BB * 4;
    float* poscol  = (float*)w;  w += (size_t)BB * 4;

    ln_kernel<<<NN, 256, 0, stream>>>(text, tf, gamma, beta, qinv);
    ln_vis_kernel<<<BB * LP, 256, 0, stream>>>(vis, vt, gamma, beta);

    score_kernel<<<1024, 256, 0, stream>>>(tf, vt, qinv, Pbuf, numq);
    gram_kernel<<<512, 256, 0, stream>>>(vt, G);
    den_kernel<<<1024, 256, 0, stream>>>(Pbuf, G, numq, logits);

    loss_row_kernel<<<NN, 64, 0, stream>>>(logits, gm, logtemp, scaled, posv, rowloss);
    colsum_kernel<<<BB, 256, 0, stream>>>(scaled, gm, colsum, poscol);
    final_kernel<<<1, 1024, 0, stream>>>(posv, rowloss, colsum, poscol, gm, out);
}

// Round 13
// 123.755 us; speedup vs baseline: 2.1762x; 1.0598x over previous
//
#include <hip/hip_runtime.h>
#include <hip/hip_bf16.h>
#include <math.h>

#define NN 1024
#define BB 64
#define LL 197
#define LP 256
#define DD 768

typedef __attribute__((ext_vector_type(8))) short short8;
typedef __attribute__((ext_vector_type(4))) float f32x4;

constexpr float LN_EPS = 1e-5f;
constexpr float NORM_EPS = 1e-12f;
constexpr float EPS = 1e-8f;

__device__ __forceinline__ float waveSum(float v) {
#pragma unroll
    for (int m = 32; m >= 1; m >>= 1) v += __shfl_xor(v, m, 64);
    return v;
}
__device__ __forceinline__ float grpSum(float v) {
#pragma unroll
    for (int m = 8; m >= 1; m >>= 1) v += __shfl_xor(v, m, 64);
    return v;
}
__device__ __forceinline__ float grpMax(float v) {
#pragma unroll
    for (int m = 8; m >= 1; m >>= 1) v = fmaxf(v, __shfl_xor(v, m, 64));
    return v;
}

__device__ __forceinline__ float bf2f(unsigned short u) {
    unsigned int x = ((unsigned int)u) << 16;
    return reinterpret_cast<float&>(x);
}

__device__ __forceinline__ void gl_lds16(const void* g, void* l) {
    __builtin_amdgcn_global_load_lds(
        (const __attribute__((address_space(1))) unsigned int*)g,
        (__attribute__((address_space(3))) unsigned int*)l, 16, 0, 0);
}

// Text LayerNorm -> bf16 + qinv = 1/max(||y||,eps)
__global__ __launch_bounds__(256) void ln_kernel(
    const float* __restrict__ x, __hip_bfloat16* __restrict__ y,
    const float* __restrict__ gamma, const float* __restrict__ beta,
    float* __restrict__ qinv) {
    const int row = blockIdx.x;
    const int tid = threadIdx.x;
    const float* xr = x + (size_t)row * DD;
    __hip_bfloat16* yr = y + (size_t)row * DD;

    float v[3];
    float s = 0.f, ss = 0.f;
#pragma unroll
    for (int c = 0; c < 3; c++) {
        float t = xr[tid + 256 * c];
        v[c] = t; s += t; ss += t * t;
    }
    __shared__ float red[8];
    s = waveSum(s); ss = waveSum(ss);
    const int w = tid >> 6;
    if ((tid & 63) == 0) { red[w] = s; red[4 + w] = ss; }
    __syncthreads();
    s = red[0] + red[1] + red[2] + red[3];
    ss = red[4] + red[5] + red[6] + red[7];
    const float mean = s * (1.f / DD);
    const float var = ss * (1.f / DD) - mean * mean;
    const float rs = rsqrtf(var + LN_EPS);

    float q = 0.f;
#pragma unroll
    for (int c = 0; c < 3; c++) {
        const int d = tid + 256 * c;
        float t = (v[c] - mean) * rs * gamma[d] + beta[d];
        __hip_bfloat16 hb = __float2bfloat16(t);
        yr[d] = hb;
        float tb = __bfloat162float(hb);
        q += tb * tb;
    }
    __syncthreads();
    q = waveSum(q);
    if ((tid & 63) == 0) red[w] = q;
    __syncthreads();
    if (tid == 0) {
        float n2 = red[0] + red[1] + red[2] + red[3];
        qinv[row] = 1.f / fmaxf(sqrtf(n2), NORM_EPS);
    }
}

// Vision LayerNorm into padded [B, LP, D]; XCD-swizzled: blockid ≡ b (mod 8).
__global__ __launch_bounds__(256) void ln_vis_kernel(
    const float* __restrict__ x, __hip_bfloat16* __restrict__ y,
    const float* __restrict__ gamma, const float* __restrict__ beta) {
    const int id = blockIdx.x;           // 0..BB*LP-1 (16384)
    const int xcd = id & 7;
    const int k = id >> 3;               // 0..2047
    const int bhi = k >> 8;              // 0..7
    const int l = k & 255;               // 0..255
    const int b = xcd + 8 * bhi;
    const int tid = threadIdx.x;
    __hip_bfloat16* yr = y + ((size_t)b * LP + l) * DD;
    if (l >= LL) {
#pragma unroll
        for (int c = 0; c < 3; c++) yr[tid + 256 * c] = __float2bfloat16(0.f);
        return;
    }
    const float* xr = x + ((size_t)b * LL + l) * DD;

    float v[3];
    float s = 0.f, ss = 0.f;
#pragma unroll
    for (int c = 0; c < 3; c++) {
        float t = xr[tid + 256 * c];
        v[c] = t; s += t; ss += t * t;
    }
    __shared__ float red[8];
    s = waveSum(s); ss = waveSum(ss);
    const int w = tid >> 6;
    if ((tid & 63) == 0) { red[w] = s; red[4 + w] = ss; }
    __syncthreads();
    s = red[0] + red[1] + red[2] + red[3];
    ss = red[4] + red[5] + red[6] + red[7];
    const float mean = s * (1.f / DD);
    const float var = ss * (1.f / DD) - mean * mean;
    const float rs = rsqrtf(var + LN_EPS);
#pragma unroll
    for (int c = 0; c < 3; c++) {
        const int d = tid + 256 * c;
        yr[d] = __float2bfloat16((v[c] - mean) * rs * gamma[d] + beta[d]);
    }
}

// Gram: G[b] = vt_b . vt_b^T, LDS-staged via global_load_lds (XOR-swizzled).
// Grid 512: 8 row-blocks of 32 x 64 b, XCD-swizzled.
__global__ __launch_bounds__(256, 4) void gram_kernel(
    const __hip_bfloat16* __restrict__ vt, __hip_bfloat16* __restrict__ G) {
    const int id = blockIdx.x;           // 0..511
    const int xcd = id & 7;
    const int k = id >> 3;               // 0..63
    const int bhi = k >> 3;              // 0..7
    const int rb = k & 7;                // 0..7
    const int b = xcd + 8 * bhi;
    const int n0 = rb * 32;
    const int tid = threadIdx.x, w = tid >> 6, lane = tid & 63;
    const int g = lane >> 4, c = lane & 15;
    const int gsw = (g ^ ((c ^ (c >> 2)) & 3)) * 16;   // swizzled read granule

    __shared__ __align__(16) unsigned char smem[36864];
    const char* vtbc = (const char*)(vt + (size_t)b * LP * DD);

#define GSTAGE(ks, bsel)                                                        \
    {                                                                           \
        const int kb_ = (ks) * 64;                                              \
        _Pragma("unroll")                                                       \
        for (int q_ = 0; q_ < 4; q_++) {                                        \
            const int o_ = q_ * 4096 + tid * 16;                                \
            const int r_ = o_ >> 6;                                             \
            const int sj_ = ((o_ >> 4) & 3) ^ ((r_ ^ (r_ >> 2)) & 3);           \
            gl_lds16(vtbc + (size_t)r_ * 1536 + kb_ + sj_ * 16,                 \
                     smem + (bsel) * 16384 + q_ * 4096 + w * 1024);             \
        }                                                                       \
        if (w < 2) {                                                            \
            const int o_ = tid * 16;                                            \
            const int r_ = o_ >> 6;                                             \
            const int sj_ = ((o_ >> 4) & 3) ^ ((r_ ^ (r_ >> 2)) & 3);           \
            gl_lds16(vtbc + (size_t)(n0 + r_) * 1536 + kb_ + sj_ * 16,          \
                     smem + 32768 + (bsel) * 2048 + w * 1024);                  \
        }                                                                       \
    }

    f32x4 acc[4][2];  // [i = col-block slot][nb row-block]
#pragma unroll
    for (int i = 0; i < 4; i++)
#pragma unroll
        for (int nb = 0; nb < 2; nb++) acc[i][nb] = {0.f, 0.f, 0.f, 0.f};

    GSTAGE(0, 0);
    asm volatile("s_waitcnt vmcnt(0)" ::: "memory");
    __syncthreads();

    for (int ks = 0; ks < 24; ks++) {
        const int cur = ks & 1;
        if (ks < 23) GSTAGE(ks + 1, cur ^ 1);
        const unsigned char* vb = smem + cur * 16384;
        const unsigned char* tb = smem + 32768 + cur * 2048;
        short8 af[2], bf[4];
#pragma unroll
        for (int nb = 0; nb < 2; nb++)
            af[nb] = *(const short8*)(tb + (nb * 16 + c) * 64 + gsw);
#pragma unroll
        for (int i = 0; i < 4; i++)
            bf[i] = *(const short8*)(vb + ((w + 4 * i) * 16 + c) * 64 + gsw);
#pragma unroll
        for (int i = 0; i < 4; i++)
#pragma unroll
            for (int nb = 0; nb < 2; nb++)
                acc[i][nb] = __builtin_amdgcn_mfma_f32_16x16x32_bf16(
                    af[nb], bf[i], acc[i][nb], 0, 0, 0);
        asm volatile("s_waitcnt vmcnt(0)" ::: "memory");
        __syncthreads();
    }
#undef GSTAGE

    __hip_bfloat16* Gb = G + (size_t)b * LP * LP;
#pragma unroll
    for (int i = 0; i < 4; i++) {
        const int col = (w + 4 * i) * 16 + c;
#pragma unroll
        for (int nb = 0; nb < 2; nb++)
#pragma unroll
            for (int r = 0; r < 4; r++)
                Gb[(size_t)(n0 + nb * 16 + g * 4 + r) * LP + col] =
                    __float2bfloat16(acc[i][nb][r]);
    }
}

// score: S = tf.vt^T (gl_lds staged dbuf, XOR-swizzled), softmax, num ->
// Pbuf (bf16 normalized P) + numq. Grid 1024, XCD-swizzled. (256,3): no spill.
__global__ __launch_bounds__(256, 3) void score_kernel(
    const __hip_bfloat16* __restrict__ tf, const __hip_bfloat16* __restrict__ vt,
    const float* __restrict__ qinv, __hip_bfloat16* __restrict__ Pbuf,
    float* __restrict__ numq) {
    const int id = blockIdx.x;
    const int xcd = id & 7;
    const int kk = id >> 3;              // 0..127
    const int bhi = kk >> 4;             // 0..7
    const int nt = kk & 15;              // 0..15
    const int b = xcd + 8 * bhi;
    const int n0 = nt * 64;
    const int tid = threadIdx.x, w = tid >> 6, lane = tid & 63;
    const int g = lane >> 4, c = lane & 15;
    const int gsw = (g ^ ((c ^ (c >> 2)) & 3)) * 16;

    __shared__ __align__(16) unsigned char smem[40960];
    float* mx = (float*)smem;            // [64][4] overlay (post-stage1)
    float* sm = mx + 256;
    float* nm = sm + 256;

    const char* vtbc = (const char*)(vt + (size_t)b * LP * DD);
    const char* tfc = (const char*)(tf + (size_t)n0 * DD);

#define SSTAGE(ks, bsel)                                                        \
    {                                                                           \
        const int kb_ = (ks) * 64;                                              \
        _Pragma("unroll")                                                       \
        for (int q_ = 0; q_ < 4; q_++) {                                        \
            const int o_ = q_ * 4096 + tid * 16;                                \
            const int r_ = o_ >> 6;                                             \
            const int sj_ = ((o_ >> 4) & 3) ^ ((r_ ^ (r_ >> 2)) & 3);           \
            gl_lds16(vtbc + (size_t)r_ * 1536 + kb_ + sj_ * 16,                 \
                     smem + (bsel) * 16384 + q_ * 4096 + w * 1024);             \
        }                                                                       \
        {                                                                       \
            const int o_ = tid * 16;                                            \
            const int r_ = o_ >> 6;                                             \
            const int sj_ = ((o_ >> 4) & 3) ^ ((r_ ^ (r_ >> 2)) & 3);           \
            gl_lds16(tfc + (size_t)r_ * 1536 + kb_ + sj_ * 16,                  \
                     smem + 32768 + (bsel) * 4096 + w * 1024);                  \
        }                                                                       \
    }

    f32x4 acc[4][4];  // [i = lb slot][nb]
#pragma unroll
    for (int i = 0; i < 4; i++)
#pragma unroll
        for (int nb = 0; nb < 4; nb++) acc[i][nb] = {0.f, 0.f, 0.f, 0.f};

    SSTAGE(0, 0);
    asm volatile("s_waitcnt vmcnt(0)" ::: "memory");
    __syncthreads();

    for (int ks = 0; ks < 24; ks++) {
        const int cur = ks & 1;
        if (ks < 23) SSTAGE(ks + 1, cur ^ 1);
        const unsigned char* vb = smem + cur * 16384;
        const unsigned char* tb = smem + 32768 + cur * 4096;
        short8 af[4], bf[4];
#pragma unroll
        for (int nb = 0; nb < 4; nb++)
            af[nb] = *(const short8*)(tb + (nb * 16 + c) * 64 + gsw);
#pragma unroll
        for (int i = 0; i < 4; i++)
            bf[i] = *(const short8*)(vb + ((w + 4 * i) * 16 + c) * 64 + gsw);
#pragma unroll
        for (int i = 0; i < 4; i++)
#pragma unroll
            for (int nb = 0; nb < 4; nb++)
                acc[i][nb] = __builtin_amdgcn_mfma_f32_16x16x32_bf16(
                    af[nb], bf[i], acc[i][nb], 0, 0, 0);
        asm volatile("s_waitcnt vmcnt(0)" ::: "memory");
        __syncthreads();
    }
#undef SSTAGE

    // ---- softmax over l (waves hold disjoint l-columns) ----
    const float inv_sqrtD = 0.0360843918f;
    float mp[4][4];
#pragma unroll
    for (int nb = 0; nb < 4; nb++)
#pragma unroll
        for (int r = 0; r < 4; r++) mp[nb][r] = -1e30f;
#pragma unroll
    for (int i = 0; i < 4; i++) {
        const int l = (w + 4 * i) * 16 + c;
        if (l < LL) {
#pragma unroll
            for (int nb = 0; nb < 4; nb++)
#pragma unroll
                for (int r = 0; r < 4; r++) mp[nb][r] = fmaxf(mp[nb][r], acc[i][nb][r]);
        }
    }
#pragma unroll
    for (int nb = 0; nb < 4; nb++)
#pragma unroll
        for (int r = 0; r < 4; r++) mp[nb][r] = grpMax(mp[nb][r]);
    if (c == 0) {
#pragma unroll
        for (int nb = 0; nb < 4; nb++)
#pragma unroll
            for (int r = 0; r < 4; r++) mx[(nb * 16 + g * 4 + r) * 4 + w] = mp[nb][r];
    }
    __syncthreads();
    float mf[4][4];
#pragma unroll
    for (int nb = 0; nb < 4; nb++)
#pragma unroll
        for (int r = 0; r < 4; r++) {
            const int row = nb * 16 + g * 4 + r;
            mf[nb][r] = fmaxf(fmaxf(mx[row * 4 + 0], mx[row * 4 + 1]),
                              fmaxf(mx[row * 4 + 2], mx[row * 4 + 3]));
        }

    float sp[4][4], np[4][4];
#pragma unroll
    for (int nb = 0; nb < 4; nb++)
#pragma unroll
        for (int r = 0; r < 4; r++) { sp[nb][r] = 0.f; np[nb][r] = 0.f; }
#pragma unroll
    for (int i = 0; i < 4; i++) {
        const int l = (w + 4 * i) * 16 + c;
#pragma unroll
        for (int nb = 0; nb < 4; nb++)
#pragma unroll
            for (int r = 0; r < 4; r++) {
                const float raw = acc[i][nb][r];
                const float p = (l < LL) ? __expf((raw - mf[nb][r]) * inv_sqrtD) : 0.f;
                acc[i][nb][r] = p;
                sp[nb][r] += p;
                np[nb][r] += p * raw;
            }
    }
#pragma unroll
    for (int nb = 0; nb < 4; nb++)
#pragma unroll
        for (int r = 0; r < 4; r++) { sp[nb][r] = grpSum(sp[nb][r]); np[nb][r] = grpSum(np[nb][r]); }
    if (c == 0) {
#pragma unroll
        for (int nb = 0; nb < 4; nb++)
#pragma unroll
            for (int r = 0; r < 4; r++) {
                const int row = nb * 16 + g * 4 + r;
                sm[row * 4 + w] = sp[nb][r];
                nm[row * 4 + w] = np[nb][r];
            }
    }
    __syncthreads();

    float invs[4][4];
#pragma unroll
    for (int nb = 0; nb < 4; nb++)
#pragma unroll
        for (int r = 0; r < 4; r++) {
            const int row = nb * 16 + g * 4 + r;
            const float ssum = sm[row * 4 + 0] + sm[row * 4 + 1] + sm[row * 4 + 2] + sm[row * 4 + 3];
            invs[nb][r] = 1.f / ssum;
        }

    __hip_bfloat16* Pb = Pbuf + ((size_t)b * NN + n0) * LP;
#pragma unroll
    for (int i = 0; i < 4; i++) {
        const int lb = w + 4 * i;
#pragma unroll
        for (int nb = 0; nb < 4; nb++)
#pragma unroll
            for (int r = 0; r < 4; r++)
                Pb[(size_t)(nb * 16 + g * 4 + r) * LP + lb * 16 + c] =
                    __float2bfloat16(acc[i][nb][r] * invs[nb][r]);
    }

    if (tid < 64) {
        const int row = tid;
        const int n = n0 + row;
        const float ssum = sm[row * 4 + 0] + sm[row * 4 + 1] + sm[row * 4 + 2] + sm[row * 4 + 3];
        const float nsum = nm[row * 4 + 0] + nm[row * 4 + 1] + nm[row * 4 + 2] + nm[row * 4 + 3];
        numq[(size_t)n * BB + b] = (nsum / ssum) * qinv[n];
    }
}

// den: T = P.G (both operands LDS-staged + swizzled, 8 K-steps), den = sum P*T,
// logits = numq / ||agg||. Grid 1024, XCD-swizzled. (256,3): no spill.
__global__ __launch_bounds__(256, 3) void den_kernel(
    const __hip_bfloat16* __restrict__ Pbuf, const __hip_bfloat16* __restrict__ G,
    const float* __restrict__ numq, float* __restrict__ logits) {
    const int id = blockIdx.x;
    const int xcd = id & 7;
    const int kk = id >> 3;
    const int bhi = kk >> 4;
    const int nt = kk & 15;
    const int b = xcd + 8 * bhi;
    const int n0 = nt * 64;
    const int tid = threadIdx.x, w = tid >> 6, lane = tid & 63;
    const int g = lane >> 4, c = lane & 15;
    const int gsw = (g ^ ((c ^ (c >> 2)) & 3)) * 16;

    __shared__ __align__(16) unsigned char smem[40960];
    float* mx = (float*)smem;            // [64][4] overlay (post-GEMM)

    const char* Gbc = (const char*)(G + (size_t)b * LP * LP);
    const char* Pbc = (const char*)(Pbuf + ((size_t)b * NN + n0) * LP);

#define DSTAGE(ks, bsel)                                                        \
    {                                                                           \
        const int kb_ = (ks) * 64;                                              \
        _Pragma("unroll")                                                       \
        for (int q_ = 0; q_ < 4; q_++) {                                        \
            const int o_ = q_ * 4096 + tid * 16;                                \
            const int r_ = o_ >> 6;                                             \
            const int sj_ = ((o_ >> 4) & 3) ^ ((r_ ^ (r_ >> 2)) & 3);           \
            gl_lds16(Gbc + (size_t)r_ * 512 + kb_ + sj_ * 16,                   \
                     smem + (bsel) * 16384 + q_ * 4096 + w * 1024);             \
        }                                                                       \
        {                                                                       \
            const int o_ = tid * 16;                                            \
            const int r_ = o_ >> 6;                                             \
            const int sj_ = ((o_ >> 4) & 3) ^ ((r_ ^ (r_ >> 2)) & 3);           \
            gl_lds16(Pbc + (size_t)r_ * 512 + kb_ + sj_ * 16,                   \
                     smem + 32768 + (bsel) * 4096 + w * 1024);                  \
        }                                                                       \
    }

    f32x4 acc[4][4];  // T frags: [i = col-block slot][nb]
#pragma unroll
    for (int i = 0; i < 4; i++)
#pragma unroll
        for (int nb = 0; nb < 4; nb++) acc[i][nb] = {0.f, 0.f, 0.f, 0.f};

    DSTAGE(0, 0);
    asm volatile("s_waitcnt vmcnt(0)" ::: "memory");
    __syncthreads();

    for (int ks = 0; ks < 8; ks++) {
        const int cur = ks & 1;
        if (ks < 7) DSTAGE(ks + 1, cur ^ 1);
        const unsigned char* vb = smem + cur * 16384;
        const unsigned char* tb = smem + 32768 + cur * 4096;
        short8 af[4], bf[4];
#pragma unroll
        for (int nb = 0; nb < 4; nb++)
            af[nb] = *(const short8*)(tb + (nb * 16 + c) * 64 + gsw);
#pragma unroll
        for (int i = 0; i < 4; i++)
            bf[i] = *(const short8*)(vb + ((w + 4 * i) * 16 + c) * 64 + gsw);
#pragma unroll
        for (int i = 0; i < 4; i++)
#pragma unroll
            for (int nb = 0; nb < 4; nb++)
                acc[i][nb] = __builtin_amdgcn_mfma_f32_16x16x32_bf16(
                    af[nb], bf[i], acc[i][nb], 0, 0, 0);
        asm volatile("s_waitcnt vmcnt(0)" ::: "memory");
        __syncthreads();
    }
#undef DSTAGE

    // den = sum over cols of P * T (P re-read from L2-hot Pbuf)
    const short* Pb = (const short*)Pbc;
    float den[4][4];
#pragma unroll
    for (int nb = 0; nb < 4; nb++)
#pragma unroll
        for (int r = 0; r < 4; r++) den[nb][r] = 0.f;
#pragma unroll
    for (int i = 0; i < 4; i++) {
        const int col = (w + 4 * i) * 16 + c;
#pragma unroll
        for (int nb = 0; nb < 4; nb++)
#pragma unroll
            for (int r = 0; r < 4; r++) {
                const float P = bf2f((unsigned short)Pb[(size_t)(nb * 16 + g * 4 + r) * LP + col]);
                den[nb][r] += P * acc[i][nb][r];
            }
    }

#pragma unroll
    for (int nb = 0; nb < 4; nb++)
#pragma unroll
        for (int r = 0; r < 4; r++) den[nb][r] = grpSum(den[nb][r]);
    if (c == 0) {
#pragma unroll
        for (int nb = 0; nb < 4; nb++)
#pragma unroll
            for (int r = 0; r < 4; r++) mx[(nb * 16 + g * 4 + r) * 4 + w] = den[nb][r];
    }
    __syncthreads();
    if (tid < 64) {
        const int row = tid;
        const int n = n0 + row;
        const float dsum = mx[row * 4 + 0] + mx[row * 4 + 1] + mx[row * 4 + 2] + mx[row * 4 + 3];
        const float dn = fmaxf(sqrtf(fmaxf(dsum, 0.f)), NORM_EPS);
        logits[(size_t)n * BB + b] = numq[(size_t)n * BB + b] / dn;
    }
}

__global__ __launch_bounds__(64) void loss_row_kernel(
    const float* __restrict__ logits, const int* __restrict__ gm,
    const float* __restrict__ logtemp, float* __restrict__ scaled,
    float* __restrict__ posv, float* __restrict__ rowloss) {
    const int n = blockIdx.x;
    const int b = threadIdx.x;
    const float invtemp = 1.f / expf(logtemp[0]);
    const float e = expf(logits[(size_t)n * BB + b] * invtemp);
    scaled[(size_t)n * BB + b] = e;
    const float sum = waveSum(e);
    const int g = gm[n];
    const float pos = __shfl(e, g, 64);
    if (b == 0) {
        posv[n] = pos;
        rowloss[n] = -logf(pos / (sum + EPS) + EPS);
    }
}

__global__ __launch_bounds__(256) void colsum_kernel(
    const float* __restrict__ scaled, const int* __restrict__ gm,
    float* __restrict__ colsum, float* __restrict__ poscol) {
    const int b = blockIdx.x;
    const int tid = threadIdx.x;
    float s = 0.f, p = 0.f;
    for (int n = tid; n < NN; n += 256) {
        const float e = scaled[(size_t)n * BB + b];
        s += e;
        if (gm[n] == b) p += e;
    }
    s = waveSum(s); p = waveSum(p);
    __shared__ float red[8];
    const int w = tid >> 6;
    if ((tid & 63) == 0) { red[w] = s; red[4 + w] = p; }
    __syncthreads();
    if (tid == 0) {
        colsum[b] = red[0] + red[1] + red[2] + red[3];
        poscol[b] = red[4] + red[5] + red[6] + red[7];
    }
}

__global__ __launch_bounds__(1024) void final_kernel(
    const float* __restrict__ posv, const float* __restrict__ rowloss,
    const float* __restrict__ colsum, const float* __restrict__ poscol,
    const int* __restrict__ gm, float* __restrict__ out) {
    const int n = threadIdx.x;
    const int g = gm[n];
    const float pos = posv[n];
    const float sum_neg = colsum[g] - poscol[g];
    const float cl = -logf(pos / (pos + sum_neg + EPS) + EPS);
    float v = rowloss[n] + cl;
    v = waveSum(v);
    __shared__ float red[16];
    if ((n & 63) == 0) red[n >> 6] = v;
    __syncthreads();
    if (n == 0) {
        float s = 0.f;
#pragma unroll
        for (int i = 0; i < 16; i++) s += red[i];
        out[0] = s / (2.f * NN);
    }
}

extern "C" void kernel_launch(void* const* d_in, const int* in_sizes, int n_in,
                              void* d_out, int out_size, void* d_ws, size_t ws_size,
                              hipStream_t stream) {
    const float* text = (const float*)d_in[0];
    const float* vis = (const float*)d_in[1];
    const int* gm = (const int*)d_in[2];
    const float* gamma = (const float*)d_in[3];
    const float* beta = (const float*)d_in[4];
    const float* logtemp = (const float*)d_in[5];
    float* out = (float*)d_out;

    char* w = (char*)d_ws;
    __hip_bfloat16* tf = (__hip_bfloat16*)w;             w += (size_t)NN * DD * 2;
    __hip_bfloat16* vt = (__hip_bfloat16*)w;             w += (size_t)BB * LP * DD * 2;
    __hip_bfloat16* G  = (__hip_bfloat16*)w;             w += (size_t)BB * LP * LP * 2;
    __hip_bfloat16* Pbuf = (__hip_bfloat16*)w;           w += (size_t)BB * NN * LP * 2;
    float* qinv    = (float*)w;  w += (size_t)NN * 4;
    float* numq    = (float*)w;  w += (size_t)NN * BB * 4;
    float* logits  = (float*)w;  w += (size_t)NN * BB * 4;
    float* scaled  = (float*)w;  w += (size_t)NN * BB * 4;
    float* posv    = (float*)w;  w += (size_t)NN * 4;
    float* rowloss = (float*)w;  w += (size_t)NN * 4;
    float* colsum  = (float*)w;  w += (size_t)BB * 4;
    float* poscol  = (float*)w;  w += (size_t)BB * 4;

    ln_kernel<<<NN, 256, 0, stream>>>(text, tf, gamma, beta, qinv);
    ln_vis_kernel<<<BB * LP, 256, 0, stream>>>(vis, vt, gamma, beta);

    score_kernel<<<1024, 256, 0, stream>>>(tf, vt, qinv, Pbuf, numq);
    gram_kernel<<<512, 256, 0, stream>>>(vt, G);
    den_kernel<<<1024, 256, 0, stream>>>(Pbuf, G, numq, logits);

    loss_row_kernel<<<NN, 64, 0, stream>>>(logits, gm, logtemp, scaled, posv, rowloss);
    colsum_kernel<<<BB, 256, 0, stream>>>(scaled, gm, colsum, poscol);
    final_kernel<<<1, 1024, 0, stream>>>(posv, rowloss, colsum, poscol, gm, out);
}

// Round 14
// 123.123 us; speedup vs baseline: 2.1873x; 1.0051x over previous
//
#include <hip/hip_runtime.h>
#include <hip/hip_bf16.h>
#include <math.h>

#define NN 1024
#define BB 64
#define LL 197
#define LP 256
#define DD 768

typedef __attribute__((ext_vector_type(8))) short short8;
typedef __attribute__((ext_vector_type(4))) float f32x4;

constexpr float LN_EPS = 1e-5f;
constexpr float NORM_EPS = 1e-12f;
constexpr float EPS = 1e-8f;

__device__ __forceinline__ float waveSum(float v) {
#pragma unroll
    for (int m = 32; m >= 1; m >>= 1) v += __shfl_xor(v, m, 64);
    return v;
}
__device__ __forceinline__ float grpSum(float v) {
#pragma unroll
    for (int m = 8; m >= 1; m >>= 1) v += __shfl_xor(v, m, 64);
    return v;
}
__device__ __forceinline__ float grpMax(float v) {
#pragma unroll
    for (int m = 8; m >= 1; m >>= 1) v = fmaxf(v, __shfl_xor(v, m, 64));
    return v;
}

__device__ __forceinline__ float bf2f(unsigned short u) {
    unsigned int x = ((unsigned int)u) << 16;
    return reinterpret_cast<float&>(x);
}

__device__ __forceinline__ void gl_lds16(const void* g, void* l) {
    __builtin_amdgcn_global_load_lds(
        (const __attribute__((address_space(1))) unsigned int*)g,
        (__attribute__((address_space(3))) unsigned int*)l, 16, 0, 0);
}

// Text LayerNorm -> bf16 + qinv = 1/max(||y||,eps)
__global__ __launch_bounds__(256) void ln_kernel(
    const float* __restrict__ x, __hip_bfloat16* __restrict__ y,
    const float* __restrict__ gamma, const float* __restrict__ beta,
    float* __restrict__ qinv) {
    const int row = blockIdx.x;
    const int tid = threadIdx.x;
    const float* xr = x + (size_t)row * DD;
    __hip_bfloat16* yr = y + (size_t)row * DD;

    float v[3];
    float s = 0.f, ss = 0.f;
#pragma unroll
    for (int c = 0; c < 3; c++) {
        float t = xr[tid + 256 * c];
        v[c] = t; s += t; ss += t * t;
    }
    __shared__ float red[8];
    s = waveSum(s); ss = waveSum(ss);
    const int w = tid >> 6;
    if ((tid & 63) == 0) { red[w] = s; red[4 + w] = ss; }
    __syncthreads();
    s = red[0] + red[1] + red[2] + red[3];
    ss = red[4] + red[5] + red[6] + red[7];
    const float mean = s * (1.f / DD);
    const float var = ss * (1.f / DD) - mean * mean;
    const float rs = rsqrtf(var + LN_EPS);

    float q = 0.f;
#pragma unroll
    for (int c = 0; c < 3; c++) {
        const int d = tid + 256 * c;
        float t = (v[c] - mean) * rs * gamma[d] + beta[d];
        __hip_bfloat16 hb = __float2bfloat16(t);
        yr[d] = hb;
        float tb = __bfloat162float(hb);
        q += tb * tb;
    }
    __syncthreads();
    q = waveSum(q);
    if ((tid & 63) == 0) red[w] = q;
    __syncthreads();
    if (tid == 0) {
        float n2 = red[0] + red[1] + red[2] + red[3];
        qinv[row] = 1.f / fmaxf(sqrtf(n2), NORM_EPS);
    }
}

// Vision LayerNorm into padded [B, LP, D]; XCD-swizzled: blockid ≡ b (mod 8).
__global__ __launch_bounds__(256) void ln_vis_kernel(
    const float* __restrict__ x, __hip_bfloat16* __restrict__ y,
    const float* __restrict__ gamma, const float* __restrict__ beta) {
    const int id = blockIdx.x;           // 0..BB*LP-1 (16384)
    const int xcd = id & 7;
    const int k = id >> 3;               // 0..2047
    const int bhi = k >> 8;              // 0..7
    const int l = k & 255;               // 0..255
    const int b = xcd + 8 * bhi;
    const int tid = threadIdx.x;
    __hip_bfloat16* yr = y + ((size_t)b * LP + l) * DD;
    if (l >= LL) {
#pragma unroll
        for (int c = 0; c < 3; c++) yr[tid + 256 * c] = __float2bfloat16(0.f);
        return;
    }
    const float* xr = x + ((size_t)b * LL + l) * DD;

    float v[3];
    float s = 0.f, ss = 0.f;
#pragma unroll
    for (int c = 0; c < 3; c++) {
        float t = xr[tid + 256 * c];
        v[c] = t; s += t; ss += t * t;
    }
    __shared__ float red[8];
    s = waveSum(s); ss = waveSum(ss);
    const int w = tid >> 6;
    if ((tid & 63) == 0) { red[w] = s; red[4 + w] = ss; }
    __syncthreads();
    s = red[0] + red[1] + red[2] + red[3];
    ss = red[4] + red[5] + red[6] + red[7];
    const float mean = s * (1.f / DD);
    const float var = ss * (1.f / DD) - mean * mean;
    const float rs = rsqrtf(var + LN_EPS);
#pragma unroll
    for (int c = 0; c < 3; c++) {
        const int d = tid + 256 * c;
        yr[d] = __float2bfloat16((v[c] - mean) * rs * gamma[d] + beta[d]);
    }
}

// Gram: G[b] = vt_b . vt_b^T, gl_lds triple-buffer + counted vmcnt.
// Grid 512: 8 row-blocks of 32 x 64 b, XCD-swizzled. LDS 55296 -> 2 blocks/CU
// (grid 512 = exactly 2/CU, one pass).
__global__ __launch_bounds__(256, 2) void gram_kernel(
    const __hip_bfloat16* __restrict__ vt, __hip_bfloat16* __restrict__ G) {
    const int id = blockIdx.x;           // 0..511
    const int xcd = id & 7;
    const int k = id >> 3;               // 0..63
    const int bhi = k >> 3;              // 0..7
    const int rb = k & 7;                // 0..7
    const int b = xcd + 8 * bhi;
    const int n0 = rb * 32;
    const int tid = threadIdx.x, w = tid >> 6, lane = tid & 63;
    const int g = lane >> 4, c = lane & 15;
    const int gsw = (g ^ ((c ^ (c >> 2)) & 3)) * 16;

    __shared__ __align__(16) unsigned char smem[55296];
    const char* vtbc = (const char*)(vt + (size_t)b * LP * DD);

// vbuf[bsel] @ bsel*16384 (48KB), tbuf[bsel] @ 49152 + bsel*2048
#define GSTAGE(ks, bsel)                                                        \
    {                                                                           \
        const int kb_ = (ks) * 64;                                              \
        _Pragma("unroll")                                                       \
        for (int q_ = 0; q_ < 4; q_++) {                                        \
            const int o_ = q_ * 4096 + tid * 16;                                \
            const int r_ = o_ >> 6;                                             \
            const int sj_ = ((o_ >> 4) & 3) ^ ((r_ ^ (r_ >> 2)) & 3);           \
            gl_lds16(vtbc + (size_t)r_ * 1536 + kb_ + sj_ * 16,                 \
                     smem + (bsel) * 16384 + q_ * 4096 + w * 1024);             \
        }                                                                       \
        if (w < 2) {                                                            \
            const int o_ = tid * 16;                                            \
            const int r_ = o_ >> 6;                                             \
            const int sj_ = ((o_ >> 4) & 3) ^ ((r_ ^ (r_ >> 2)) & 3);           \
            gl_lds16(vtbc + (size_t)(n0 + r_) * 1536 + kb_ + sj_ * 16,          \
                     smem + 49152 + (bsel) * 2048 + w * 1024);                  \
        }                                                                       \
    }

    f32x4 acc[4][2];
#pragma unroll
    for (int i = 0; i < 4; i++)
#pragma unroll
        for (int nb = 0; nb < 2; nb++) acc[i][nb] = {0.f, 0.f, 0.f, 0.f};

    GSTAGE(0, 0);
    GSTAGE(1, 1);
    asm volatile("s_waitcnt vmcnt(4)" ::: "memory");  // tile0 done (w2/3 exact; w0/1 safe-over)
    __syncthreads();

    for (int ks = 0; ks < 24; ks++) {
        if (ks < 22) GSTAGE(ks + 2, (ks + 2) % 3);
        const unsigned char* vb = smem + (ks % 3) * 16384;
        const unsigned char* tb = smem + 49152 + (ks % 3) * 2048;
        short8 af[2], bf[4];
#pragma unroll
        for (int nb = 0; nb < 2; nb++)
            af[nb] = *(const short8*)(tb + (nb * 16 + c) * 64 + gsw);
#pragma unroll
        for (int i = 0; i < 4; i++)
            bf[i] = *(const short8*)(vb + ((w + 4 * i) * 16 + c) * 64 + gsw);
#pragma unroll
        for (int i = 0; i < 4; i++)
#pragma unroll
            for (int nb = 0; nb < 2; nb++)
                acc[i][nb] = __builtin_amdgcn_mfma_f32_16x16x32_bf16(
                    af[nb], bf[i], acc[i][nb], 0, 0, 0);
        if (ks < 22) asm volatile("s_waitcnt vmcnt(4)" ::: "memory");
        else         asm volatile("s_waitcnt vmcnt(0)" ::: "memory");
        __syncthreads();
    }
#undef GSTAGE

    __hip_bfloat16* Gb = G + (size_t)b * LP * LP;
#pragma unroll
    for (int i = 0; i < 4; i++) {
        const int col = (w + 4 * i) * 16 + c;
#pragma unroll
        for (int nb = 0; nb < 2; nb++)
#pragma unroll
            for (int r = 0; r < 4; r++)
                Gb[(size_t)(n0 + nb * 16 + g * 4 + r) * LP + col] =
                    __float2bfloat16(acc[i][nb][r]);
    }
}

// score: S = tf.vt^T (gl_lds triple-buffer, counted vmcnt), softmax, num ->
// Pbuf + numq. Grid 1024, XCD-swizzled. (256,3): no spill. LDS 61440.
__global__ __launch_bounds__(256, 3) void score_kernel(
    const __hip_bfloat16* __restrict__ tf, const __hip_bfloat16* __restrict__ vt,
    const float* __restrict__ qinv, __hip_bfloat16* __restrict__ Pbuf,
    float* __restrict__ numq) {
    const int id = blockIdx.x;
    const int xcd = id & 7;
    const int kk = id >> 3;              // 0..127
    const int bhi = kk >> 4;             // 0..7
    const int nt = kk & 15;              // 0..15
    const int b = xcd + 8 * bhi;
    const int n0 = nt * 64;
    const int tid = threadIdx.x, w = tid >> 6, lane = tid & 63;
    const int g = lane >> 4, c = lane & 15;
    const int gsw = (g ^ ((c ^ (c >> 2)) & 3)) * 16;

    __shared__ __align__(16) unsigned char smem[61440];
    float* mx = (float*)smem;            // [64][4] overlay (post-stage1)
    float* sm = mx + 256;
    float* nm = sm + 256;

    const char* vtbc = (const char*)(vt + (size_t)b * LP * DD);
    const char* tfc = (const char*)(tf + (size_t)n0 * DD);

// vbuf[bsel] @ bsel*16384 (48KB), tbuf[bsel] @ 49152 + bsel*4096
#define SSTAGE(ks, bsel)                                                        \
    {                                                                           \
        const int kb_ = (ks) * 64;                                              \
        _Pragma("unroll")                                                       \
        for (int q_ = 0; q_ < 4; q_++) {                                        \
            const int o_ = q_ * 4096 + tid * 16;                                \
            const int r_ = o_ >> 6;                                             \
            const int sj_ = ((o_ >> 4) & 3) ^ ((r_ ^ (r_ >> 2)) & 3);           \
            gl_lds16(vtbc + (size_t)r_ * 1536 + kb_ + sj_ * 16,                 \
                     smem + (bsel) * 16384 + q_ * 4096 + w * 1024);             \
        }                                                                       \
        {                                                                       \
            const int o_ = tid * 16;                                            \
            const int r_ = o_ >> 6;                                             \
            const int sj_ = ((o_ >> 4) & 3) ^ ((r_ ^ (r_ >> 2)) & 3);           \
            gl_lds16(tfc + (size_t)r_ * 1536 + kb_ + sj_ * 16,                  \
                     smem + 49152 + (bsel) * 4096 + w * 1024);                  \
        }                                                                       \
    }

    f32x4 acc[4][4];
#pragma unroll
    for (int i = 0; i < 4; i++)
#pragma unroll
        for (int nb = 0; nb < 4; nb++) acc[i][nb] = {0.f, 0.f, 0.f, 0.f};

    SSTAGE(0, 0);
    SSTAGE(1, 1);
    asm volatile("s_waitcnt vmcnt(5)" ::: "memory");  // tile0 done
    __syncthreads();

    for (int ks = 0; ks < 24; ks++) {
        if (ks < 22) SSTAGE(ks + 2, (ks + 2) % 3);
        const unsigned char* vb = smem + (ks % 3) * 16384;
        const unsigned char* tb = smem + 49152 + (ks % 3) * 4096;
        short8 af[4], bf[4];
#pragma unroll
        for (int nb = 0; nb < 4; nb++)
            af[nb] = *(const short8*)(tb + (nb * 16 + c) * 64 + gsw);
#pragma unroll
        for (int i = 0; i < 4; i++)
            bf[i] = *(const short8*)(vb + ((w + 4 * i) * 16 + c) * 64 + gsw);
#pragma unroll
        for (int i = 0; i < 4; i++)
#pragma unroll
            for (int nb = 0; nb < 4; nb++)
                acc[i][nb] = __builtin_amdgcn_mfma_f32_16x16x32_bf16(
                    af[nb], bf[i], acc[i][nb], 0, 0, 0);
        if (ks < 22) asm volatile("s_waitcnt vmcnt(5)" ::: "memory");
        else         asm volatile("s_waitcnt vmcnt(0)" ::: "memory");
        __syncthreads();
    }
#undef SSTAGE

    // ---- softmax over l (waves hold disjoint l-columns) ----
    const float inv_sqrtD = 0.0360843918f;
    float mp[4][4];
#pragma unroll
    for (int nb = 0; nb < 4; nb++)
#pragma unroll
        for (int r = 0; r < 4; r++) mp[nb][r] = -1e30f;
#pragma unroll
    for (int i = 0; i < 4; i++) {
        const int l = (w + 4 * i) * 16 + c;
        if (l < LL) {
#pragma unroll
            for (int nb = 0; nb < 4; nb++)
#pragma unroll
                for (int r = 0; r < 4; r++) mp[nb][r] = fmaxf(mp[nb][r], acc[i][nb][r]);
        }
    }
#pragma unroll
    for (int nb = 0; nb < 4; nb++)
#pragma unroll
        for (int r = 0; r < 4; r++) mp[nb][r] = grpMax(mp[nb][r]);
    if (c == 0) {
#pragma unroll
        for (int nb = 0; nb < 4; nb++)
#pragma unroll
            for (int r = 0; r < 4; r++) mx[(nb * 16 + g * 4 + r) * 4 + w] = mp[nb][r];
    }
    __syncthreads();
    float mf[4][4];
#pragma unroll
    for (int nb = 0; nb < 4; nb++)
#pragma unroll
        for (int r = 0; r < 4; r++) {
            const int row = nb * 16 + g * 4 + r;
            mf[nb][r] = fmaxf(fmaxf(mx[row * 4 + 0], mx[row * 4 + 1]),
                              fmaxf(mx[row * 4 + 2], mx[row * 4 + 3]));
        }

    float sp[4][4], np[4][4];
#pragma unroll
    for (int nb = 0; nb < 4; nb++)
#pragma unroll
        for (int r = 0; r < 4; r++) { sp[nb][r] = 0.f; np[nb][r] = 0.f; }
#pragma unroll
    for (int i = 0; i < 4; i++) {
        const int l = (w + 4 * i) * 16 + c;
#pragma unroll
        for (int nb = 0; nb < 4; nb++)
#pragma unroll
            for (int r = 0; r < 4; r++) {
                const float raw = acc[i][nb][r];
                const float p = (l < LL) ? __expf((raw - mf[nb][r]) * inv_sqrtD) : 0.f;
                acc[i][nb][r] = p;
                sp[nb][r] += p;
                np[nb][r] += p * raw;
            }
    }
#pragma unroll
    for (int nb = 0; nb < 4; nb++)
#pragma unroll
        for (int r = 0; r < 4; r++) { sp[nb][r] = grpSum(sp[nb][r]); np[nb][r] = grpSum(np[nb][r]); }
    if (c == 0) {
#pragma unroll
        for (int nb = 0; nb < 4; nb++)
#pragma unroll
            for (int r = 0; r < 4; r++) {
                const int row = nb * 16 + g * 4 + r;
                sm[row * 4 + w] = sp[nb][r];
                nm[row * 4 + w] = np[nb][r];
            }
    }
    __syncthreads();

    float invs[4][4];
#pragma unroll
    for (int nb = 0; nb < 4; nb++)
#pragma unroll
        for (int r = 0; r < 4; r++) {
            const int row = nb * 16 + g * 4 + r;
            const float ssum = sm[row * 4 + 0] + sm[row * 4 + 1] + sm[row * 4 + 2] + sm[row * 4 + 3];
            invs[nb][r] = 1.f / ssum;
        }

    __hip_bfloat16* Pb = Pbuf + ((size_t)b * NN + n0) * LP;
#pragma unroll
    for (int i = 0; i < 4; i++) {
        const int lb = w + 4 * i;
#pragma unroll
        for (int nb = 0; nb < 4; nb++)
#pragma unroll
            for (int r = 0; r < 4; r++)
                Pb[(size_t)(nb * 16 + g * 4 + r) * LP + lb * 16 + c] =
                    __float2bfloat16(acc[i][nb][r] * invs[nb][r]);
    }

    if (tid < 64) {
        const int row = tid;
        const int n = n0 + row;
        const float ssum = sm[row * 4 + 0] + sm[row * 4 + 1] + sm[row * 4 + 2] + sm[row * 4 + 3];
        const float nsum = nm[row * 4 + 0] + nm[row * 4 + 1] + nm[row * 4 + 2] + nm[row * 4 + 3];
        numq[(size_t)n * BB + b] = (nsum / ssum) * qinv[n];
    }
}

// den: T = P.G (triple-buffer staged, counted vmcnt, 8 K-steps), den = sum P*T,
// logits = numq / ||agg||. Grid 1024, XCD-swizzled. (256,3). LDS 61440.
__global__ __launch_bounds__(256, 3) void den_kernel(
    const __hip_bfloat16* __restrict__ Pbuf, const __hip_bfloat16* __restrict__ G,
    const float* __restrict__ numq, float* __restrict__ logits) {
    const int id = blockIdx.x;
    const int xcd = id & 7;
    const int kk = id >> 3;
    const int bhi = kk >> 4;
    const int nt = kk & 15;
    const int b = xcd + 8 * bhi;
    const int n0 = nt * 64;
    const int tid = threadIdx.x, w = tid >> 6, lane = tid & 63;
    const int g = lane >> 4, c = lane & 15;
    const int gsw = (g ^ ((c ^ (c >> 2)) & 3)) * 16;

    __shared__ __align__(16) unsigned char smem[61440];
    float* mx = (float*)smem;            // [64][4] overlay (post-GEMM)

    const char* Gbc = (const char*)(G + (size_t)b * LP * LP);
    const char* Pbc = (const char*)(Pbuf + ((size_t)b * NN + n0) * LP);

#define DSTAGE(ks, bsel)                                                        \
    {                                                                           \
        const int kb_ = (ks) * 64;                                              \
        _Pragma("unroll")                                                       \
        for (int q_ = 0; q_ < 4; q_++) {                                        \
            const int o_ = q_ * 4096 + tid * 16;                                \
            const int r_ = o_ >> 6;                                             \
            const int sj_ = ((o_ >> 4) & 3) ^ ((r_ ^ (r_ >> 2)) & 3);           \
            gl_lds16(Gbc + (size_t)r_ * 512 + kb_ + sj_ * 16,                   \
                     smem + (bsel) * 16384 + q_ * 4096 + w * 1024);             \
        }                                                                       \
        {                                                                       \
            const int o_ = tid * 16;                                            \
            const int r_ = o_ >> 6;                                             \
            const int sj_ = ((o_ >> 4) & 3) ^ ((r_ ^ (r_ >> 2)) & 3);           \
            gl_lds16(Pbc + (size_t)r_ * 512 + kb_ + sj_ * 16,                   \
                     smem + 49152 + (bsel) * 4096 + w * 1024);                  \
        }                                                                       \
    }

    f32x4 acc[4][4];
#pragma unroll
    for (int i = 0; i < 4; i++)
#pragma unroll
        for (int nb = 0; nb < 4; nb++) acc[i][nb] = {0.f, 0.f, 0.f, 0.f};

    DSTAGE(0, 0);
    DSTAGE(1, 1);
    asm volatile("s_waitcnt vmcnt(5)" ::: "memory");
    __syncthreads();

    for (int ks = 0; ks < 8; ks++) {
        if (ks < 6) DSTAGE(ks + 2, (ks + 2) % 3);
        const unsigned char* vb = smem + (ks % 3) * 16384;
        const unsigned char* tb = smem + 49152 + (ks % 3) * 4096;
        short8 af[4], bf[4];
#pragma unroll
        for (int nb = 0; nb < 4; nb++)
            af[nb] = *(const short8*)(tb + (nb * 16 + c) * 64 + gsw);
#pragma unroll
        for (int i = 0; i < 4; i++)
            bf[i] = *(const short8*)(vb + ((w + 4 * i) * 16 + c) * 64 + gsw);
#pragma unroll
        for (int i = 0; i < 4; i++)
#pragma unroll
            for (int nb = 0; nb < 4; nb++)
                acc[i][nb] = __builtin_amdgcn_mfma_f32_16x16x32_bf16(
                    af[nb], bf[i], acc[i][nb], 0, 0, 0);
        if (ks < 6) asm volatile("s_waitcnt vmcnt(5)" ::: "memory");
        else        asm volatile("s_waitcnt vmcnt(0)" ::: "memory");
        __syncthreads();
    }
#undef DSTAGE

    // den = sum over cols of P * T (P re-read from L2-hot Pbuf)
    const short* Pb = (const short*)Pbc;
    float den[4][4];
#pragma unroll
    for (int nb = 0; nb < 4; nb++)
#pragma unroll
        for (int r = 0; r < 4; r++) den[nb][r] = 0.f;
#pragma unroll
    for (int i = 0; i < 4; i++) {
        const int col = (w + 4 * i) * 16 + c;
#pragma unroll
        for (int nb = 0; nb < 4; nb++)
#pragma unroll
            for (int r = 0; r < 4; r++) {
                const float P = bf2f((unsigned short)Pb[(size_t)(nb * 16 + g * 4 + r) * LP + col]);
                den[nb][r] += P * acc[i][nb][r];
            }
    }

#pragma unroll
    for (int nb = 0; nb < 4; nb++)
#pragma unroll
        for (int r = 0; r < 4; r++) den[nb][r] = grpSum(den[nb][r]);
    if (c == 0) {
#pragma unroll
        for (int nb = 0; nb < 4; nb++)
#pragma unroll
            for (int r = 0; r < 4; r++) mx[(nb * 16 + g * 4 + r) * 4 + w] = den[nb][r];
    }
    __syncthreads();
    if (tid < 64) {
        const int row = tid;
        const int n = n0 + row;
        const float dsum = mx[row * 4 + 0] + mx[row * 4 + 1] + mx[row * 4 + 2] + mx[row * 4 + 3];
        const float dn = fmaxf(sqrtf(fmaxf(dsum, 0.f)), NORM_EPS);
        logits[(size_t)n * BB + b] = numq[(size_t)n * BB + b] / dn;
    }
}

__global__ __launch_bounds__(64) void loss_row_kernel(
    const float* __restrict__ logits, const int* __restrict__ gm,
    const float* __restrict__ logtemp, float* __restrict__ scaled,
    float* __restrict__ posv, float* __restrict__ rowloss) {
    const int n = blockIdx.x;
    const int b = threadIdx.x;
    const float invtemp = 1.f / expf(logtemp[0]);
    const float e = expf(logits[(size_t)n * BB + b] * invtemp);
    scaled[(size_t)n * BB + b] = e;
    const float sum = waveSum(e);
    const int g = gm[n];
    const float pos = __shfl(e, g, 64);
    if (b == 0) {
        posv[n] = pos;
        rowloss[n] = -logf(pos / (sum + EPS) + EPS);
    }
}

__global__ __launch_bounds__(256) void colsum_kernel(
    const float* __restrict__ scaled, const int* __restrict__ gm,
    float* __restrict__ colsum, float* __restrict__ poscol) {
    const int b = blockIdx.x;
    const int tid = threadIdx.x;
    float s = 0.f, p = 0.f;
    for (int n = tid; n < NN; n += 256) {
        const float e = scaled[(size_t)n * BB + b];
        s += e;
        if (gm[n] == b) p += e;
    }
    s = waveSum(s); p = waveSum(p);
    __shared__ float red[8];
    const int w = tid >> 6;
    if ((tid & 63) == 0) { red[w] = s; red[4 + w] = p; }
    __syncthreads();
    if (tid == 0) {
        colsum[b] = red[0] + red[1] + red[2] + red[3];
        poscol[b] = red[4] + red[5] + red[6] + red[7];
    }
}

__global__ __launch_bounds__(1024) void final_kernel(
    const float* __restrict__ posv, const float* __restrict__ rowloss,
    const float* __restrict__ colsum, const float* __restrict__ poscol,
    const int* __restrict__ gm, float* __restrict__ out) {
    const int n = threadIdx.x;
    const int g = gm[n];
    const float pos = posv[n];
    const float sum_neg = colsum[g] - poscol[g];
    const float cl = -logf(pos / (pos + sum_neg + EPS) + EPS);
    float v = rowloss[n] + cl;
    v = waveSum(v);
    __shared__ float red[16];
    if ((n & 63) == 0) red[n >> 6] = v;
    __syncthreads();
    if (n == 0) {
        float s = 0.f;
#pragma unroll
        for (int i = 0; i < 16; i++) s += red[i];
        out[0] = s / (2.f * NN);
    }
}

extern "C" void kernel_launch(void* const* d_in, const int* in_sizes, int n_in,
                              void* d_out, int out_size, void* d_ws, size_t ws_size,
                              hipStream_t stream) {
    const float* text = (const float*)d_in[0];
    const float* vis = (const float*)d_in[1];
    const int* gm = (const int*)d_in[2];
    const float* gamma = (const float*)d_in[3];
    const float* beta = (const float*)d_in[4];
    const float* logtemp = (const float*)d_in[5];
    float* out = (float*)d_out;

    char* w = (char*)d_ws;
    __hip_bfloat16* tf = (__hip_bfloat16*)w;             w += (size_t)NN * DD * 2;
    __hip_bfloat16* vt = (__hip_bfloat16*)w;             w += (size_t)BB * LP * DD * 2;
    __hip_bfloat16* G  = (__hip_bfloat16*)w;             w += (size_t)BB * LP * LP * 2;
    __hip_bfloat16* Pbuf = (__hip_bfloat16*)w;           w += (size_t)BB * NN * LP * 2;
    float* qinv    = (float*)w;  w += (size_t)NN * 4;
    float* numq    = (float*)w;  w += (size_t)NN * BB * 4;
    float* logits  = (float*)w;  w += (size_t)NN * BB * 4;
    float* scaled  = (float*)w;  w += (size_t)NN * BB * 4;
    float* posv    = (float*)w;  w += (size_t)NN * 4;
    float* rowloss = (float*)w;  w += (size_t)NN * 4;
    float* colsum  = (float*)w;  w += (size_t)BB * 4;
    float* poscol  = (float*)w;  w += (size_t)BB * 4;

    ln_kernel<<<NN, 256, 0, stream>>>(text, tf, gamma, beta, qinv);
    ln_vis_kernel<<<BB * LP, 256, 0, stream>>>(vis, vt, gamma, beta);

    score_kernel<<<1024, 256, 0, stream>>>(tf, vt, qinv, Pbuf, numq);
    gram_kernel<<<512, 256, 0, stream>>>(vt, G);
    den_kernel<<<1024, 256, 0, stream>>>(Pbuf, G, numq, logits);

    loss_row_kernel<<<NN, 64, 0, stream>>>(logits, gm, logtemp, scaled, posv, rowloss);
    colsum_kernel<<<BB, 256, 0, stream>>>(scaled, gm, colsum, poscol);
    final_kernel<<<1, 1024, 0, stream>>>(posv, rowloss, colsum, poscol, gm, out);
}

// Round 15
// 119.110 us; speedup vs baseline: 2.2610x; 1.0337x over previous
//
#include <hip/hip_runtime.h>
#include <hip/hip_bf16.h>
#include <math.h>

#define NN 1024
#define BB 64
#define LL 197
#define LP 256
#define DD 768

typedef __attribute__((ext_vector_type(8))) short short8;
typedef __attribute__((ext_vector_type(4))) float f32x4;

constexpr float LN_EPS = 1e-5f;
constexpr float NORM_EPS = 1e-12f;
constexpr float EPS = 1e-8f;

__device__ __forceinline__ float waveSum(float v) {
#pragma unroll
    for (int m = 32; m >= 1; m >>= 1) v += __shfl_xor(v, m, 64);
    return v;
}
__device__ __forceinline__ float grpSum(float v) {
#pragma unroll
    for (int m = 8; m >= 1; m >>= 1) v += __shfl_xor(v, m, 64);
    return v;
}
__device__ __forceinline__ float grpMax(float v) {
#pragma unroll
    for (int m = 8; m >= 1; m >>= 1) v = fmaxf(v, __shfl_xor(v, m, 64));
    return v;
}

__device__ __forceinline__ float bf2f(unsigned short u) {
    unsigned int x = ((unsigned int)u) << 16;
    return reinterpret_cast<float&>(x);
}

__device__ __forceinline__ void gl_lds16(const void* g, void* l) {
    __builtin_amdgcn_global_load_lds(
        (const __attribute__((address_space(1))) unsigned int*)g,
        (__attribute__((address_space(3))) unsigned int*)l, 16, 0, 0);
}

// Raw barrier (no compiler-inserted vmcnt(0) drain) + scheduling pin.
__device__ __forceinline__ void raw_barrier() {
    __builtin_amdgcn_sched_barrier(0);
    __builtin_amdgcn_s_barrier();
    __builtin_amdgcn_sched_barrier(0);
}

// Text LayerNorm -> bf16 + qinv = 1/max(||y||,eps)
__global__ __launch_bounds__(256) void ln_kernel(
    const float* __restrict__ x, __hip_bfloat16* __restrict__ y,
    const float* __restrict__ gamma, const float* __restrict__ beta,
    float* __restrict__ qinv) {
    const int row = blockIdx.x;
    const int tid = threadIdx.x;
    const float* xr = x + (size_t)row * DD;
    __hip_bfloat16* yr = y + (size_t)row * DD;

    float v[3];
    float s = 0.f, ss = 0.f;
#pragma unroll
    for (int c = 0; c < 3; c++) {
        float t = xr[tid + 256 * c];
        v[c] = t; s += t; ss += t * t;
    }
    __shared__ float red[8];
    s = waveSum(s); ss = waveSum(ss);
    const int w = tid >> 6;
    if ((tid & 63) == 0) { red[w] = s; red[4 + w] = ss; }
    __syncthreads();
    s = red[0] + red[1] + red[2] + red[3];
    ss = red[4] + red[5] + red[6] + red[7];
    const float mean = s * (1.f / DD);
    const float var = ss * (1.f / DD) - mean * mean;
    const float rs = rsqrtf(var + LN_EPS);

    float q = 0.f;
#pragma unroll
    for (int c = 0; c < 3; c++) {
        const int d = tid + 256 * c;
        float t = (v[c] - mean) * rs * gamma[d] + beta[d];
        __hip_bfloat16 hb = __float2bfloat16(t);
        yr[d] = hb;
        float tb = __bfloat162float(hb);
        q += tb * tb;
    }
    __syncthreads();
    q = waveSum(q);
    if ((tid & 63) == 0) red[w] = q;
    __syncthreads();
    if (tid == 0) {
        float n2 = red[0] + red[1] + red[2] + red[3];
        qinv[row] = 1.f / fmaxf(sqrtf(n2), NORM_EPS);
    }
}

// Vision LayerNorm into padded [B, LP, D]; XCD-swizzled: blockid ≡ b (mod 8).
__global__ __launch_bounds__(256) void ln_vis_kernel(
    const float* __restrict__ x, __hip_bfloat16* __restrict__ y,
    const float* __restrict__ gamma, const float* __restrict__ beta) {
    const int id = blockIdx.x;           // 0..BB*LP-1 (16384)
    const int xcd = id & 7;
    const int k = id >> 3;               // 0..2047
    const int bhi = k >> 8;              // 0..7
    const int l = k & 255;               // 0..255
    const int b = xcd + 8 * bhi;
    const int tid = threadIdx.x;
    __hip_bfloat16* yr = y + ((size_t)b * LP + l) * DD;
    if (l >= LL) {
#pragma unroll
        for (int c = 0; c < 3; c++) yr[tid + 256 * c] = __float2bfloat16(0.f);
        return;
    }
    const float* xr = x + ((size_t)b * LL + l) * DD;

    float v[3];
    float s = 0.f, ss = 0.f;
#pragma unroll
    for (int c = 0; c < 3; c++) {
        float t = xr[tid + 256 * c];
        v[c] = t; s += t; ss += t * t;
    }
    __shared__ float red[8];
    s = waveSum(s); ss = waveSum(ss);
    const int w = tid >> 6;
    if ((tid & 63) == 0) { red[w] = s; red[4 + w] = ss; }
    __syncthreads();
    s = red[0] + red[1] + red[2] + red[3];
    ss = red[4] + red[5] + red[6] + red[7];
    const float mean = s * (1.f / DD);
    const float var = ss * (1.f / DD) - mean * mean;
    const float rs = rsqrtf(var + LN_EPS);
#pragma unroll
    for (int c = 0; c < 3; c++) {
        const int d = tid + 256 * c;
        yr[d] = __float2bfloat16((v[c] - mean) * rs * gamma[d] + beta[d]);
    }
}

// Gram: G[b] = vt_b . vt_b^T, gl_lds triple-buffer + counted vmcnt + raw
// barriers. Grid 512 (2/CU exactly), XCD-swizzled. LDS 55296.
__global__ __launch_bounds__(256, 2) void gram_kernel(
    const __hip_bfloat16* __restrict__ vt, __hip_bfloat16* __restrict__ G) {
    const int id = blockIdx.x;           // 0..511
    const int xcd = id & 7;
    const int k = id >> 3;               // 0..63
    const int bhi = k >> 3;              // 0..7
    const int rb = k & 7;                // 0..7
    const int b = xcd + 8 * bhi;
    const int n0 = rb * 32;
    const int tid = threadIdx.x, w = tid >> 6, lane = tid & 63;
    const int g = lane >> 4, c = lane & 15;
    const int gsw = (g ^ ((c ^ (c >> 2)) & 3)) * 16;

    __shared__ __align__(16) unsigned char smem[55296];
    const char* vtbc = (const char*)(vt + (size_t)b * LP * DD);

// vbuf[bsel] @ bsel*16384 (48KB), tbuf[bsel] @ 49152 + bsel*2048
#define GSTAGE(ks, bsel)                                                        \
    {                                                                           \
        const int kb_ = (ks) * 64;                                              \
        _Pragma("unroll")                                                       \
        for (int q_ = 0; q_ < 4; q_++) {                                        \
            const int o_ = q_ * 4096 + tid * 16;                                \
            const int r_ = o_ >> 6;                                             \
            const int sj_ = ((o_ >> 4) & 3) ^ ((r_ ^ (r_ >> 2)) & 3);           \
            gl_lds16(vtbc + (size_t)r_ * 1536 + kb_ + sj_ * 16,                 \
                     smem + (bsel) * 16384 + q_ * 4096 + w * 1024);             \
        }                                                                       \
        if (w < 2) {                                                            \
            const int o_ = tid * 16;                                            \
            const int r_ = o_ >> 6;                                             \
            const int sj_ = ((o_ >> 4) & 3) ^ ((r_ ^ (r_ >> 2)) & 3);           \
            gl_lds16(vtbc + (size_t)(n0 + r_) * 1536 + kb_ + sj_ * 16,          \
                     smem + 49152 + (bsel) * 2048 + w * 1024);                  \
        }                                                                       \
    }

    f32x4 acc[4][2];
#pragma unroll
    for (int i = 0; i < 4; i++)
#pragma unroll
        for (int nb = 0; nb < 2; nb++) acc[i][nb] = {0.f, 0.f, 0.f, 0.f};

    GSTAGE(0, 0);
    GSTAGE(1, 1);
    asm volatile("s_waitcnt vmcnt(4)" ::: "memory");  // tile0 done
    raw_barrier();

    for (int ks = 0; ks < 24; ks++) {
        if (ks < 22) GSTAGE(ks + 2, (ks + 2) % 3);
        const unsigned char* vb = smem + (ks % 3) * 16384;
        const unsigned char* tb = smem + 49152 + (ks % 3) * 2048;
        short8 af[2], bf[4];
#pragma unroll
        for (int nb = 0; nb < 2; nb++)
            af[nb] = *(const short8*)(tb + (nb * 16 + c) * 64 + gsw);
#pragma unroll
        for (int i = 0; i < 4; i++)
            bf[i] = *(const short8*)(vb + ((w + 4 * i) * 16 + c) * 64 + gsw);
#pragma unroll
        for (int i = 0; i < 4; i++)
#pragma unroll
            for (int nb = 0; nb < 2; nb++)
                acc[i][nb] = __builtin_amdgcn_mfma_f32_16x16x32_bf16(
                    af[nb], bf[i], acc[i][nb], 0, 0, 0);
        __builtin_amdgcn_sched_barrier(0);
        if (ks < 22) asm volatile("s_waitcnt vmcnt(4)" ::: "memory");
        else         asm volatile("s_waitcnt vmcnt(0)" ::: "memory");
        raw_barrier();
    }
#undef GSTAGE

    __hip_bfloat16* Gb = G + (size_t)b * LP * LP;
#pragma unroll
    for (int i = 0; i < 4; i++) {
        const int col = (w + 4 * i) * 16 + c;
#pragma unroll
        for (int nb = 0; nb < 2; nb++)
#pragma unroll
            for (int r = 0; r < 4; r++)
                Gb[(size_t)(n0 + nb * 16 + g * 4 + r) * LP + col] =
                    __float2bfloat16(acc[i][nb][r]);
    }
}

// score: S = tf.vt^T (gl_lds double-buffer, counted vmcnt, raw barriers),
// softmax, num -> Pbuf + numq. Grid 1024, XCD-swizzled. (256,3). LDS 40960.
__global__ __launch_bounds__(256, 3) void score_kernel(
    const __hip_bfloat16* __restrict__ tf, const __hip_bfloat16* __restrict__ vt,
    const float* __restrict__ qinv, __hip_bfloat16* __restrict__ Pbuf,
    float* __restrict__ numq) {
    const int id = blockIdx.x;
    const int xcd = id & 7;
    const int kk = id >> 3;              // 0..127
    const int bhi = kk >> 4;             // 0..7
    const int nt = kk & 15;              // 0..15
    const int b = xcd + 8 * bhi;
    const int n0 = nt * 64;
    const int tid = threadIdx.x, w = tid >> 6, lane = tid & 63;
    const int g = lane >> 4, c = lane & 15;
    const int gsw = (g ^ ((c ^ (c >> 2)) & 3)) * 16;

    __shared__ __align__(16) unsigned char smem[40960];
    float* mx = (float*)smem;            // [64][4] overlay (post-stage1)
    float* sm = mx + 256;
    float* nm = sm + 256;

    const char* vtbc = (const char*)(vt + (size_t)b * LP * DD);
    const char* tfc = (const char*)(tf + (size_t)n0 * DD);

// vbuf[bsel] @ bsel*16384 (32KB), tbuf[bsel] @ 32768 + bsel*4096
#define SSTAGE(ks, bsel)                                                        \
    {                                                                           \
        const int kb_ = (ks) * 64;                                              \
        _Pragma("unroll")                                                       \
        for (int q_ = 0; q_ < 4; q_++) {                                        \
            const int o_ = q_ * 4096 + tid * 16;                                \
            const int r_ = o_ >> 6;                                             \
            const int sj_ = ((o_ >> 4) & 3) ^ ((r_ ^ (r_ >> 2)) & 3);           \
            gl_lds16(vtbc + (size_t)r_ * 1536 + kb_ + sj_ * 16,                 \
                     smem + (bsel) * 16384 + q_ * 4096 + w * 1024);             \
        }                                                                       \
        {                                                                       \
            const int o_ = tid * 16;                                            \
            const int r_ = o_ >> 6;                                             \
            const int sj_ = ((o_ >> 4) & 3) ^ ((r_ ^ (r_ >> 2)) & 3);           \
            gl_lds16(tfc + (size_t)r_ * 1536 + kb_ + sj_ * 16,                  \
                     smem + 32768 + (bsel) * 4096 + w * 1024);                  \
        }                                                                       \
    }

    f32x4 acc[4][4];
#pragma unroll
    for (int i = 0; i < 4; i++)
#pragma unroll
        for (int nb = 0; nb < 4; nb++) acc[i][nb] = {0.f, 0.f, 0.f, 0.f};

    SSTAGE(0, 0);
    SSTAGE(1, 1);
    asm volatile("s_waitcnt vmcnt(5)" ::: "memory");  // tile0 done
    raw_barrier();

    for (int ks = 0; ks < 24; ks++) {
        const unsigned char* vb = smem + (ks & 1) * 16384;
        const unsigned char* tb = smem + 32768 + (ks & 1) * 4096;
        short8 af[4], bf[4];
#pragma unroll
        for (int nb = 0; nb < 4; nb++)
            af[nb] = *(const short8*)(tb + (nb * 16 + c) * 64 + gsw);
#pragma unroll
        for (int i = 0; i < 4; i++)
            bf[i] = *(const short8*)(vb + ((w + 4 * i) * 16 + c) * 64 + gsw);
#pragma unroll
        for (int i = 0; i < 4; i++)
#pragma unroll
            for (int nb = 0; nb < 4; nb++)
                acc[i][nb] = __builtin_amdgcn_mfma_f32_16x16x32_bf16(
                    af[nb], bf[i], acc[i][nb], 0, 0, 0);
        // all waves done reading buf ks&1
        raw_barrier();
        if (ks < 22) {
            SSTAGE(ks + 2, ks & 1);
            asm volatile("s_waitcnt vmcnt(5)" ::: "memory");  // tile ks+1 done
        } else {
            asm volatile("s_waitcnt vmcnt(0)" ::: "memory");
        }
        raw_barrier();
    }
#undef SSTAGE

    // ---- softmax over l (waves hold disjoint l-columns) ----
    const float inv_sqrtD = 0.0360843918f;
    float mp[4][4];
#pragma unroll
    for (int nb = 0; nb < 4; nb++)
#pragma unroll
        for (int r = 0; r < 4; r++) mp[nb][r] = -1e30f;
#pragma unroll
    for (int i = 0; i < 4; i++) {
        const int l = (w + 4 * i) * 16 + c;
        if (l < LL) {
#pragma unroll
            for (int nb = 0; nb < 4; nb++)
#pragma unroll
                for (int r = 0; r < 4; r++) mp[nb][r] = fmaxf(mp[nb][r], acc[i][nb][r]);
        }
    }
#pragma unroll
    for (int nb = 0; nb < 4; nb++)
#pragma unroll
        for (int r = 0; r < 4; r++) mp[nb][r] = grpMax(mp[nb][r]);
    if (c == 0) {
#pragma unroll
        for (int nb = 0; nb < 4; nb++)
#pragma unroll
            for (int r = 0; r < 4; r++) mx[(nb * 16 + g * 4 + r) * 4 + w] = mp[nb][r];
    }
    __syncthreads();
    float mf[4][4];
#pragma unroll
    for (int nb = 0; nb < 4; nb++)
#pragma unroll
        for (int r = 0; r < 4; r++) {
            const int row = nb * 16 + g * 4 + r;
            mf[nb][r] = fmaxf(fmaxf(mx[row * 4 + 0], mx[row * 4 + 1]),
                              fmaxf(mx[row * 4 + 2], mx[row * 4 + 3]));
        }

    float sp[4][4], np[4][4];
#pragma unroll
    for (int nb = 0; nb < 4; nb++)
#pragma unroll
        for (int r = 0; r < 4; r++) { sp[nb][r] = 0.f; np[nb][r] = 0.f; }
#pragma unroll
    for (int i = 0; i < 4; i++) {
        const int l = (w + 4 * i) * 16 + c;
#pragma unroll
        for (int nb = 0; nb < 4; nb++)
#pragma unroll
            for (int r = 0; r < 4; r++) {
                const float raw = acc[i][nb][r];
                const float p = (l < LL) ? __expf((raw - mf[nb][r]) * inv_sqrtD) : 0.f;
                acc[i][nb][r] = p;
                sp[nb][r] += p;
                np[nb][r] += p * raw;
            }
    }
#pragma unroll
    for (int nb = 0; nb < 4; nb++)
#pragma unroll
        for (int r = 0; r < 4; r++) { sp[nb][r] = grpSum(sp[nb][r]); np[nb][r] = grpSum(np[nb][r]); }
    if (c == 0) {
#pragma unroll
        for (int nb = 0; nb < 4; nb++)
#pragma unroll
            for (int r = 0; r < 4; r++) {
                const int row = nb * 16 + g * 4 + r;
                sm[row * 4 + w] = sp[nb][r];
                nm[row * 4 + w] = np[nb][r];
            }
    }
    __syncthreads();

    float invs[4][4];
#pragma unroll
    for (int nb = 0; nb < 4; nb++)
#pragma unroll
        for (int r = 0; r < 4; r++) {
            const int row = nb * 16 + g * 4 + r;
            const float ssum = sm[row * 4 + 0] + sm[row * 4 + 1] + sm[row * 4 + 2] + sm[row * 4 + 3];
            invs[nb][r] = 1.f / ssum;
        }

    __hip_bfloat16* Pb = Pbuf + ((size_t)b * NN + n0) * LP;
#pragma unroll
    for (int i = 0; i < 4; i++) {
        const int lb = w + 4 * i;
#pragma unroll
        for (int nb = 0; nb < 4; nb++)
#pragma unroll
            for (int r = 0; r < 4; r++)
                Pb[(size_t)(nb * 16 + g * 4 + r) * LP + lb * 16 + c] =
                    __float2bfloat16(acc[i][nb][r] * invs[nb][r]);
    }

    if (tid < 64) {
        const int row = tid;
        const int n = n0 + row;
        const float ssum = sm[row * 4 + 0] + sm[row * 4 + 1] + sm[row * 4 + 2] + sm[row * 4 + 3];
        const float nsum = nm[row * 4 + 0] + nm[row * 4 + 1] + nm[row * 4 + 2] + nm[row * 4 + 3];
        numq[(size_t)n * BB + b] = (nsum / ssum) * qinv[n];
    }
}

// den: T = P.G (double-buffer staged, counted vmcnt, raw barriers, 8 K-steps),
// den = sum P*T, logits = numq / ||agg||. Grid 1024, XCD-swizzled. (256,3).
__global__ __launch_bounds__(256, 3) void den_kernel(
    const __hip_bfloat16* __restrict__ Pbuf, const __hip_bfloat16* __restrict__ G,
    const float* __restrict__ numq, float* __restrict__ logits) {
    const int id = blockIdx.x;
    const int xcd = id & 7;
    const int kk = id >> 3;
    const int bhi = kk >> 4;
    const int nt = kk & 15;
    const int b = xcd + 8 * bhi;
    const int n0 = nt * 64;
    const int tid = threadIdx.x, w = tid >> 6, lane = tid & 63;
    const int g = lane >> 4, c = lane & 15;
    const int gsw = (g ^ ((c ^ (c >> 2)) & 3)) * 16;

    __shared__ __align__(16) unsigned char smem[40960];
    float* mx = (float*)smem;            // [64][4] overlay (post-GEMM)

    const char* Gbc = (const char*)(G + (size_t)b * LP * LP);
    const char* Pbc = (const char*)(Pbuf + ((size_t)b * NN + n0) * LP);

#define DSTAGE(ks, bsel)                                                        \
    {                                                                           \
        const int kb_ = (ks) * 64;                                              \
        _Pragma("unroll")                                                       \
        for (int q_ = 0; q_ < 4; q_++) {                                        \
            const int o_ = q_ * 4096 + tid * 16;                                \
            const int r_ = o_ >> 6;                                             \
            const int sj_ = ((o_ >> 4) & 3) ^ ((r_ ^ (r_ >> 2)) & 3);           \
            gl_lds16(Gbc + (size_t)r_ * 512 + kb_ + sj_ * 16,                   \
                     smem + (bsel) * 16384 + q_ * 4096 + w * 1024);             \
        }                                                                       \
        {                                                                       \
            const int o_ = tid * 16;                                            \
            const int r_ = o_ >> 6;                                             \
            const int sj_ = ((o_ >> 4) & 3) ^ ((r_ ^ (r_ >> 2)) & 3);           \
            gl_lds16(Pbc + (size_t)r_ * 512 + kb_ + sj_ * 16,                   \
                     smem + 32768 + (bsel) * 4096 + w * 1024);                  \
        }                                                                       \
    }

    f32x4 acc[4][4];
#pragma unroll
    for (int i = 0; i < 4; i++)
#pragma unroll
        for (int nb = 0; nb < 4; nb++) acc[i][nb] = {0.f, 0.f, 0.f, 0.f};

    DSTAGE(0, 0);
    DSTAGE(1, 1);
    asm volatile("s_waitcnt vmcnt(5)" ::: "memory");
    raw_barrier();

    for (int ks = 0; ks < 8; ks++) {
        const unsigned char* vb = smem + (ks & 1) * 16384;
        const unsigned char* tb = smem + 32768 + (ks & 1) * 4096;
        short8 af[4], bf[4];
#pragma unroll
        for (int nb = 0; nb < 4; nb++)
            af[nb] = *(const short8*)(tb + (nb * 16 + c) * 64 + gsw);
#pragma unroll
        for (int i = 0; i < 4; i++)
            bf[i] = *(const short8*)(vb + ((w + 4 * i) * 16 + c) * 64 + gsw);
#pragma unroll
        for (int i = 0; i < 4; i++)
#pragma unroll
            for (int nb = 0; nb < 4; nb++)
                acc[i][nb] = __builtin_amdgcn_mfma_f32_16x16x32_bf16(
                    af[nb], bf[i], acc[i][nb], 0, 0, 0);
        raw_barrier();
        if (ks < 6) {
            DSTAGE(ks + 2, ks & 1);
            asm volatile("s_waitcnt vmcnt(5)" ::: "memory");
        } else {
            asm volatile("s_waitcnt vmcnt(0)" ::: "memory");
        }
        raw_barrier();
    }
#undef DSTAGE

    // den = sum over cols of P * T (P re-read from L2-hot Pbuf)
    const short* Pb = (const short*)Pbc;
    float den[4][4];
#pragma unroll
    for (int nb = 0; nb < 4; nb++)
#pragma unroll
        for (int r = 0; r < 4; r++) den[nb][r] = 0.f;
#pragma unroll
    for (int i = 0; i < 4; i++) {
        const int col = (w + 4 * i) * 16 + c;
#pragma unroll
        for (int nb = 0; nb < 4; nb++)
#pragma unroll
            for (int r = 0; r < 4; r++) {
                const float P = bf2f((unsigned short)Pb[(size_t)(nb * 16 + g * 4 + r) * LP + col]);
                den[nb][r] += P * acc[i][nb][r];
            }
    }

#pragma unroll
    for (int nb = 0; nb < 4; nb++)
#pragma unroll
        for (int r = 0; r < 4; r++) den[nb][r] = grpSum(den[nb][r]);
    __syncthreads();
    if (c == 0) {
#pragma unroll
        for (int nb = 0; nb < 4; nb++)
#pragma unroll
            for (int r = 0; r < 4; r++) mx[(nb * 16 + g * 4 + r) * 4 + w] = den[nb][r];
    }
    __syncthreads();
    if (tid < 64) {
        const int row = tid;
        const int n = n0 + row;
        const float dsum = mx[row * 4 + 0] + mx[row * 4 + 1] + mx[row * 4 + 2] + mx[row * 4 + 3];
        const float dn = fmaxf(sqrtf(fmaxf(dsum, 0.f)), NORM_EPS);
        logits[(size_t)n * BB + b] = numq[(size_t)n * BB + b] / dn;
    }
}

__global__ __launch_bounds__(64) void loss_row_kernel(
    const float* __restrict__ logits, const int* __restrict__ gm,
    const float* __restrict__ logtemp, float* __restrict__ scaled,
    float* __restrict__ posv, float* __restrict__ rowloss) {
    const int n = blockIdx.x;
    const int b = threadIdx.x;
    const float invtemp = 1.f / expf(logtemp[0]);
    const float e = expf(logits[(size_t)n * BB + b] * invtemp);
    scaled[(size_t)n * BB + b] = e;
    const float sum = waveSum(e);
    const int g = gm[n];
    const float pos = __shfl(e, g, 64);
    if (b == 0) {
        posv[n] = pos;
        rowloss[n] = -logf(pos / (sum + EPS) + EPS);
    }
}

__global__ __launch_bounds__(256) void colsum_kernel(
    const float* __restrict__ scaled, const int* __restrict__ gm,
    float* __restrict__ colsum, float* __restrict__ poscol) {
    const int b = blockIdx.x;
    const int tid = threadIdx.x;
    float s = 0.f, p = 0.f;
    for (int n = tid; n < NN; n += 256) {
        const float e = scaled[(size_t)n * BB + b];
        s += e;
        if (gm[n] == b) p += e;
    }
    s = waveSum(s); p = waveSum(p);
    __shared__ float red[8];
    const int w = tid >> 6;
    if ((tid & 63) == 0) { red[w] = s; red[4 + w] = p; }
    __syncthreads();
    if (tid == 0) {
        colsum[b] = red[0] + red[1] + red[2] + red[3];
        poscol[b] = red[4] + red[5] + red[6] + red[7];
    }
}

__global__ __launch_bounds__(1024) void final_kernel(
    const float* __restrict__ posv, const float* __restrict__ rowloss,
    const float* __restrict__ colsum, const float* __restrict__ poscol,
    const int* __restrict__ gm, float* __restrict__ out) {
    const int n = threadIdx.x;
    const int g = gm[n];
    const float pos = posv[n];
    const float sum_neg = colsum[g] - poscol[g];
    const float cl = -logf(pos / (pos + sum_neg + EPS) + EPS);
    float v = rowloss[n] + cl;
    v = waveSum(v);
    __shared__ float red[16];
    if ((n & 63) == 0) red[n >> 6] = v;
    __syncthreads();
    if (n == 0) {
        float s = 0.f;
#pragma unroll
        for (int i = 0; i < 16; i++) s += red[i];
        out[0] = s / (2.f * NN);
    }
}

extern "C" void kernel_launch(void* const* d_in, const int* in_sizes, int n_in,
                              void* d_out, int out_size, void* d_ws, size_t ws_size,
                              hipStream_t stream) {
    const float* text = (const float*)d_in[0];
    const float* vis = (const float*)d_in[1];
    const int* gm = (const int*)d_in[2];
    const float* gamma = (const float*)d_in[3];
    const float* beta = (const float*)d_in[4];
    const float* logtemp = (const float*)d_in[5];
    float* out = (float*)d_out;

    char* w = (char*)d_ws;
    __hip_bfloat16* tf = (__hip_bfloat16*)w;             w += (size_t)NN * DD * 2;
    __hip_bfloat16* vt = (__hip_bfloat16*)w;             w += (size_t)BB * LP * DD * 2;
    __hip_bfloat16* G  = (__hip_bfloat16*)w;             w += (size_t)BB * LP * LP * 2;
    __hip_bfloat16* Pbuf = (__hip_bfloat16*)w;           w += (size_t)BB * NN * LP * 2;
    float* qinv    = (float*)w;  w += (size_t)NN * 4;
    float* numq    = (float*)w;  w += (size_t)NN * BB * 4;
    float* logits  = (float*)w;  w += (size_t)NN * BB * 4;
    float* scaled  = (float*)w;  w += (size_t)NN * BB * 4;
    float* posv    = (float*)w;  w += (size_t)NN * 4;
    float* rowloss = (float*)w;  w += (size_t)NN * 4;
    float* colsum  = (float*)w;  w += (size_t)BB * 4;
    float* poscol  = (float*)w;  w += (size_t)BB * 4;

    ln_kernel<<<NN, 256, 0, stream>>>(text, tf, gamma, beta, qinv);
    ln_vis_kernel<<<BB * LP, 256, 0, stream>>>(vis, vt, gamma, beta);

    score_kernel<<<1024, 256, 0, stream>>>(tf, vt, qinv, Pbuf, numq);
    gram_kernel<<<512, 256, 0, stream>>>(vt, G);
    den_kernel<<<1024, 256, 0, stream>>>(Pbuf, G, numq, logits);

    loss_row_kernel<<<NN, 64, 0, stream>>>(logits, gm, logtemp, scaled, posv, rowloss);
    colsum_kernel<<<BB, 256, 0, stream>>>(scaled, gm, colsum, poscol);
    final_kernel<<<1, 1024, 0, stream>>>(posv, rowloss, colsum, poscol, gm, out);
}

// Round 16
// 116.417 us; speedup vs baseline: 2.3133x; 1.0231x over previous
//
#include <hip/hip_runtime.h>
#include <hip/hip_bf16.h>
#include <math.h>

#define NN 1024
#define BB 64
#define LL 197
#define LP 256
#define LBV 13        // valid l-blocks (l < 208 covers LL=197)
#define VROWS 208     // staged vt/G rows in score/den
#define DD 768

typedef __attribute__((ext_vector_type(8))) short short8;
typedef __attribute__((ext_vector_type(4))) float f32x4;

constexpr float LN_EPS = 1e-5f;
constexpr float NORM_EPS = 1e-12f;
constexpr float EPS = 1e-8f;

__device__ __forceinline__ float waveSum(float v) {
#pragma unroll
    for (int m = 32; m >= 1; m >>= 1) v += __shfl_xor(v, m, 64);
    return v;
}
__device__ __forceinline__ float grpSum(float v) {
#pragma unroll
    for (int m = 8; m >= 1; m >>= 1) v += __shfl_xor(v, m, 64);
    return v;
}
__device__ __forceinline__ float grpMax(float v) {
#pragma unroll
    for (int m = 8; m >= 1; m >>= 1) v = fmaxf(v, __shfl_xor(v, m, 64));
    return v;
}

__device__ __forceinline__ float bf2f(unsigned short u) {
    unsigned int x = ((unsigned int)u) << 16;
    return reinterpret_cast<float&>(x);
}

__device__ __forceinline__ void gl_lds16(const void* g, void* l) {
    __builtin_amdgcn_global_load_lds(
        (const __attribute__((address_space(1))) unsigned int*)g,
        (__attribute__((address_space(3))) unsigned int*)l, 16, 0, 0);
}

// Raw barrier (no compiler-inserted vmcnt(0) drain) + scheduling pin.
__device__ __forceinline__ void raw_barrier() {
    __builtin_amdgcn_sched_barrier(0);
    __builtin_amdgcn_s_barrier();
    __builtin_amdgcn_sched_barrier(0);
}

// Text LayerNorm -> bf16 + qinv = 1/max(||y||,eps)
__global__ __launch_bounds__(256) void ln_kernel(
    const float* __restrict__ x, __hip_bfloat16* __restrict__ y,
    const float* __restrict__ gamma, const float* __restrict__ beta,
    float* __restrict__ qinv) {
    const int row = blockIdx.x;
    const int tid = threadIdx.x;
    const float* xr = x + (size_t)row * DD;
    __hip_bfloat16* yr = y + (size_t)row * DD;

    float v[3];
    float s = 0.f, ss = 0.f;
#pragma unroll
    for (int c = 0; c < 3; c++) {
        float t = xr[tid + 256 * c];
        v[c] = t; s += t; ss += t * t;
    }
    __shared__ float red[8];
    s = waveSum(s); ss = waveSum(ss);
    const int w = tid >> 6;
    if ((tid & 63) == 0) { red[w] = s; red[4 + w] = ss; }
    __syncthreads();
    s = red[0] + red[1] + red[2] + red[3];
    ss = red[4] + red[5] + red[6] + red[7];
    const float mean = s * (1.f / DD);
    const float var = ss * (1.f / DD) - mean * mean;
    const float rs = rsqrtf(var + LN_EPS);

    float q = 0.f;
#pragma unroll
    for (int c = 0; c < 3; c++) {
        const int d = tid + 256 * c;
        float t = (v[c] - mean) * rs * gamma[d] + beta[d];
        __hip_bfloat16 hb = __float2bfloat16(t);
        yr[d] = hb;
        float tb = __bfloat162float(hb);
        q += tb * tb;
    }
    __syncthreads();
    q = waveSum(q);
    if ((tid & 63) == 0) red[w] = q;
    __syncthreads();
    if (tid == 0) {
        float n2 = red[0] + red[1] + red[2] + red[3];
        qinv[row] = 1.f / fmaxf(sqrtf(n2), NORM_EPS);
    }
}

// Vision LayerNorm into padded [B, LP, D]; XCD-swizzled: blockid ≡ b (mod 8).
__global__ __launch_bounds__(256) void ln_vis_kernel(
    const float* __restrict__ x, __hip_bfloat16* __restrict__ y,
    const float* __restrict__ gamma, const float* __restrict__ beta) {
    const int id = blockIdx.x;           // 0..BB*LP-1 (16384)
    const int xcd = id & 7;
    const int k = id >> 3;               // 0..2047
    const int bhi = k >> 8;              // 0..7
    const int l = k & 255;               // 0..255
    const int b = xcd + 8 * bhi;
    const int tid = threadIdx.x;
    __hip_bfloat16* yr = y + ((size_t)b * LP + l) * DD;
    if (l >= LL) {
#pragma unroll
        for (int c = 0; c < 3; c++) yr[tid + 256 * c] = __float2bfloat16(0.f);
        return;
    }
    const float* xr = x + ((size_t)b * LL + l) * DD;

    float v[3];
    float s = 0.f, ss = 0.f;
#pragma unroll
    for (int c = 0; c < 3; c++) {
        float t = xr[tid + 256 * c];
        v[c] = t; s += t; ss += t * t;
    }
    __shared__ float red[8];
    s = waveSum(s); ss = waveSum(ss);
    const int w = tid >> 6;
    if ((tid & 63) == 0) { red[w] = s; red[4 + w] = ss; }
    __syncthreads();
    s = red[0] + red[1] + red[2] + red[3];
    ss = red[4] + red[5] + red[6] + red[7];
    const float mean = s * (1.f / DD);
    const float var = ss * (1.f / DD) - mean * mean;
    const float rs = rsqrtf(var + LN_EPS);
#pragma unroll
    for (int c = 0; c < 3; c++) {
        const int d = tid + 256 * c;
        yr[d] = __float2bfloat16((v[c] - mean) * rs * gamma[d] + beta[d]);
    }
}

// Gram: G[b] = vt_b . vt_b^T, gl_lds triple-buffer + counted vmcnt + raw
// barriers. Grid 512 (2/CU exactly), XCD-swizzled. LDS 55296. (unchanged r15)
__global__ __launch_bounds__(256, 2) void gram_kernel(
    const __hip_bfloat16* __restrict__ vt, __hip_bfloat16* __restrict__ G) {
    const int id = blockIdx.x;           // 0..511
    const int xcd = id & 7;
    const int k = id >> 3;               // 0..63
    const int bhi = k >> 3;              // 0..7
    const int rb = k & 7;                // 0..7
    const int b = xcd + 8 * bhi;
    const int n0 = rb * 32;
    const int tid = threadIdx.x, w = tid >> 6, lane = tid & 63;
    const int g = lane >> 4, c = lane & 15;
    const int gsw = (g ^ ((c ^ (c >> 2)) & 3)) * 16;

    __shared__ __align__(16) unsigned char smem[55296];
    const char* vtbc = (const char*)(vt + (size_t)b * LP * DD);

#define GSTAGE(ks, bsel)                                                        \
    {                                                                           \
        const int kb_ = (ks) * 64;                                              \
        _Pragma("unroll")                                                       \
        for (int q_ = 0; q_ < 4; q_++) {                                        \
            const int o_ = q_ * 4096 + tid * 16;                                \
            const int r_ = o_ >> 6;                                             \
            const int sj_ = ((o_ >> 4) & 3) ^ ((r_ ^ (r_ >> 2)) & 3);           \
            gl_lds16(vtbc + (size_t)r_ * 1536 + kb_ + sj_ * 16,                 \
                     smem + (bsel) * 16384 + q_ * 4096 + w * 1024);             \
        }                                                                       \
        if (w < 2) {                                                            \
            const int o_ = tid * 16;                                            \
            const int r_ = o_ >> 6;                                             \
            const int sj_ = ((o_ >> 4) & 3) ^ ((r_ ^ (r_ >> 2)) & 3);           \
            gl_lds16(vtbc + (size_t)(n0 + r_) * 1536 + kb_ + sj_ * 16,          \
                     smem + 49152 + (bsel) * 2048 + w * 1024);                  \
        }                                                                       \
    }

    f32x4 acc[4][2];
#pragma unroll
    for (int i = 0; i < 4; i++)
#pragma unroll
        for (int nb = 0; nb < 2; nb++) acc[i][nb] = {0.f, 0.f, 0.f, 0.f};

    GSTAGE(0, 0);
    GSTAGE(1, 1);
    asm volatile("s_waitcnt vmcnt(4)" ::: "memory");
    raw_barrier();

    for (int ks = 0; ks < 24; ks++) {
        if (ks < 22) GSTAGE(ks + 2, (ks + 2) % 3);
        const unsigned char* vb = smem + (ks % 3) * 16384;
        const unsigned char* tb = smem + 49152 + (ks % 3) * 2048;
        short8 af[2], bf[4];
#pragma unroll
        for (int nb = 0; nb < 2; nb++)
            af[nb] = *(const short8*)(tb + (nb * 16 + c) * 64 + gsw);
#pragma unroll
        for (int i = 0; i < 4; i++)
            bf[i] = *(const short8*)(vb + ((w + 4 * i) * 16 + c) * 64 + gsw);
#pragma unroll
        for (int i = 0; i < 4; i++)
#pragma unroll
            for (int nb = 0; nb < 2; nb++)
                acc[i][nb] = __builtin_amdgcn_mfma_f32_16x16x32_bf16(
                    af[nb], bf[i], acc[i][nb], 0, 0, 0);
        __builtin_amdgcn_sched_barrier(0);
        if (ks < 22) asm volatile("s_waitcnt vmcnt(4)" ::: "memory");
        else         asm volatile("s_waitcnt vmcnt(0)" ::: "memory");
        raw_barrier();
    }
#undef GSTAGE

    __hip_bfloat16* Gb = G + (size_t)b * LP * LP;
#pragma unroll
    for (int i = 0; i < 4; i++) {
        const int col = (w + 4 * i) * 16 + c;
#pragma unroll
        for (int nb = 0; nb < 2; nb++)
#pragma unroll
            for (int r = 0; r < 4; r++)
                Gb[(size_t)(n0 + nb * 16 + g * 4 + r) * LP + col] =
                    __float2bfloat16(acc[i][nb][r]);
    }
}

// score: S = tf.vt^T over 13 real l-blocks only (208 staged vt rows),
// gl_lds double-buffer, counted vmcnt, raw barriers, softmax, num ->
// Pbuf + numq. Grid 1024, XCD-swizzled. (256,3). LDS 34816 -> 4 blocks/CU.
__global__ __launch_bounds__(256, 3) void score_kernel(
    const __hip_bfloat16* __restrict__ tf, const __hip_bfloat16* __restrict__ vt,
    const float* __restrict__ qinv, __hip_bfloat16* __restrict__ Pbuf,
    float* __restrict__ numq) {
    const int id = blockIdx.x;
    const int xcd = id & 7;
    const int kk = id >> 3;              // 0..127
    const int bhi = kk >> 4;             // 0..7
    const int nt = kk & 15;              // 0..15
    const int b = xcd + 8 * bhi;
    const int n0 = nt * 64;
    const int tid = threadIdx.x, w = tid >> 6, lane = tid & 63;
    const int g = lane >> 4, c = lane & 15;
    const int gsw = (g ^ ((c ^ (c >> 2)) & 3)) * 16;

    __shared__ __align__(16) unsigned char smem[34816];
    float* mx = (float*)smem;            // [64][4] overlay (post-stage1)
    float* sm = mx + 256;
    float* nm = sm + 256;

    const char* vtbc = (const char*)(vt + (size_t)b * LP * DD);
    const char* tfc = (const char*)(tf + (size_t)n0 * DD);

// vbuf[bsel] @ bsel*13312 (208 rows x 64B), tbuf[bsel] @ 26624 + bsel*4096.
// 3 full rounds + distributed tail (lanes<16; uniform 5 gl_lds per wave).
#define SSTAGE(ks, bsel)                                                        \
    {                                                                           \
        const int kb_ = (ks) * 64;                                              \
        _Pragma("unroll")                                                       \
        for (int q_ = 0; q_ < 3; q_++) {                                        \
            const int o_ = q_ * 4096 + tid * 16;                                \
            const int r_ = o_ >> 6;                                             \
            const int sj_ = ((o_ >> 4) & 3) ^ ((r_ ^ (r_ >> 2)) & 3);           \
            gl_lds16(vtbc + (size_t)r_ * 1536 + kb_ + sj_ * 16,                 \
                     smem + (bsel) * 13312 + q_ * 4096 + w * 1024);             \
        }                                                                       \
        if (lane < 16) {                                                        \
            const int o_ = 12288 + (w * 16 + lane) * 16;                        \
            const int r_ = o_ >> 6;                                             \
            const int sj_ = ((o_ >> 4) & 3) ^ ((r_ ^ (r_ >> 2)) & 3);           \
            gl_lds16(vtbc + (size_t)r_ * 1536 + kb_ + sj_ * 16,                 \
                     smem + (bsel) * 13312 + 12288 + w * 256);                  \
        }                                                                       \
        {                                                                       \
            const int o_ = tid * 16;                                            \
            const int r_ = o_ >> 6;                                             \
            const int sj_ = ((o_ >> 4) & 3) ^ ((r_ ^ (r_ >> 2)) & 3);           \
            gl_lds16(tfc + (size_t)r_ * 1536 + kb_ + sj_ * 16,                  \
                     smem + 26624 + (bsel) * 4096 + w * 1024);                  \
        }                                                                       \
    }

    f32x4 acc[4][4];
#pragma unroll
    for (int i = 0; i < 4; i++)
#pragma unroll
        for (int nb = 0; nb < 4; nb++) acc[i][nb] = {0.f, 0.f, 0.f, 0.f};

    SSTAGE(0, 0);
    SSTAGE(1, 1);
    asm volatile("s_waitcnt vmcnt(5)" ::: "memory");
    raw_barrier();

    for (int ks = 0; ks < 24; ks++) {
        const unsigned char* vb = smem + (ks & 1) * 13312;
        const unsigned char* tb = smem + 26624 + (ks & 1) * 4096;
        short8 af[4];
#pragma unroll
        for (int nb = 0; nb < 4; nb++)
            af[nb] = *(const short8*)(tb + (nb * 16 + c) * 64 + gsw);
#pragma unroll
        for (int i = 0; i < 4; i++) {
            const int lb = w + 4 * i;
            if (lb < LBV) {
                short8 bfv = *(const short8*)(vb + (lb * 16 + c) * 64 + gsw);
#pragma unroll
                for (int nb = 0; nb < 4; nb++)
                    acc[i][nb] = __builtin_amdgcn_mfma_f32_16x16x32_bf16(
                        af[nb], bfv, acc[i][nb], 0, 0, 0);
            }
        }
        raw_barrier();
        if (ks < 22) {
            SSTAGE(ks + 2, ks & 1);
            asm volatile("s_waitcnt vmcnt(5)" ::: "memory");
        } else {
            asm volatile("s_waitcnt vmcnt(0)" ::: "memory");
        }
        raw_barrier();
    }
#undef SSTAGE

    // ---- softmax over l (waves hold disjoint l-columns) ----
    const float inv_sqrtD = 0.0360843918f;
    float mp[4][4];
#pragma unroll
    for (int nb = 0; nb < 4; nb++)
#pragma unroll
        for (int r = 0; r < 4; r++) mp[nb][r] = -1e30f;
#pragma unroll
    for (int i = 0; i < 4; i++) {
        const int l = (w + 4 * i) * 16 + c;
        if (l < LL) {
#pragma unroll
            for (int nb = 0; nb < 4; nb++)
#pragma unroll
                for (int r = 0; r < 4; r++) mp[nb][r] = fmaxf(mp[nb][r], acc[i][nb][r]);
        }
    }
#pragma unroll
    for (int nb = 0; nb < 4; nb++)
#pragma unroll
        for (int r = 0; r < 4; r++) mp[nb][r] = grpMax(mp[nb][r]);
    if (c == 0) {
#pragma unroll
        for (int nb = 0; nb < 4; nb++)
#pragma unroll
            for (int r = 0; r < 4; r++) mx[(nb * 16 + g * 4 + r) * 4 + w] = mp[nb][r];
    }
    __syncthreads();
    float mf[4][4];
#pragma unroll
    for (int nb = 0; nb < 4; nb++)
#pragma unroll
        for (int r = 0; r < 4; r++) {
            const int row = nb * 16 + g * 4 + r;
            mf[nb][r] = fmaxf(fmaxf(mx[row * 4 + 0], mx[row * 4 + 1]),
                              fmaxf(mx[row * 4 + 2], mx[row * 4 + 3]));
        }

    float sp[4][4], np[4][4];
#pragma unroll
    for (int nb = 0; nb < 4; nb++)
#pragma unroll
        for (int r = 0; r < 4; r++) { sp[nb][r] = 0.f; np[nb][r] = 0.f; }
#pragma unroll
    for (int i = 0; i < 4; i++) {
        const int l = (w + 4 * i) * 16 + c;
#pragma unroll
        for (int nb = 0; nb < 4; nb++)
#pragma unroll
            for (int r = 0; r < 4; r++) {
                const float raw = acc[i][nb][r];
                const float p = (l < LL) ? __expf((raw - mf[nb][r]) * inv_sqrtD) : 0.f;
                acc[i][nb][r] = p;
                sp[nb][r] += p;
                np[nb][r] += p * raw;
            }
    }
#pragma unroll
    for (int nb = 0; nb < 4; nb++)
#pragma unroll
        for (int r = 0; r < 4; r++) { sp[nb][r] = grpSum(sp[nb][r]); np[nb][r] = grpSum(np[nb][r]); }
    if (c == 0) {
#pragma unroll
        for (int nb = 0; nb < 4; nb++)
#pragma unroll
            for (int r = 0; r < 4; r++) {
                const int row = nb * 16 + g * 4 + r;
                sm[row * 4 + w] = sp[nb][r];
                nm[row * 4 + w] = np[nb][r];
            }
    }
    __syncthreads();

    float invs[4][4];
#pragma unroll
    for (int nb = 0; nb < 4; nb++)
#pragma unroll
        for (int r = 0; r < 4; r++) {
            const int row = nb * 16 + g * 4 + r;
            const float ssum = sm[row * 4 + 0] + sm[row * 4 + 1] + sm[row * 4 + 2] + sm[row * 4 + 3];
            invs[nb][r] = 1.f / ssum;
        }

    // P write: all 16 l-blocks (invalid/pad blocks hold p=0 -> writes zeros)
    __hip_bfloat16* Pb = Pbuf + ((size_t)b * NN + n0) * LP;
#pragma unroll
    for (int i = 0; i < 4; i++) {
        const int lb = w + 4 * i;
#pragma unroll
        for (int nb = 0; nb < 4; nb++)
#pragma unroll
            for (int r = 0; r < 4; r++)
                Pb[(size_t)(nb * 16 + g * 4 + r) * LP + lb * 16 + c] =
                    __float2bfloat16(acc[i][nb][r] * invs[nb][r]);
    }

    if (tid < 64) {
        const int row = tid;
        const int n = n0 + row;
        const float ssum = sm[row * 4 + 0] + sm[row * 4 + 1] + sm[row * 4 + 2] + sm[row * 4 + 3];
        const float nsum = nm[row * 4 + 0] + nm[row * 4 + 1] + nm[row * 4 + 2] + nm[row * 4 + 3];
        numq[(size_t)n * BB + b] = (nsum / ssum) * qinv[n];
    }
}

// den: T = P.G over 13 col-blocks, K=224 (7 steps; P cols >=208 are zero),
// den = sum P*T, logits = numq / ||agg||. Grid 1024, XCD-swizzled. (256,3).
// LDS 34816 (208 G rows + 64 P rows, double-buffered).
__global__ __launch_bounds__(256, 3) void den_kernel(
    const __hip_bfloat16* __restrict__ Pbuf, const __hip_bfloat16* __restrict__ G,
    const float* __restrict__ numq, float* __restrict__ logits) {
    const int id = blockIdx.x;
    const int xcd = id & 7;
    const int kk = id >> 3;
    const int bhi = kk >> 4;
    const int nt = kk & 15;
    const int b = xcd + 8 * bhi;
    const int n0 = nt * 64;
    const int tid = threadIdx.x, w = tid >> 6, lane = tid & 63;
    const int g = lane >> 4, c = lane & 15;
    const int gsw = (g ^ ((c ^ (c >> 2)) & 3)) * 16;

    __shared__ __align__(16) unsigned char smem[34816];
    float* mx = (float*)smem;            // [64][4] overlay (post-GEMM)

    const char* Gbc = (const char*)(G + (size_t)b * LP * LP);
    const char* Pbc = (const char*)(Pbuf + ((size_t)b * NN + n0) * LP);

#define DSTAGE(ks, bsel)                                                        \
    {                                                                           \
        const int kb_ = (ks) * 64;                                              \
        _Pragma("unroll")                                                       \
        for (int q_ = 0; q_ < 3; q_++) {                                        \
            const int o_ = q_ * 4096 + tid * 16;                                \
            const int r_ = o_ >> 6;                                             \
            const int sj_ = ((o_ >> 4) & 3) ^ ((r_ ^ (r_ >> 2)) & 3);           \
            gl_lds16(Gbc + (size_t)r_ * 512 + kb_ + sj_ * 16,                   \
                     smem + (bsel) * 13312 + q_ * 4096 + w * 1024);             \
        }                                                                       \
        if (lane < 16) {                                                        \
            const int o_ = 12288 + (w * 16 + lane) * 16;                        \
            const int r_ = o_ >> 6;                                             \
            const int sj_ = ((o_ >> 4) & 3) ^ ((r_ ^ (r_ >> 2)) & 3);           \
            gl_lds16(Gbc + (size_t)r_ * 512 + kb_ + sj_ * 16,                   \
                     smem + (bsel) * 13312 + 12288 + w * 256);                  \
        }                                                                       \
        {                                                                       \
            const int o_ = tid * 16;                                            \
            const int r_ = o_ >> 6;                                             \
            const int sj_ = ((o_ >> 4) & 3) ^ ((r_ ^ (r_ >> 2)) & 3);           \
            gl_lds16(Pbc + (size_t)r_ * 512 + kb_ + sj_ * 16,                   \
                     smem + 26624 + (bsel) * 4096 + w * 1024);                  \
        }                                                                       \
    }

    f32x4 acc[4][4];
#pragma unroll
    for (int i = 0; i < 4; i++)
#pragma unroll
        for (int nb = 0; nb < 4; nb++) acc[i][nb] = {0.f, 0.f, 0.f, 0.f};

    DSTAGE(0, 0);
    DSTAGE(1, 1);
    asm volatile("s_waitcnt vmcnt(5)" ::: "memory");
    raw_barrier();

    for (int ks = 0; ks < 7; ks++) {
        const unsigned char* vb = smem + (ks & 1) * 13312;
        const unsigned char* tb = smem + 26624 + (ks & 1) * 4096;
        short8 af[4];
#pragma unroll
        for (int nb = 0; nb < 4; nb++)
            af[nb] = *(const short8*)(tb + (nb * 16 + c) * 64 + gsw);
#pragma unroll
        for (int i = 0; i < 4; i++) {
            const int lb = w + 4 * i;
            if (lb < LBV) {
                short8 bfv = *(const short8*)(vb + (lb * 16 + c) * 64 + gsw);
#pragma unroll
                for (int nb = 0; nb < 4; nb++)
                    acc[i][nb] = __builtin_amdgcn_mfma_f32_16x16x32_bf16(
                        af[nb], bfv, acc[i][nb], 0, 0, 0);
            }
        }
        raw_barrier();
        if (ks < 5) {
            DSTAGE(ks + 2, ks & 1);
            asm volatile("s_waitcnt vmcnt(5)" ::: "memory");
        } else {
            asm volatile("s_waitcnt vmcnt(0)" ::: "memory");
        }
        raw_barrier();
    }
#undef DSTAGE

    // den = sum over valid cols of P * T (P re-read from L2-hot Pbuf)
    const short* Pb = (const short*)Pbc;
    float den[4][4];
#pragma unroll
    for (int nb = 0; nb < 4; nb++)
#pragma unroll
        for (int r = 0; r < 4; r++) den[nb][r] = 0.f;
#pragma unroll
    for (int i = 0; i < 4; i++) {
        const int lb = w + 4 * i;
        if (lb < LBV) {
            const int col = lb * 16 + c;
#pragma unroll
            for (int nb = 0; nb < 4; nb++)
#pragma unroll
                for (int r = 0; r < 4; r++) {
                    const float P = bf2f((unsigned short)Pb[(size_t)(nb * 16 + g * 4 + r) * LP + col]);
                    den[nb][r] += P * acc[i][nb][r];
                }
        }
    }

#pragma unroll
    for (int nb = 0; nb < 4; nb++)
#pragma unroll
        for (int r = 0; r < 4; r++) den[nb][r] = grpSum(den[nb][r]);
    __syncthreads();
    if (c == 0) {
#pragma unroll
        for (int nb = 0; nb < 4; nb++)
#pragma unroll
            for (int r = 0; r < 4; r++) mx[(nb * 16 + g * 4 + r) * 4 + w] = den[nb][r];
    }
    __syncthreads();
    if (tid < 64) {
        const int row = tid;
        const int n = n0 + row;
        const float dsum = mx[row * 4 + 0] + mx[row * 4 + 1] + mx[row * 4 + 2] + mx[row * 4 + 3];
        const float dn = fmaxf(sqrtf(fmaxf(dsum, 0.f)), NORM_EPS);
        logits[(size_t)n * BB + b] = numq[(size_t)n * BB + b] / dn;
    }
}

__global__ __launch_bounds__(64) void loss_row_kernel(
    const float* __restrict__ logits, const int* __restrict__ gm,
    const float* __restrict__ logtemp, float* __restrict__ scaled,
    float* __restrict__ posv, float* __restrict__ rowloss) {
    const int n = blockIdx.x;
    const int b = threadIdx.x;
    const float invtemp = 1.f / expf(logtemp[0]);
    const float e = expf(logits[(size_t)n * BB + b] * invtemp);
    scaled[(size_t)n * BB + b] = e;
    const float sum = waveSum(e);
    const int g = gm[n];
    const float pos = __shfl(e, g, 64);
    if (b == 0) {
        posv[n] = pos;
        rowloss[n] = -logf(pos / (sum + EPS) + EPS);
    }
}

__global__ __launch_bounds__(256) void colsum_kernel(
    const float* __restrict__ scaled, const int* __restrict__ gm,
    float* __restrict__ colsum, float* __restrict__ poscol) {
    const int b = blockIdx.x;
    const int tid = threadIdx.x;
    float s = 0.f, p = 0.f;
    for (int n = tid; n < NN; n += 256) {
        const float e = scaled[(size_t)n * BB + b];
        s += e;
        if (gm[n] == b) p += e;
    }
    s = waveSum(s); p = waveSum(p);
    __shared__ float red[8];
    const int w = tid >> 6;
    if ((tid & 63) == 0) { red[w] = s; red[4 + w] = p; }
    __syncthreads();
    if (tid == 0) {
        colsum[b] = red[0] + red[1] + red[2] + red[3];
        poscol[b] = red[4] + red[5] + red[6] + red[7];
    }
}

__global__ __launch_bounds__(1024) void final_kernel(
    const float* __restrict__ posv, const float* __restrict__ rowloss,
    const float* __restrict__ colsum, const float* __restrict__ poscol,
    const int* __restrict__ gm, float* __restrict__ out) {
    const int n = threadIdx.x;
    const int g = gm[n];
    const float pos = posv[n];
    const float sum_neg = colsum[g] - poscol[g];
    const float cl = -logf(pos / (pos + sum_neg + EPS) + EPS);
    float v = rowloss[n] + cl;
    v = waveSum(v);
    __shared__ float red[16];
    if ((n & 63) == 0) red[n >> 6] = v;
    __syncthreads();
    if (n == 0) {
        float s = 0.f;
#pragma unroll
        for (int i = 0; i < 16; i++) s += red[i];
        out[0] = s / (2.f * NN);
    }
}

extern "C" void kernel_launch(void* const* d_in, const int* in_sizes, int n_in,
                              void* d_out, int out_size, void* d_ws, size_t ws_size,
                              hipStream_t stream) {
    const float* text = (const float*)d_in[0];
    const float* vis = (const float*)d_in[1];
    const int* gm = (const int*)d_in[2];
    const float* gamma = (const float*)d_in[3];
    const float* beta = (const float*)d_in[4];
    const float* logtemp = (const float*)d_in[5];
    float* out = (float*)d_out;

    char* w = (char*)d_ws;
    __hip_bfloat16* tf = (__hip_bfloat16*)w;             w += (size_t)NN * DD * 2;
    __hip_bfloat16* vt = (__hip_bfloat16*)w;             w += (size_t)BB * LP * DD * 2;
    __hip_bfloat16* G  = (__hip_bfloat16*)w;             w += (size_t)BB * LP * LP * 2;
    __hip_bfloat16* Pbuf = (__hip_bfloat16*)w;           w += (size_t)BB * NN * LP * 2;
    float* qinv    = (float*)w;  w += (size_t)NN * 4;
    float* numq    = (float*)w;  w += (size_t)NN * BB * 4;
    float* logits  = (float*)w;  w += (size_t)NN * BB * 4;
    float* scaled  = (float*)w;  w += (size_t)NN * BB * 4;
    float* posv    = (float*)w;  w += (size_t)NN * 4;
    float* rowloss = (float*)w;  w += (size_t)NN * 4;
    float* colsum  = (float*)w;  w += (size_t)BB * 4;
    float* poscol  = (float*)w;  w += (size_t)BB * 4;

    ln_kernel<<<NN, 256, 0, stream>>>(text, tf, gamma, beta, qinv);
    ln_vis_kernel<<<BB * LP, 256, 0, stream>>>(vis, vt, gamma, beta);

    score_kernel<<<1024, 256, 0, stream>>>(tf, vt, qinv, Pbuf, numq);
    gram_kernel<<<512, 256, 0, stream>>>(vt, G);
    den_kernel<<<1024, 256, 0, stream>>>(Pbuf, G, numq, logits);

    loss_row_kernel<<<NN, 64, 0, stream>>>(logits, gm, logtemp, scaled, posv, rowloss);
    colsum_kernel<<<BB, 256, 0, stream>>>(scaled, gm, colsum, poscol);
    final_kernel<<<1, 1024, 0, stream>>>(posv, rowloss, colsum, poscol, gm, out);
}